// Round 17
// baseline (338.351 us; speedup 1.0000x reference)
//
#include <hip/hip_runtime.h>

#define CDIV(a,b) (((a)+(b)-1)/(b))

typedef __attribute__((ext_vector_type(8))) short bf16x8;
typedef __attribute__((ext_vector_type(4))) float f32x4;

__device__ __forceinline__ unsigned short f2b(float v) {
  union { float f; unsigned u; } x; x.f = v;
  unsigned r = x.u + 0x7FFFu + ((x.u >> 16) & 1u);
  return (unsigned short)(r >> 16);
}

__device__ __forceinline__ void gload_lds16(const void* g, void* l) {
  __builtin_amdgcn_global_load_lds(
      (const __attribute__((address_space(1))) unsigned int*)(g),
      (__attribute__((address_space(3))) unsigned int*)(l), 16, 0, 0);
}

struct GA {
  const unsigned short* A;
  const unsigned short* B;
  float* C;
  const int* ridx;
  float* csum;      // non-null => fused column stats (REQUIRES no split-K)
  float* csumsq;
  int N, K, lda, ldb;
};

// ---- 128x128 MFMA GEMM, dbuf LDS + counted vmcnt, XOR-swizzled, optional
// A-row indirection + optional fused column stats; z selects operand set.
__global__ __launch_bounds__(256) void gemm128z(GA g0, GA g1, GA g2, GA g3) {
  __shared__ __align__(16) unsigned short As[2][128 * 64];
  __shared__ __align__(16) unsigned short Bs[2][128 * 64];
  const int z = blockIdx.z;
  GA g = (z == 0) ? g0 : (z == 1) ? g1 : (z == 2) ? g2 : g3;

  const int tid = threadIdx.x;
  const int lane = tid & 63;
  const int wid = tid >> 6;
  const int wm = (wid >> 1) * 64;
  const int wn = (wid & 1) * 64;
  const long bm = (long)blockIdx.x * 128;
  const long bn = (long)blockIdx.y * 128;

  f32x4 acc[4][4] = {};

  const int lr = tid >> 3;
  const int lc = (((tid & 7) ^ (lr & 7)) * 8);

  const unsigned short* ap[4];
  const unsigned short* bp[4];
#pragma unroll
  for (int i = 0; i < 4; ++i) {
    long row = bm + i * 32 + lr;
    long arow = g.ridx ? (long)g.ridx[row] : row;
    ap[i] = g.A + arow * g.lda + lc;
    bp[i] = g.B + (bn + i * 32 + lr) * (long)g.ldb + lc;
  }

  const int rsel = lane & 15;
  const int rx = rsel & 7;

  auto STAGE = [&](int buf, int k0) {
#pragma unroll
    for (int i = 0; i < 4; ++i) {
      const int eoff = (i * 256 + tid) * 8;
      gload_lds16(ap[i] + k0, &As[buf][eoff]);
      gload_lds16(bp[i] + k0, &Bs[buf][eoff]);
    }
  };
  auto COMPUTE = [&](int buf) {
#pragma unroll
    for (int kk = 0; kk < 2; ++kk) {
      const int koz = (((kk * 4 + (lane >> 4)) ^ rx) << 3);
      bf16x8 av[4], bv[4];
#pragma unroll
      for (int m = 0; m < 4; ++m)
        av[m] = *(const bf16x8*)(&As[buf][(wm + m * 16 + rsel) * 64 + koz]);
#pragma unroll
      for (int n = 0; n < 4; ++n)
        bv[n] = *(const bf16x8*)(&Bs[buf][(wn + n * 16 + rsel) * 64 + koz]);
#pragma unroll
      for (int m = 0; m < 4; ++m)
#pragma unroll
        for (int n = 0; n < 4; ++n)
          acc[m][n] = __builtin_amdgcn_mfma_f32_16x16x32_bf16(av[m], bv[n], acc[m][n], 0, 0, 0);
    }
  };

  STAGE(0, 0);
  int cur = 0;
  for (int k0 = 64; k0 < g.K; k0 += 64) {
    STAGE(cur ^ 1, k0);
    asm volatile("s_waitcnt vmcnt(8)" ::: "memory");
    __builtin_amdgcn_s_barrier();
    asm volatile("" ::: "memory");
    COMPUTE(cur);
    asm volatile("" ::: "memory");
    __builtin_amdgcn_s_barrier();
    cur ^= 1;
  }
  asm volatile("s_waitcnt vmcnt(0)" ::: "memory");
  __builtin_amdgcn_s_barrier();
  asm volatile("" ::: "memory");
  COMPUTE(cur);

  const int crow0 = (lane >> 4) * 4;
  const int ccol = lane & 15;
#pragma unroll
  for (int m = 0; m < 4; ++m)
#pragma unroll
    for (int n = 0; n < 4; ++n) {
      const long r = bm + wm + m * 16 + crow0;
      const long c = bn + wn + n * 16 + ccol;
#pragma unroll
      for (int q = 0; q < 4; ++q)
        g.C[(r + q) * (long)g.N + c] = acc[m][n][q];
    }

  if (g.csum) {
#pragma unroll
    for (int n = 0; n < 4; ++n) {
      float s = 0.f, s2 = 0.f;
#pragma unroll
      for (int m = 0; m < 4; ++m)
#pragma unroll
        for (int q = 0; q < 4; ++q) {
          float v = acc[m][n][q];
          s += v; s2 += v * v;
        }
      s  += __shfl_xor(s, 16);  s  += __shfl_xor(s, 32);
      s2 += __shfl_xor(s2, 16); s2 += __shfl_xor(s2, 32);
      if ((lane >> 4) == 0) {
        const long c = bn + wn + n * 16 + ccol;
        atomicAdd(&g.csum[c], s);
        atomicAdd(&g.csumsq[c], s2);
      }
    }
  }
}

// ---- 128x128 GEMM + fused stats + device-wide spin barrier + fused BN apply.
// Writes final BN+ReLU output directly (no f32 Z roundtrip). REQUIRES all
// blocks co-resident: 432 blocks @ 64KB LDS = 2/CU -> capacity 512. no split-K.
__global__ __launch_bounds__(256) void gemm128_bn(
    GA g, const float* __restrict__ gamma, const float* __restrict__ beta,
    float* __restrict__ outp, int outN, int nblocks, int* __restrict__ done_ctr) {
  __shared__ __align__(16) unsigned short As[2][128 * 64];
  __shared__ __align__(16) unsigned short Bs[2][128 * 64];

  const int tid = threadIdx.x;
  const int lane = tid & 63;
  const int wid = tid >> 6;
  const int wm = (wid >> 1) * 64;
  const int wn = (wid & 1) * 64;
  const long bm = (long)blockIdx.x * 128;
  const long bn = (long)blockIdx.y * 128;

  f32x4 acc[4][4] = {};

  const int lr = tid >> 3;
  const int lc = (((tid & 7) ^ (lr & 7)) * 8);

  const unsigned short* ap[4];
  const unsigned short* bp[4];
#pragma unroll
  for (int i = 0; i < 4; ++i) {
    long row = bm + i * 32 + lr;
    ap[i] = g.A + row * g.lda + lc;
    bp[i] = g.B + (bn + i * 32 + lr) * (long)g.ldb + lc;
  }

  const int rsel = lane & 15;
  const int rx = rsel & 7;

  auto STAGE = [&](int buf, int k0) {
#pragma unroll
    for (int i = 0; i < 4; ++i) {
      const int eoff = (i * 256 + tid) * 8;
      gload_lds16(ap[i] + k0, &As[buf][eoff]);
      gload_lds16(bp[i] + k0, &Bs[buf][eoff]);
    }
  };
  auto COMPUTE = [&](int buf) {
#pragma unroll
    for (int kk = 0; kk < 2; ++kk) {
      const int koz = (((kk * 4 + (lane >> 4)) ^ rx) << 3);
      bf16x8 av[4], bv[4];
#pragma unroll
      for (int m = 0; m < 4; ++m)
        av[m] = *(const bf16x8*)(&As[buf][(wm + m * 16 + rsel) * 64 + koz]);
#pragma unroll
      for (int n = 0; n < 4; ++n)
        bv[n] = *(const bf16x8*)(&Bs[buf][(wn + n * 16 + rsel) * 64 + koz]);
#pragma unroll
      for (int m = 0; m < 4; ++m)
#pragma unroll
        for (int n = 0; n < 4; ++n)
          acc[m][n] = __builtin_amdgcn_mfma_f32_16x16x32_bf16(av[m], bv[n], acc[m][n], 0, 0, 0);
    }
  };

  STAGE(0, 0);
  int cur = 0;
  for (int k0 = 64; k0 < g.K; k0 += 64) {
    STAGE(cur ^ 1, k0);
    asm volatile("s_waitcnt vmcnt(8)" ::: "memory");
    __builtin_amdgcn_s_barrier();
    asm volatile("" ::: "memory");
    COMPUTE(cur);
    asm volatile("" ::: "memory");
    __builtin_amdgcn_s_barrier();
    cur ^= 1;
  }
  asm volatile("s_waitcnt vmcnt(0)" ::: "memory");
  __builtin_amdgcn_s_barrier();
  asm volatile("" ::: "memory");
  COMPUTE(cur);

  const int crow0 = (lane >> 4) * 4;
  const int ccol = lane & 15;

  // fused column stats (device-scope atomics -> coherent point)
#pragma unroll
  for (int n = 0; n < 4; ++n) {
    float s = 0.f, s2 = 0.f;
#pragma unroll
    for (int m = 0; m < 4; ++m)
#pragma unroll
      for (int q = 0; q < 4; ++q) {
        float v = acc[m][n][q];
        s += v; s2 += v * v;
      }
    s  += __shfl_xor(s, 16);  s  += __shfl_xor(s, 32);
    s2 += __shfl_xor(s2, 16); s2 += __shfl_xor(s2, 32);
    if ((lane >> 4) == 0) {
      const long c = bn + wn + n * 16 + ccol;
      atomicAdd(&g.csum[c], s);
      atomicAdd(&g.csumsq[c], s2);
    }
  }

  // device-wide barrier (all blocks resident by construction)
  __threadfence();
  __syncthreads();
  if (tid == 0) {
    atomicAdd(done_ctr, 1);
    while (__hip_atomic_load(done_ctr, __ATOMIC_ACQUIRE,
                             __HIP_MEMORY_SCOPE_AGENT) < nblocks) {
      __builtin_amdgcn_s_sleep(8);
    }
  }
  __syncthreads();

  // BN + ReLU applied in registers, write final output
  const float invB = 1.f / 2048.f;
#pragma unroll
  for (int n = 0; n < 4; ++n) {
    const long c = bn + wn + n * 16 + ccol;
    if (c >= outN) continue;
    float cs = __hip_atomic_load(&g.csum[c], __ATOMIC_RELAXED, __HIP_MEMORY_SCOPE_AGENT);
    float cq = __hip_atomic_load(&g.csumsq[c], __ATOMIC_RELAXED, __HIP_MEMORY_SCOPE_AGENT);
    float m_ = cs * invB;
    float var = fmaxf(cq * invB - m_ * m_, 0.f);
    float sc = gamma[c] * rsqrtf(var + 1e-5f);
    float sh = beta[c] - m_ * sc;
#pragma unroll
    for (int m = 0; m < 4; ++m) {
      const long r = bm + wm + m * 16 + crow0;
#pragma unroll
      for (int q = 0; q < 4; ++q) {
        float v = acc[m][n][q] * sc + sh;
        v = (v >= 0.f) ? v : 0.f;
        outp[(r + q) * (long)outN + c] = v;
      }
    }
  }
}

// ---- 64x128 MFMA GEMM, dbuf + counted vmcnt, swizzled, optional fused stats
__global__ __launch_bounds__(256) void gemm64s(GA g0, GA g1, GA g2, GA g3) {
  __shared__ __align__(16) unsigned short As[2][64 * 64];
  __shared__ __align__(16) unsigned short Bs[2][128 * 64];
  const int z = blockIdx.z;
  GA g = (z == 0) ? g0 : (z == 1) ? g1 : (z == 2) ? g2 : g3;

  const int tid = threadIdx.x;
  const int lane = tid & 63;
  const int wid = tid >> 6;
  const int wn = wid * 32;
  const long bm = (long)blockIdx.x * 64;
  const long bn = (long)blockIdx.y * 128;

  f32x4 acc[4][2] = {};

  const int lr = tid >> 3;
  const int lc = (((tid & 7) ^ (lr & 7)) * 8);

  const long r0 = g.ridx ? (long)g.ridx[bm + lr] : bm + lr;
  const long r1 = g.ridx ? (long)g.ridx[bm + 32 + lr] : bm + 32 + lr;
  const unsigned short* ap0 = g.A + r0 * g.lda + lc;
  const unsigned short* ap1 = g.A + r1 * g.lda + lc;
  const unsigned short* bp0 = g.B + (bn + lr) * (long)g.ldb + lc;
  const unsigned short* bp1 = g.B + (bn + 32 + lr) * (long)g.ldb + lc;
  const unsigned short* bp2 = g.B + (bn + 64 + lr) * (long)g.ldb + lc;
  const unsigned short* bp3 = g.B + (bn + 96 + lr) * (long)g.ldb + lc;

  const int rsel = lane & 15;
  const int rx = rsel & 7;

  auto STAGE = [&](int buf, int k0) {
    gload_lds16(ap0 + k0, &As[buf][tid * 8]);
    gload_lds16(ap1 + k0, &As[buf][(256 + tid) * 8]);
    gload_lds16(bp0 + k0, &Bs[buf][tid * 8]);
    gload_lds16(bp1 + k0, &Bs[buf][(256 + tid) * 8]);
    gload_lds16(bp2 + k0, &Bs[buf][(512 + tid) * 8]);
    gload_lds16(bp3 + k0, &Bs[buf][(768 + tid) * 8]);
  };
  auto COMPUTE = [&](int buf) {
#pragma unroll
    for (int kk = 0; kk < 2; ++kk) {
      const int koz = (((kk * 4 + (lane >> 4)) ^ rx) << 3);
      bf16x8 av[4], bv[2];
#pragma unroll
      for (int m = 0; m < 4; ++m)
        av[m] = *(const bf16x8*)(&As[buf][(m * 16 + rsel) * 64 + koz]);
#pragma unroll
      for (int n = 0; n < 2; ++n)
        bv[n] = *(const bf16x8*)(&Bs[buf][(wn + n * 16 + rsel) * 64 + koz]);
#pragma unroll
      for (int m = 0; m < 4; ++m)
#pragma unroll
        for (int n = 0; n < 2; ++n)
          acc[m][n] = __builtin_amdgcn_mfma_f32_16x16x32_bf16(av[m], bv[n], acc[m][n], 0, 0, 0);
    }
  };

  STAGE(0, 0);
  int cur = 0;
  for (int k0 = 64; k0 < g.K; k0 += 64) {
    STAGE(cur ^ 1, k0);
    asm volatile("s_waitcnt vmcnt(6)" ::: "memory");
    __builtin_amdgcn_s_barrier();
    asm volatile("" ::: "memory");
    COMPUTE(cur);
    asm volatile("" ::: "memory");
    __builtin_amdgcn_s_barrier();
    cur ^= 1;
  }
  asm volatile("s_waitcnt vmcnt(0)" ::: "memory");
  __builtin_amdgcn_s_barrier();
  asm volatile("" ::: "memory");
  COMPUTE(cur);

  const int crow0 = (lane >> 4) * 4;
  const int ccol = lane & 15;
#pragma unroll
  for (int m = 0; m < 4; ++m)
#pragma unroll
    for (int n = 0; n < 2; ++n) {
      const long r = bm + m * 16 + crow0;
      const long c = bn + wn + n * 16 + ccol;
#pragma unroll
      for (int q = 0; q < 4; ++q)
        g.C[(r + q) * (long)g.N + c] = acc[m][n][q];
    }

  if (g.csum) {
#pragma unroll
    for (int n = 0; n < 2; ++n) {
      float s = 0.f, s2 = 0.f;
#pragma unroll
      for (int m = 0; m < 4; ++m)
#pragma unroll
        for (int q = 0; q < 4; ++q) {
          float v = acc[m][n][q];
          s += v; s2 += v * v;
        }
      s  += __shfl_xor(s, 16);  s  += __shfl_xor(s, 32);
      s2 += __shfl_xor(s2, 16); s2 += __shfl_xor(s2, 32);
      if ((lane >> 4) == 0) {
        const long c = bn + wn + n * 16 + ccol;
        atomicAdd(&g.csum[c], s);
        atomicAdd(&g.csumsq[c], s2);
      }
    }
  }
}

// ---------------- merged prep kernels ----------------
__global__ void init_all(int* iz, int nIz, float* deg, int nDeg,
                         float* stats, int nStats) {
  int i = blockIdx.x * 256 + threadIdx.x;
  if (i < nIz) iz[i] = 0;
  if (i < nDeg) deg[i] = 1.f;
  if (i < nStats) stats[i] = 0.f;
}

__global__ void prep_b(const int* __restrict__ d_ei, const float* __restrict__ d_ew,
                       float* __restrict__ deg_d,
                       const int* __restrict__ p_ei, const float* __restrict__ p_ew,
                       float* __restrict__ deg_p,
                       const int* __restrict__ d_index, int* __restrict__ flag_d,
                       const int* __restrict__ p_index, int* __restrict__ flag_p) {
  int e = blockIdx.x * 256 + threadIdx.x;
  if (e < 65536) atomicAdd(&deg_d[d_ei[65536 + e]], d_ew[e]);
  int e2 = e - 65536;
  if (e2 >= 0 && e2 < 25000) atomicAdd(&deg_p[p_ei[25000 + e2]], p_ew[e2]);
  if (e < 2048) flag_d[d_index[e]] = 1;
  else if (e < 4096) flag_p[p_index[e - 2048]] = 1;
}

__global__ void prep_c(float* __restrict__ deg, int nDeg,
                       int* __restrict__ flag_d, int* __restrict__ ctr_d,
                       int* __restrict__ slot_d,
                       int* __restrict__ flag_p, int* __restrict__ ctr_p,
                       int* __restrict__ slot_p) {
  int i = blockIdx.x * 256 + threadIdx.x;
  if (i < nDeg) deg[i] = rsqrtf(deg[i]);
  if (i < 10000) {
    if (flag_d[i]) { int s = atomicAdd(ctr_d, 1); flag_d[i] = s + 1; slot_d[s] = i; }
  } else if (i < 15000) {
    int j = i - 10000;
    if (flag_p[j]) { int s = atomicAdd(ctr_p, 1); flag_p[j] = s + 1; slot_p[s] = j; }
  }
}

__global__ void prep_d(const int* __restrict__ d_index, const int* __restrict__ flag_d,
                       int* __restrict__ ridx_d,
                       const int* __restrict__ p_index, const int* __restrict__ flag_p,
                       int* __restrict__ ridx_p,
                       const int* __restrict__ d_ei, int* __restrict__ cnt_d,
                       const int* __restrict__ p_ei, int* __restrict__ cnt_p) {
  int e = blockIdx.x * 256 + threadIdx.x;
  if (e < 2048) ridx_d[e] = flag_d[d_index[e]] - 1;
  else if (e < 4096) { int j = e - 2048; ridx_p[j] = flag_p[p_index[j]] - 1; }
  if (e < 65536) { int s = flag_d[d_ei[65536 + e]]; if (s) atomicAdd(&cnt_d[s - 1], 1); }
  int e2 = e - 65536;
  if (e2 >= 0 && e2 < 25000) { int s = flag_p[p_ei[25000 + e2]]; if (s) atomicAdd(&cnt_p[s - 1], 1); }
}

__global__ void scan2048x2(const int* __restrict__ cnt_d, int* __restrict__ rp_d,
                           const int* __restrict__ cnt_p, int* __restrict__ rp_p) {
  const int* cnt = blockIdx.x ? cnt_p : cnt_d;
  int* rowptr    = blockIdx.x ? rp_p : rp_d;
  __shared__ int part[256];
  int tid = threadIdx.x;
  int base = tid * 8;
  int vals[8]; int s = 0;
#pragma unroll
  for (int i = 0; i < 8; ++i) { vals[i] = s; s += cnt[base + i]; }
  part[tid] = s;
  __syncthreads();
  if (tid == 0) { int r = 0; for (int i = 0; i < 256; ++i) { int t = part[i]; part[i] = r; r += t; } }
  __syncthreads();
  int off = part[tid];
#pragma unroll
  for (int i = 0; i < 8; ++i) rowptr[base + i] = off + vals[i];
  if (tid == 255) rowptr[2048] = off + s;
}
__global__ void fill_edges2(
    const int* __restrict__ d_ei, const float* __restrict__ d_ew,
    const float* __restrict__ dinv_d, const int* __restrict__ flag_d,
    const int* __restrict__ rp_d, int* __restrict__ fill_d,
    int2* __restrict__ em_d,
    const int* __restrict__ p_ei, const float* __restrict__ p_ew,
    const float* __restrict__ dinv_p, const int* __restrict__ flag_p,
    const int* __restrict__ rp_p, int* __restrict__ fill_p,
    int2* __restrict__ em_p) {
  int e = blockIdx.x * 256 + threadIdx.x;
  if (e < 65536) {
    int dst = d_ei[65536 + e];
    int s = flag_d[dst];
    if (s) {
      int src = d_ei[e];
      int pos = rp_d[s - 1] + atomicAdd(&fill_d[s - 1], 1);
      float cf = d_ew[e] * dinv_d[src] * dinv_d[dst];
      em_d[pos] = make_int2(src, __float_as_int(cf));
    }
  }
  int e2 = e - 65536;
  if (e2 >= 0 && e2 < 25000) {
    int dst = p_ei[25000 + e2];
    int s = flag_p[dst];
    if (s) {
      int src = p_ei[e2];
      int pos = rp_p[s - 1] + atomicAdd(&fill_p[s - 1], 1);
      float cf = p_ew[e2] * dinv_p[src] * dinv_p[dst];
      em_p[pos] = make_int2(src, __float_as_int(cf));
    }
  }
}

// ---- wave-per-(slot, 64-f4 chunk) gather, 4-edge unroll, packed int2 meta.
__global__ __launch_bounds__(256) void gather_agg5b(
    const float* __restrict__ Xd, const float* __restrict__ dinv_d,
    const int* __restrict__ slot_d, const int* __restrict__ rp_d,
    const int2* __restrict__ em_d,
    const int* __restrict__ nflag_d, unsigned short* __restrict__ aggd,
    const float* __restrict__ Xp, const float* __restrict__ dinv_p,
    const int* __restrict__ slot_p, const int* __restrict__ rp_p,
    const int2* __restrict__ em_p,
    const int* __restrict__ nflag_p, unsigned short* __restrict__ aggp)
{
  const int gw = blockIdx.x * 4 + (threadIdx.x >> 6);
  const int lane = threadIdx.x & 63;

  int slot, c, Kdata4, Kst4, Kld, nflag;
  const float *X, *dinv; const int *slotn, *rp; const int2* em;
  unsigned short* agg;
  if (gw < 8192) {
    slot = gw >> 2;
    c = (gw & 3) * 64 + lane;
    X = Xd; dinv = dinv_d; slotn = slot_d; rp = rp_d; em = em_d;
    nflag = *nflag_d; agg = aggd; Kdata4 = 256; Kst4 = 256; Kld = 1024;
  } else {
    int q = gw - 8192;
    slot = q / 11;
    c = (q - slot * 11) * 64 + lane;
    X = Xp; dinv = dinv_p; slotn = slot_p; rp = rp_p; em = em_p;
    nflag = *nflag_p; agg = aggp; Kdata4 = 703; Kst4 = 704; Kld = 2812;
  }
  if (slot >= nflag) return;

  const int n = slotn[slot];
  const float dn = dinv[n];
  const float selfc = dn * dn;
  const int e0 = rp[slot], e1 = rp[slot + 1];
  const bool valid = c < Kdata4;

  float ax = 0.f, ay = 0.f, az = 0.f, aw = 0.f;
  if (valid) {
    float4 v = *(const float4*)(X + (long)n * Kld + 4 * c);
    ax = selfc * v.x; ay = selfc * v.y; az = selfc * v.z; aw = selfc * v.w;
  }

  int e = e0;
  for (; e + 4 <= e1; e += 4) {
    const int2 m0 = em[e], m1 = em[e + 1], m2 = em[e + 2], m3 = em[e + 3];
    if (valid) {
      float4 v0 = *(const float4*)(X + (long)m0.x * Kld + 4 * c);
      float4 v1 = *(const float4*)(X + (long)m1.x * Kld + 4 * c);
      float4 v2 = *(const float4*)(X + (long)m2.x * Kld + 4 * c);
      float4 v3 = *(const float4*)(X + (long)m3.x * Kld + 4 * c);
      const float c0 = __int_as_float(m0.y), c1 = __int_as_float(m1.y);
      const float c2 = __int_as_float(m2.y), c3 = __int_as_float(m3.y);
      ax += c0 * v0.x; ay += c0 * v0.y; az += c0 * v0.z; aw += c0 * v0.w;
      ax += c1 * v1.x; ay += c1 * v1.y; az += c1 * v1.z; aw += c1 * v1.w;
      ax += c2 * v2.x; ay += c2 * v2.y; az += c2 * v2.z; aw += c2 * v2.w;
      ax += c3 * v3.x; ay += c3 * v3.y; az += c3 * v3.z; aw += c3 * v3.w;
    }
  }
  for (; e < e1; ++e) {
    const int2 m = em[e];
    if (valid) {
      float4 v = *(const float4*)(X + (long)m.x * Kld + 4 * c);
      const float cf = __int_as_float(m.y);
      ax += cf * v.x; ay += cf * v.y; az += cf * v.z; aw += cf * v.w;
    }
  }

  if (c < Kst4) {
    ushort4 o; o.x = f2b(ax); o.y = f2b(ay); o.z = f2b(az); o.w = f2b(aw);
    *(ushort4*)(agg + (long)slot * (Kst4 * 4) + 4 * c) = o;
  }
}

// ---- all 7 weight transposes in one flattened launch ----
__global__ void transposeAll(
    const float* W0, unsigned short* T0,
    const float* W1, unsigned short* T1,
    const float* W2, unsigned short* T2,
    const float* W3, unsigned short* T3,
    const float* W4, unsigned short* T4,
    const float* W5, unsigned short* T5,
    const float* W6, unsigned short* T6)
{
  __shared__ float tile[32][33];
  int bid = blockIdx.x;
  const float* W; unsigned short* Wt; int K, N, Kp, Np_, tx, local;
  if      (bid <  1024) { W=W0; Wt=T0; K=1024; N=1024; Kp=1024; Np_=1024; tx=32;  local=bid; }
  else if (bid <  3840) { W=W1; Wt=T1; K=2812; N=1024; Kp=2816; Np_=1024; tx=88;  local=bid-1024; }
  else if (bid <  7296) { W=W2; Wt=T2; K=3372; N=1024; Kp=3456; Np_=1024; tx=108; local=bid-3840; }
  else if (bid <  7552) { W=W3; Wt=T3; K=1024; N=256;  Kp=1024; Np_=256;  tx=32;  local=bid-7296; }
  else if (bid <  7808) { W=W4; Wt=T4; K=256;  N=1024; Kp=256;  Np_=1024; tx=8;   local=bid-7552; }
  else if (bid <  7840) { W=W5; Wt=T5; K=256;  N=64;   Kp=256;  Np_=128;  tx=8;   local=bid-7808; }
  else                  { W=W6; Wt=T6; K=1024; N=3372; Kp=1024; Np_=3456; tx=32;  local=bid-7840; }
  int k0 = (local % tx) * 32, n0 = (local / tx) * 32;
  for (int i = threadIdx.y; i < 32; i += 8) {
    int k = k0 + i, n = n0 + threadIdx.x;
    tile[i][threadIdx.x] = (k < K && n < N) ? W[(size_t)k * N + n] : 0.f;
  }
  __syncthreads();
  for (int i = threadIdx.y; i < 32; i += 8) {
    int n = n0 + i, k = k0 + threadIdx.x;
    if (n < Np_ && k < Kp) Wt[(size_t)n * Kp + k] = f2b(tile[threadIdx.x][i]);
  }
}

// vectorized colstats (for split-K layers only)
__global__ void colstats4(const float* __restrict__ Z, const float* __restrict__ Z2,
                          const float* __restrict__ Z3, int ldz, int cols,
                          float* __restrict__ csum, float* __restrict__ csumsq) {
  int c4 = blockIdx.x * 256 + threadIdx.x;
  if (c4 * 4 >= cols) return;
  int r0 = blockIdx.y * 16;
  float sx = 0.f, sy = 0.f, sz_ = 0.f, sw = 0.f;
  float qx = 0.f, qy = 0.f, qz = 0.f, qw = 0.f;
  for (int r = r0; r < r0 + 16; ++r) {
    float4 v = *(const float4*)(Z + (long)r * ldz + 4 * c4);
    if (Z2) { float4 w = *(const float4*)(Z2 + (long)r * ldz + 4 * c4);
              v.x += w.x; v.y += w.y; v.z += w.z; v.w += w.w; }
    if (Z3) { float4 w = *(const float4*)(Z3 + (long)r * ldz + 4 * c4);
              v.x += w.x; v.y += w.y; v.z += w.z; v.w += w.w; }
    sx += v.x; sy += v.y; sz_ += v.z; sw += v.w;
    qx += v.x * v.x; qy += v.y * v.y; qz += v.z * v.z; qw += v.w * v.w;
  }
  atomicAdd(&csum[4 * c4 + 0], sx); atomicAdd(&csum[4 * c4 + 1], sy);
  atomicAdd(&csum[4 * c4 + 2], sz_); atomicAdd(&csum[4 * c4 + 3], sw);
  atomicAdd(&csumsq[4 * c4 + 0], qx); atomicAdd(&csumsq[4 * c4 + 1], qy);
  atomicAdd(&csumsq[4 * c4 + 2], qz); atomicAdd(&csumsq[4 * c4 + 3], qw);
}

// apply with INLINE bn-finalize. csum==null -> bias-only.
__global__ void apply_bn4(const float* __restrict__ Z, const float* __restrict__ Z2,
                          const float* __restrict__ Z3,
                          int ldz, int total4, int cols4,
                          const float* __restrict__ csum, const float* __restrict__ csumsq,
                          const float* __restrict__ g, const float* __restrict__ beta,
                          int leaky,
                          float* __restrict__ f32out, int ldf,
                          unsigned short* __restrict__ b16out, int ldb) {
  int idx = blockIdx.x*256+threadIdx.x;
  if (idx >= total4) return;
  int b = idx / cols4, j = (idx % cols4) * 4;
  float4 v = *(const float4*)(Z + (long)b * ldz + j);
  if (Z2) { float4 w = *(const float4*)(Z2 + (long)b * ldz + j);
            v.x += w.x; v.y += w.y; v.z += w.z; v.w += w.w; }
  if (Z3) { float4 w = *(const float4*)(Z3 + (long)b * ldz + j);
            v.x += w.x; v.y += w.y; v.z += w.z; v.w += w.w; }
  if (csum) {
    const float invB = 1.f / 2048.f;
    float4 cs = *(const float4*)(csum + j);
    float4 cq = *(const float4*)(csumsq + j);
    float4 gg = *(const float4*)(g + j);
    float4 bb = *(const float4*)(beta + j);
    float m, var, sc;
    m = cs.x * invB; var = fmaxf(cq.x * invB - m * m, 0.f);
    sc = gg.x * rsqrtf(var + 1e-5f); v.x = v.x * sc + (bb.x - m * sc);
    m = cs.y * invB; var = fmaxf(cq.y * invB - m * m, 0.f);
    sc = gg.y * rsqrtf(var + 1e-5f); v.y = v.y * sc + (bb.y - m * sc);
    m = cs.z * invB; var = fmaxf(cq.z * invB - m * m, 0.f);
    sc = gg.z * rsqrtf(var + 1e-5f); v.z = v.z * sc + (bb.z - m * sc);
    m = cs.w * invB; var = fmaxf(cq.w * invB - m * m, 0.f);
    sc = gg.w * rsqrtf(var + 1e-5f); v.w = v.w * sc + (bb.w - m * sc);
  } else {
    float4 bb = *(const float4*)(beta + j);
    v.x += bb.x; v.y += bb.y; v.z += bb.z; v.w += bb.w;
  }
  const float neg = leaky ? 0.01f : 0.f;
  v.x = (v.x >= 0.f) ? v.x : neg * v.x;
  v.y = (v.y >= 0.f) ? v.y : neg * v.y;
  v.z = (v.z >= 0.f) ? v.z : neg * v.z;
  v.w = (v.w >= 0.f) ? v.w : neg * v.w;
  if (f32out) *(float4*)(f32out + (long)b * ldf + j) = v;
  if (b16out) {
    ushort4 o; o.x = f2b(v.x); o.y = f2b(v.y); o.z = f2b(v.z); o.w = f2b(v.w);
    *(ushort4*)(b16out + (long)b * ldb + j) = o;
  }
}

// GCN applies (f4) + feat copy (f4) + pad in one launch.
// idx < 2*2048*256: apply part. else copy part: per row 75 dv + 256 pe + 21 pad f4-units.
__global__ void apply_feat(const float* __restrict__ Zd, const float* __restrict__ Pd,
                           const float* __restrict__ bd,
                           const float* __restrict__ Zp, const float* __restrict__ Pp,
                           const float* __restrict__ bp,
                           const float* __restrict__ dv, const float* __restrict__ pe,
                           float* __restrict__ feat_f32, unsigned short* __restrict__ feat_b16) {
  int idx = blockIdx.x*256+threadIdx.x;
  const int APPLY_N = 2 * 2048 * 256;
  if (idx < APPLY_N) {
    const bool isP = idx >= 2048 * 256;
    int l = isP ? idx - 2048 * 256 : idx;
    int b = l >> 8, j = (l & 255) * 4;
    const float* Z = isP ? Zp : Zd;
    const float* P = isP ? Pp : Pd;
    const float* bias = isP ? bp : bd;
    const int coloff = isP ? 2348 : 1324;
    float4 v = *(const float4*)(Z + (long)b * 1024 + j);
    float4 w = *(const float4*)(P + (long)b * 1024 + j);
    float4 bb = *(const float4*)(bias + j);
    v.x += w.x + bb.x; v.y += w.y + bb.y; v.z += w.z + bb.z; v.w += w.w + bb.w;
    v.x = (v.x >= 0.f) ? v.x : 0.01f * v.x;
    v.y = (v.y >= 0.f) ? v.y : 0.01f * v.y;
    v.z = (v.z >= 0.f) ? v.z : 0.01f * v.z;
    v.w = (v.w >= 0.f) ? v.w : 0.01f * v.w;
    *(float4*)(feat_f32 + (long)b * 3372 + coloff + j) = v;
    ushort4 o; o.x = f2b(v.x); o.y = f2b(v.y); o.z = f2b(v.z); o.w = f2b(v.w);
    *(ushort4*)(feat_b16 + (long)b * 3456 + coloff + j) = o;
    return;
  }
  int q = idx - APPLY_N;
  if (q >= 2048 * 352) return;
  int b = q / 352, u = q % 352;
  if (u < 331) {
    int c = u * 4;                           // 0..1323
    float4 v;
    if (u < 75) v = *(const float4*)(dv + (long)b * 300 + c);
    else        v = *(const float4*)(pe + (long)b * 1024 + (c - 300));
    *(float4*)(feat_f32 + (long)b * 3372 + c) = v;
    ushort4 o; o.x = f2b(v.x); o.y = f2b(v.y); o.z = f2b(v.z); o.w = f2b(v.w);
    *(ushort4*)(feat_b16 + (long)b * 3456 + c) = o;
  } else {
    int c = 3372 + (u - 331) * 4;            // bf16 pad
    ushort4 o; o.x = 0; o.y = 0; o.z = 0; o.w = 0;
    *(ushort4*)(feat_b16 + (long)b * 3456 + c) = o;
  }
}

// head: bn(inline stats) + lrelu + dot(W2) + b2 -> y
__global__ void head_fused(const float* __restrict__ Z, int ldz,
                           const float* __restrict__ csum, const float* __restrict__ csumsq,
                           const float* __restrict__ g, const float* __restrict__ beta,
                           const float* __restrict__ W2, const float* __restrict__ b2,
                           float* __restrict__ y) {
  int b = blockIdx.x*256+threadIdx.x;
  if (b >= 2048) return;
  const float invB = 1.f / 2048.f;
  float s = b2[0];
  for (int k = 0; k < 64; ++k) {
    float m = csum[k] * invB;
    float var = fmaxf(csumsq[k] * invB - m * m, 0.f);
    float sc = g[k] * rsqrtf(var + 1e-5f);
    float sh = beta[k] - m * sc;
    float v = Z[(long)b * ldz + k];
    v = v * sc + sh;
    v = (v >= 0.f) ? v : 0.01f * v;
    s += v * W2[k];
  }
  y[b] = s;
}

extern "C" void kernel_launch(void* const* d_in, const int* in_sizes, int n_in,
                              void* d_out, int out_size, void* d_ws, size_t ws_size,
                              hipStream_t stream) {
  (void)in_sizes; (void)n_in; (void)out_size; (void)ws_size;
  const int*   d_index = (const int*)d_in[0];
  const int*   p_index = (const int*)d_in[1];
  const float* d_vecs  = (const float*)d_in[2];
  const float* p_emb   = (const float*)d_in[3];
  const float* d_ecfps = (const float*)d_in[4];
  const int*   d_ei    = (const int*)d_in[5];
  const float* d_ew    = (const float*)d_in[6];
  const float* p_gos   = (const float*)d_in[7];
  const int*   p_ei    = (const int*)d_in[8];
  const float* p_ew    = (const float*)d_in[9];
  const float* d_gcn_W = (const float*)d_in[10];
  const float* d_gcn_b = (const float*)d_in[11];
  const float* p_gcn_W = (const float*)d_in[12];
  const float* p_gcn_b = (const float*)d_in[13];
  const float* enc_W1  = (const float*)d_in[14];
  const float* enc_g1  = (const float*)d_in[16];
  const float* enc_be1 = (const float*)d_in[17];
  const float* enc_W2  = (const float*)d_in[18];
  const float* enc_g2  = (const float*)d_in[20];
  const float* enc_be2 = (const float*)d_in[21];
  const float* dec_W1  = (const float*)d_in[22];
  const float* dec_g1  = (const float*)d_in[24];
  const float* dec_be1 = (const float*)d_in[25];
  const float* dec_W2  = (const float*)d_in[26];
  const float* dec_g2  = (const float*)d_in[28];
  const float* dec_be2 = (const float*)d_in[29];
  const float* out_W1  = (const float*)d_in[30];
  const float* out_g1  = (const float*)d_in[32];
  const float* out_be1 = (const float*)d_in[33];
  const float* out_W2  = (const float*)d_in[34];
  const float* out_b2  = (const float*)d_in[35];

  float* out = (float*)d_out;
  float* y_out    = out;
  float* enc_out  = out + 2048;
  float* dec_out  = out + 526336;
  float* feat_out = out + 7432192;

  char* ws = (char*)d_ws;
  size_t off = 0;
  auto alloc = [&](size_t bytes) {
    size_t o = off; off = (off + bytes + 255) & ~(size_t)255; return (void*)(ws + o);
  };
  int* iz = (int*)alloc((size_t)23200 * 4);
  int* flag_d = iz;
  int* flag_p = iz + 10000;
  int* cnt_d  = iz + 15000;
  int* cnt_p  = iz + 17048;
  int* fill_d = iz + 19096;
  int* fill_p = iz + 21144;
  int* ctr    = iz + 23192;      // 2
  int* done_ctr = iz + 23196;    // spin-barrier counter (zeroed each call)
  int* slotnode_d = (int*)alloc(2048 * 4);
  int* slotnode_p = (int*)alloc(2048 * 4);
  int* rowptr_d = (int*)alloc(2049 * 4);
  int* rowptr_p = (int*)alloc(2049 * 4);
  int* ridx_d = (int*)alloc(2048 * 4);
  int* ridx_p = (int*)alloc(2048 * 4);
  int2* em_d = (int2*)alloc((size_t)65536 * 8);
  int2* em_p = (int2*)alloc((size_t)25000 * 8);
  float* deg   = (float*)alloc((size_t)15000 * 4);
  float* deg_d = deg;
  float* deg_p = deg + 10000;
  float* stats = (float*)alloc((size_t)34560 * 4);
  float* cs_e1 = stats,         * cq_e1 = stats + 3456;
  float* cs_e2 = stats + 6912,  * cq_e2 = stats + 10368;
  float* cs_d1 = stats + 13824, * cq_d1 = stats + 17280;
  float* cs_d2 = stats + 27648, * cq_d2 = stats + 31104;
  unsigned short* aggd_b = (unsigned short*)alloc((size_t)2048 * 1024 * 2);
  unsigned short* aggp_b = (unsigned short*)alloc((size_t)2048 * 2816 * 2);
  unsigned short* WdT   = (unsigned short*)alloc((size_t)1024 * 1024 * 2);
  unsigned short* WpT   = (unsigned short*)alloc((size_t)1024 * 2816 * 2);
  unsigned short* eW1T  = (unsigned short*)alloc((size_t)1024 * 3456 * 2);
  unsigned short* eW2T  = (unsigned short*)alloc((size_t)256 * 1024 * 2);
  unsigned short* dhT   = (unsigned short*)alloc((size_t)1152 * 256 * 2);
  unsigned short* dW2T  = (unsigned short*)alloc((size_t)3456 * 1024 * 2);
  unsigned short* featb = (unsigned short*)alloc((size_t)2048 * 3456 * 2);
  float* Z    = (float*)alloc((size_t)2048 * 3456 * 4);
  float* P0   = (float*)alloc((size_t)2048 * 1152 * 4);
  float* P1   = (float*)alloc((size_t)2048 * 1152 * 4);
  float* P2   = (float*)alloc((size_t)2048 * 1152 * 4);
  unsigned short* h1b  = (unsigned short*)alloc((size_t)2048 * 1024 * 2);
  unsigned short* encb = (unsigned short*)alloc((size_t)2048 * 256 * 2);
  unsigned short* h3b  = (unsigned short*)alloc((size_t)2048 * 1024 * 2);

  // ---- GCN prep (merged launches) ----
  init_all<<<CDIV(34560,256),256,0,stream>>>(iz, 23200, deg, 15000, stats, 34560);
  prep_b<<<CDIV(90536,256),256,0,stream>>>(d_ei, d_ew, deg_d, p_ei, p_ew, deg_p,
                                           d_index, flag_d, p_index, flag_p);
  prep_c<<<CDIV(15000,256),256,0,stream>>>(deg, 15000, flag_d, ctr, slotnode_d,
                                           flag_p, ctr + 1, slotnode_p);
  prep_d<<<CDIV(90536,256),256,0,stream>>>(d_index, flag_d, ridx_d, p_index, flag_p, ridx_p,
                                           d_ei, cnt_d, p_ei, cnt_p);
  scan2048x2<<<2,256,0,stream>>>(cnt_d, rowptr_d, cnt_p, rowptr_p);
  fill_edges2<<<CDIV(90536,256),256,0,stream>>>(
      d_ei, d_ew, deg_d, flag_d, rowptr_d, fill_d, em_d,
      p_ei, p_ew, deg_p, flag_p, rowptr_p, fill_p, em_p);
  gather_agg5b<<<7680,256,0,stream>>>(
      d_ecfps, deg_d, slotnode_d, rowptr_d, em_d, ctr, aggd_b,
      p_gos,   deg_p, slotnode_p, rowptr_p, em_p, ctr + 1, aggp_b);

  // ---- all weight transposes in one launch ----
  transposeAll<<<11296, dim3(32,8), 0, stream>>>(
      d_gcn_W, WdT, p_gcn_W, WpT, enc_W1, eW1T, enc_W2, eW2T,
      dec_W1, dhT, out_W1, dhT + (size_t)1024 * 256, dec_W2, dW2T);

  // ---- GCN GEMMs: dbuf 128^2, d splitK x2 + p splitK x2 (512 blocks) ----
  {
    GA gd0{aggd_b,        WdT,        Z,  ridx_d, nullptr, nullptr, 1024,  512, 1024, 1024};
    GA gd1{aggd_b + 512,  WdT + 512,  P0, ridx_d, nullptr, nullptr, 1024,  512, 1024, 1024};
    GA gp0{aggp_b,        WpT,        P1, ridx_p, nullptr, nullptr, 1024, 1408, 2816, 2816};
    GA gp1{aggp_b + 1408, WpT + 1408, P2, ridx_p, nullptr, nullptr, 1024, 1408, 2816, 2816};
    gemm128z<<<dim3(16,8,4),256,0,stream>>>(gd0, gd1, gp0, gp1);
  }
  apply_feat<<<CDIV(2*2048*256 + 2048*352,256),256,0,stream>>>(
      Z, P0, d_gcn_b, P1, P2, p_gcn_b, d_vecs, p_emb, feat_out, featb);

  // ---- encoder L1: dbuf 128^2, split-K x3 (384 blocks) ----
  {
    GA e0{featb,        eW1T,        Z,  nullptr, nullptr, nullptr, 1024, 1152, 3456, 3456};
    GA e1{featb + 1152, eW1T + 1152, P0, nullptr, nullptr, nullptr, 1024, 1152, 3456, 3456};
    GA e2{featb + 2304, eW1T + 2304, P1, nullptr, nullptr, nullptr, 1024, 1152, 3456, 3456};
    gemm128z<<<dim3(16,8,3),256,0,stream>>>(e0, e1, e2, e0);
  }
  colstats4<<<dim3(1,128),256,0,stream>>>(Z, P0, P1, 1024, 1024, cs_e1, cq_e1);
  apply_bn4<<<CDIV(2048*256,256),256,0,stream>>>(Z, P0, P1, 1024, 2048*256, 256,
      cs_e1, cq_e1, enc_g1, enc_be1, 0, nullptr, 0, h1b, 1024);

  // ---- encoder L2: split-K x2 -> encoded (64-tile dbuf) ----
  {
    GA e0{h1b,       eW2T,       Z,  nullptr, nullptr, nullptr, 256, 512, 1024, 1024};
    GA e1{h1b + 512, eW2T + 512, P0, nullptr, nullptr, nullptr, 256, 512, 1024, 1024};
    gemm64s<<<dim3(32,2,2),256,0,stream>>>(e0, e1, e0, e0);
  }
  colstats4<<<dim3(1,128),256,0,stream>>>(Z, P0, nullptr, 256, 256, cs_e2, cq_e2);
  apply_bn4<<<CDIV(2048*64,256),256,0,stream>>>(Z, P0, nullptr, 256, 2048*64, 64,
      cs_e2, cq_e2, enc_g2, enc_be2, 0, enc_out, 256, encb, 256);

  // ---- decoder L1 + head GEMM with FUSED stats (288 blocks, no split-K) ----
  {
    GA g0{encb, dhT, Z, nullptr, cs_d1, cq_d1, 1152, 256, 256, 256};
    gemm64s<<<dim3(32,9,1),256,0,stream>>>(g0, g0, g0, g0);
  }
  apply_bn4<<<CDIV(2048*256,256),256,0,stream>>>(Z, nullptr, nullptr, 1152, 2048*256, 256,
      cs_d1, cq_d1, dec_g1, dec_be1, 0, nullptr, 0, h3b, 1024);
  head_fused<<<8,256,0,stream>>>(Z + 1024, 1152, cs_d1 + 1024, cq_d1 + 1024,
                                 out_g1, out_be1, out_W2, out_b2, y_out);

  // ---- decoder L2: fused GEMM+stats+barrier+BN apply (432 blocks, 2/CU) ----
  {
    GA g0{h3b, dW2T, nullptr, nullptr, cs_d2, cq_d2, 3456, 1024, 1024, 1024};
    gemm128_bn<<<dim3(16,27),256,0,stream>>>(g0, dec_g2, dec_be2, dec_out, 3372,
                                             432, done_ctr);
  }
}

// Round 18
// 280.991 us; speedup vs baseline: 1.2041x; 1.2041x over previous
//
#include <hip/hip_runtime.h>

#define CDIV(a,b) (((a)+(b)-1)/(b))

typedef __attribute__((ext_vector_type(8))) short bf16x8;
typedef __attribute__((ext_vector_type(4))) float f32x4;

__device__ __forceinline__ unsigned short f2b(float v) {
  union { float f; unsigned u; } x; x.f = v;
  unsigned r = x.u + 0x7FFFu + ((x.u >> 16) & 1u);
  return (unsigned short)(r >> 16);
}

__device__ __forceinline__ void gload_lds16(const void* g, void* l) {
  __builtin_amdgcn_global_load_lds(
      (const __attribute__((address_space(1))) unsigned int*)(g),
      (__attribute__((address_space(3))) unsigned int*)(l), 16, 0, 0);
}

struct GA {
  const unsigned short* A;
  const unsigned short* B;
  float* C;
  const int* ridx;
  float* csum;      // non-null => fused column stats (REQUIRES no split-K)
  float* csumsq;
  int N, K, lda, ldb;
};

// ---- 128x128 MFMA GEMM, dbuf LDS + counted vmcnt, XOR-swizzled, optional
// A-row indirection + optional fused column stats; z selects operand set.
__global__ __launch_bounds__(256) void gemm128z(GA g0, GA g1, GA g2, GA g3) {
  __shared__ __align__(16) unsigned short As[2][128 * 64];
  __shared__ __align__(16) unsigned short Bs[2][128 * 64];
  const int z = blockIdx.z;
  GA g = (z == 0) ? g0 : (z == 1) ? g1 : (z == 2) ? g2 : g3;

  const int tid = threadIdx.x;
  const int lane = tid & 63;
  const int wid = tid >> 6;
  const int wm = (wid >> 1) * 64;
  const int wn = (wid & 1) * 64;
  const long bm = (long)blockIdx.x * 128;
  const long bn = (long)blockIdx.y * 128;

  f32x4 acc[4][4] = {};

  const int lr = tid >> 3;
  const int lc = (((tid & 7) ^ (lr & 7)) * 8);

  const unsigned short* ap[4];
  const unsigned short* bp[4];
#pragma unroll
  for (int i = 0; i < 4; ++i) {
    long row = bm + i * 32 + lr;
    long arow = g.ridx ? (long)g.ridx[row] : row;
    ap[i] = g.A + arow * g.lda + lc;
    bp[i] = g.B + (bn + i * 32 + lr) * (long)g.ldb + lc;
  }

  const int rsel = lane & 15;
  const int rx = rsel & 7;

  auto STAGE = [&](int buf, int k0) {
#pragma unroll
    for (int i = 0; i < 4; ++i) {
      const int eoff = (i * 256 + tid) * 8;
      gload_lds16(ap[i] + k0, &As[buf][eoff]);
      gload_lds16(bp[i] + k0, &Bs[buf][eoff]);
    }
  };
  auto COMPUTE = [&](int buf) {
#pragma unroll
    for (int kk = 0; kk < 2; ++kk) {
      const int koz = (((kk * 4 + (lane >> 4)) ^ rx) << 3);
      bf16x8 av[4], bv[4];
#pragma unroll
      for (int m = 0; m < 4; ++m)
        av[m] = *(const bf16x8*)(&As[buf][(wm + m * 16 + rsel) * 64 + koz]);
#pragma unroll
      for (int n = 0; n < 4; ++n)
        bv[n] = *(const bf16x8*)(&Bs[buf][(wn + n * 16 + rsel) * 64 + koz]);
#pragma unroll
      for (int m = 0; m < 4; ++m)
#pragma unroll
        for (int n = 0; n < 4; ++n)
          acc[m][n] = __builtin_amdgcn_mfma_f32_16x16x32_bf16(av[m], bv[n], acc[m][n], 0, 0, 0);
    }
  };

  STAGE(0, 0);
  int cur = 0;
  for (int k0 = 64; k0 < g.K; k0 += 64) {
    STAGE(cur ^ 1, k0);
    asm volatile("s_waitcnt vmcnt(8)" ::: "memory");
    __builtin_amdgcn_s_barrier();
    asm volatile("" ::: "memory");
    COMPUTE(cur);
    asm volatile("" ::: "memory");
    __builtin_amdgcn_s_barrier();
    cur ^= 1;
  }
  asm volatile("s_waitcnt vmcnt(0)" ::: "memory");
  __builtin_amdgcn_s_barrier();
  asm volatile("" ::: "memory");
  COMPUTE(cur);

  const int crow0 = (lane >> 4) * 4;
  const int ccol = lane & 15;
#pragma unroll
  for (int m = 0; m < 4; ++m)
#pragma unroll
    for (int n = 0; n < 4; ++n) {
      const long r = bm + wm + m * 16 + crow0;
      const long c = bn + wn + n * 16 + ccol;
#pragma unroll
      for (int q = 0; q < 4; ++q)
        g.C[(r + q) * (long)g.N + c] = acc[m][n][q];
    }

  if (g.csum) {
#pragma unroll
    for (int n = 0; n < 4; ++n) {
      float s = 0.f, s2 = 0.f;
#pragma unroll
      for (int m = 0; m < 4; ++m)
#pragma unroll
        for (int q = 0; q < 4; ++q) {
          float v = acc[m][n][q];
          s += v; s2 += v * v;
        }
      s  += __shfl_xor(s, 16);  s  += __shfl_xor(s, 32);
      s2 += __shfl_xor(s2, 16); s2 += __shfl_xor(s2, 32);
      if ((lane >> 4) == 0) {
        const long c = bn + wn + n * 16 + ccol;
        atomicAdd(&g.csum[c], s);
        atomicAdd(&g.csumsq[c], s2);
      }
    }
  }
}

// ---- 64x128 MFMA GEMM, dbuf + counted vmcnt, swizzled, optional fused stats
__global__ __launch_bounds__(256) void gemm64s(GA g0, GA g1, GA g2, GA g3) {
  __shared__ __align__(16) unsigned short As[2][64 * 64];
  __shared__ __align__(16) unsigned short Bs[2][128 * 64];
  const int z = blockIdx.z;
  GA g = (z == 0) ? g0 : (z == 1) ? g1 : (z == 2) ? g2 : g3;

  const int tid = threadIdx.x;
  const int lane = tid & 63;
  const int wid = tid >> 6;
  const int wn = wid * 32;
  const long bm = (long)blockIdx.x * 64;
  const long bn = (long)blockIdx.y * 128;

  f32x4 acc[4][2] = {};

  const int lr = tid >> 3;
  const int lc = (((tid & 7) ^ (lr & 7)) * 8);

  const long r0 = g.ridx ? (long)g.ridx[bm + lr] : bm + lr;
  const long r1 = g.ridx ? (long)g.ridx[bm + 32 + lr] : bm + 32 + lr;
  const unsigned short* ap0 = g.A + r0 * g.lda + lc;
  const unsigned short* ap1 = g.A + r1 * g.lda + lc;
  const unsigned short* bp0 = g.B + (bn + lr) * (long)g.ldb + lc;
  const unsigned short* bp1 = g.B + (bn + 32 + lr) * (long)g.ldb + lc;
  const unsigned short* bp2 = g.B + (bn + 64 + lr) * (long)g.ldb + lc;
  const unsigned short* bp3 = g.B + (bn + 96 + lr) * (long)g.ldb + lc;

  const int rsel = lane & 15;
  const int rx = rsel & 7;

  auto STAGE = [&](int buf, int k0) {
    gload_lds16(ap0 + k0, &As[buf][tid * 8]);
    gload_lds16(ap1 + k0, &As[buf][(256 + tid) * 8]);
    gload_lds16(bp0 + k0, &Bs[buf][tid * 8]);
    gload_lds16(bp1 + k0, &Bs[buf][(256 + tid) * 8]);
    gload_lds16(bp2 + k0, &Bs[buf][(512 + tid) * 8]);
    gload_lds16(bp3 + k0, &Bs[buf][(768 + tid) * 8]);
  };
  auto COMPUTE = [&](int buf) {
#pragma unroll
    for (int kk = 0; kk < 2; ++kk) {
      const int koz = (((kk * 4 + (lane >> 4)) ^ rx) << 3);
      bf16x8 av[4], bv[2];
#pragma unroll
      for (int m = 0; m < 4; ++m)
        av[m] = *(const bf16x8*)(&As[buf][(m * 16 + rsel) * 64 + koz]);
#pragma unroll
      for (int n = 0; n < 2; ++n)
        bv[n] = *(const bf16x8*)(&Bs[buf][(wn + n * 16 + rsel) * 64 + koz]);
#pragma unroll
      for (int m = 0; m < 4; ++m)
#pragma unroll
        for (int n = 0; n < 2; ++n)
          acc[m][n] = __builtin_amdgcn_mfma_f32_16x16x32_bf16(av[m], bv[n], acc[m][n], 0, 0, 0);
    }
  };

  STAGE(0, 0);
  int cur = 0;
  for (int k0 = 64; k0 < g.K; k0 += 64) {
    STAGE(cur ^ 1, k0);
    asm volatile("s_waitcnt vmcnt(6)" ::: "memory");
    __builtin_amdgcn_s_barrier();
    asm volatile("" ::: "memory");
    COMPUTE(cur);
    asm volatile("" ::: "memory");
    __builtin_amdgcn_s_barrier();
    cur ^= 1;
  }
  asm volatile("s_waitcnt vmcnt(0)" ::: "memory");
  __builtin_amdgcn_s_barrier();
  asm volatile("" ::: "memory");
  COMPUTE(cur);

  const int crow0 = (lane >> 4) * 4;
  const int ccol = lane & 15;
#pragma unroll
  for (int m = 0; m < 4; ++m)
#pragma unroll
    for (int n = 0; n < 2; ++n) {
      const long r = bm + m * 16 + crow0;
      const long c = bn + wn + n * 16 + ccol;
#pragma unroll
      for (int q = 0; q < 4; ++q)
        g.C[(r + q) * (long)g.N + c] = acc[m][n][q];
    }

  if (g.csum) {
#pragma unroll
    for (int n = 0; n < 2; ++n) {
      float s = 0.f, s2 = 0.f;
#pragma unroll
      for (int m = 0; m < 4; ++m)
#pragma unroll
        for (int q = 0; q < 4; ++q) {
          float v = acc[m][n][q];
          s += v; s2 += v * v;
        }
      s  += __shfl_xor(s, 16);  s  += __shfl_xor(s, 32);
      s2 += __shfl_xor(s2, 16); s2 += __shfl_xor(s2, 32);
      if ((lane >> 4) == 0) {
        const long c = bn + wn + n * 16 + ccol;
        atomicAdd(&g.csum[c], s);
        atomicAdd(&g.csumsq[c], s2);
      }
    }
  }
}

// ---------------- merged prep kernels ----------------
__global__ void init_all(int* iz, int nIz, float* deg, int nDeg,
                         float* stats, int nStats) {
  int i = blockIdx.x * 256 + threadIdx.x;
  if (i < nIz) iz[i] = 0;
  if (i < nDeg) deg[i] = 1.f;
  if (i < nStats) stats[i] = 0.f;
}

__global__ void prep_b(const int* __restrict__ d_ei, const float* __restrict__ d_ew,
                       float* __restrict__ deg_d,
                       const int* __restrict__ p_ei, const float* __restrict__ p_ew,
                       float* __restrict__ deg_p,
                       const int* __restrict__ d_index, int* __restrict__ flag_d,
                       const int* __restrict__ p_index, int* __restrict__ flag_p) {
  int e = blockIdx.x * 256 + threadIdx.x;
  if (e < 65536) atomicAdd(&deg_d[d_ei[65536 + e]], d_ew[e]);
  int e2 = e - 65536;
  if (e2 >= 0 && e2 < 25000) atomicAdd(&deg_p[p_ei[25000 + e2]], p_ew[e2]);
  if (e < 2048) flag_d[d_index[e]] = 1;
  else if (e < 4096) flag_p[p_index[e - 2048]] = 1;
}

__global__ void prep_c(float* __restrict__ deg, int nDeg,
                       int* __restrict__ flag_d, int* __restrict__ ctr_d,
                       int* __restrict__ slot_d,
                       int* __restrict__ flag_p, int* __restrict__ ctr_p,
                       int* __restrict__ slot_p) {
  int i = blockIdx.x * 256 + threadIdx.x;
  if (i < nDeg) deg[i] = rsqrtf(deg[i]);
  if (i < 10000) {
    if (flag_d[i]) { int s = atomicAdd(ctr_d, 1); flag_d[i] = s + 1; slot_d[s] = i; }
  } else if (i < 15000) {
    int j = i - 10000;
    if (flag_p[j]) { int s = atomicAdd(ctr_p, 1); flag_p[j] = s + 1; slot_p[s] = j; }
  }
}

__global__ void prep_d(const int* __restrict__ d_index, const int* __restrict__ flag_d,
                       int* __restrict__ ridx_d,
                       const int* __restrict__ p_index, const int* __restrict__ flag_p,
                       int* __restrict__ ridx_p,
                       const int* __restrict__ d_ei, int* __restrict__ cnt_d,
                       const int* __restrict__ p_ei, int* __restrict__ cnt_p) {
  int e = blockIdx.x * 256 + threadIdx.x;
  if (e < 2048) ridx_d[e] = flag_d[d_index[e]] - 1;
  else if (e < 4096) { int j = e - 2048; ridx_p[j] = flag_p[p_index[j]] - 1; }
  if (e < 65536) { int s = flag_d[d_ei[65536 + e]]; if (s) atomicAdd(&cnt_d[s - 1], 1); }
  int e2 = e - 65536;
  if (e2 >= 0 && e2 < 25000) { int s = flag_p[p_ei[25000 + e2]]; if (s) atomicAdd(&cnt_p[s - 1], 1); }
}

__global__ void scan2048x2(const int* __restrict__ cnt_d, int* __restrict__ rp_d,
                           const int* __restrict__ cnt_p, int* __restrict__ rp_p) {
  const int* cnt = blockIdx.x ? cnt_p : cnt_d;
  int* rowptr    = blockIdx.x ? rp_p : rp_d;
  __shared__ int part[256];
  int tid = threadIdx.x;
  int base = tid * 8;
  int vals[8]; int s = 0;
#pragma unroll
  for (int i = 0; i < 8; ++i) { vals[i] = s; s += cnt[base + i]; }
  part[tid] = s;
  __syncthreads();
  if (tid == 0) { int r = 0; for (int i = 0; i < 256; ++i) { int t = part[i]; part[i] = r; r += t; } }
  __syncthreads();
  int off = part[tid];
#pragma unroll
  for (int i = 0; i < 8; ++i) rowptr[base + i] = off + vals[i];
  if (tid == 255) rowptr[2048] = off + s;
}
__global__ void fill_edges2(
    const int* __restrict__ d_ei, const float* __restrict__ d_ew,
    const float* __restrict__ dinv_d, const int* __restrict__ flag_d,
    const int* __restrict__ rp_d, int* __restrict__ fill_d,
    int2* __restrict__ em_d,
    const int* __restrict__ p_ei, const float* __restrict__ p_ew,
    const float* __restrict__ dinv_p, const int* __restrict__ flag_p,
    const int* __restrict__ rp_p, int* __restrict__ fill_p,
    int2* __restrict__ em_p) {
  int e = blockIdx.x * 256 + threadIdx.x;
  if (e < 65536) {
    int dst = d_ei[65536 + e];
    int s = flag_d[dst];
    if (s) {
      int src = d_ei[e];
      int pos = rp_d[s - 1] + atomicAdd(&fill_d[s - 1], 1);
      float cf = d_ew[e] * dinv_d[src] * dinv_d[dst];
      em_d[pos] = make_int2(src, __float_as_int(cf));
    }
  }
  int e2 = e - 65536;
  if (e2 >= 0 && e2 < 25000) {
    int dst = p_ei[25000 + e2];
    int s = flag_p[dst];
    if (s) {
      int src = p_ei[e2];
      int pos = rp_p[s - 1] + atomicAdd(&fill_p[s - 1], 1);
      float cf = p_ew[e2] * dinv_p[src] * dinv_p[dst];
      em_p[pos] = make_int2(src, __float_as_int(cf));
    }
  }
}

// ---- wave-per-(slot, 64-f4 chunk) gather, 4-edge unroll, packed int2 meta.
__global__ __launch_bounds__(256) void gather_agg5b(
    const float* __restrict__ Xd, const float* __restrict__ dinv_d,
    const int* __restrict__ slot_d, const int* __restrict__ rp_d,
    const int2* __restrict__ em_d,
    const int* __restrict__ nflag_d, unsigned short* __restrict__ aggd,
    const float* __restrict__ Xp, const float* __restrict__ dinv_p,
    const int* __restrict__ slot_p, const int* __restrict__ rp_p,
    const int2* __restrict__ em_p,
    const int* __restrict__ nflag_p, unsigned short* __restrict__ aggp)
{
  const int gw = blockIdx.x * 4 + (threadIdx.x >> 6);
  const int lane = threadIdx.x & 63;

  int slot, c, Kdata4, Kst4, Kld, nflag;
  const float *X, *dinv; const int *slotn, *rp; const int2* em;
  unsigned short* agg;
  if (gw < 8192) {
    slot = gw >> 2;
    c = (gw & 3) * 64 + lane;
    X = Xd; dinv = dinv_d; slotn = slot_d; rp = rp_d; em = em_d;
    nflag = *nflag_d; agg = aggd; Kdata4 = 256; Kst4 = 256; Kld = 1024;
  } else {
    int q = gw - 8192;
    slot = q / 11;
    c = (q - slot * 11) * 64 + lane;
    X = Xp; dinv = dinv_p; slotn = slot_p; rp = rp_p; em = em_p;
    nflag = *nflag_p; agg = aggp; Kdata4 = 703; Kst4 = 704; Kld = 2812;
  }
  if (slot >= nflag) return;

  const int n = slotn[slot];
  const float dn = dinv[n];
  const float selfc = dn * dn;
  const int e0 = rp[slot], e1 = rp[slot + 1];
  const bool valid = c < Kdata4;

  float ax = 0.f, ay = 0.f, az = 0.f, aw = 0.f;
  if (valid) {
    float4 v = *(const float4*)(X + (long)n * Kld + 4 * c);
    ax = selfc * v.x; ay = selfc * v.y; az = selfc * v.z; aw = selfc * v.w;
  }

  int e = e0;
  for (; e + 4 <= e1; e += 4) {
    const int2 m0 = em[e], m1 = em[e + 1], m2 = em[e + 2], m3 = em[e + 3];
    if (valid) {
      float4 v0 = *(const float4*)(X + (long)m0.x * Kld + 4 * c);
      float4 v1 = *(const float4*)(X + (long)m1.x * Kld + 4 * c);
      float4 v2 = *(const float4*)(X + (long)m2.x * Kld + 4 * c);
      float4 v3 = *(const float4*)(X + (long)m3.x * Kld + 4 * c);
      const float c0 = __int_as_float(m0.y), c1 = __int_as_float(m1.y);
      const float c2 = __int_as_float(m2.y), c3 = __int_as_float(m3.y);
      ax += c0 * v0.x; ay += c0 * v0.y; az += c0 * v0.z; aw += c0 * v0.w;
      ax += c1 * v1.x; ay += c1 * v1.y; az += c1 * v1.z; aw += c1 * v1.w;
      ax += c2 * v2.x; ay += c2 * v2.y; az += c2 * v2.z; aw += c2 * v2.w;
      ax += c3 * v3.x; ay += c3 * v3.y; az += c3 * v3.z; aw += c3 * v3.w;
    }
  }
  for (; e < e1; ++e) {
    const int2 m = em[e];
    if (valid) {
      float4 v = *(const float4*)(X + (long)m.x * Kld + 4 * c);
      const float cf = __int_as_float(m.y);
      ax += cf * v.x; ay += cf * v.y; az += cf * v.z; aw += cf * v.w;
    }
  }

  if (c < Kst4) {
    ushort4 o; o.x = f2b(ax); o.y = f2b(ay); o.z = f2b(az); o.w = f2b(aw);
    *(ushort4*)(agg + (long)slot * (Kst4 * 4) + 4 * c) = o;
  }
}

// ---- all 7 weight transposes in one flattened launch ----
__global__ void transposeAll(
    const float* W0, unsigned short* T0,
    const float* W1, unsigned short* T1,
    const float* W2, unsigned short* T2,
    const float* W3, unsigned short* T3,
    const float* W4, unsigned short* T4,
    const float* W5, unsigned short* T5,
    const float* W6, unsigned short* T6)
{
  __shared__ float tile[32][33];
  int bid = blockIdx.x;
  const float* W; unsigned short* Wt; int K, N, Kp, Np_, tx, local;
  if      (bid <  1024) { W=W0; Wt=T0; K=1024; N=1024; Kp=1024; Np_=1024; tx=32;  local=bid; }
  else if (bid <  3840) { W=W1; Wt=T1; K=2812; N=1024; Kp=2816; Np_=1024; tx=88;  local=bid-1024; }
  else if (bid <  7296) { W=W2; Wt=T2; K=3372; N=1024; Kp=3456; Np_=1024; tx=108; local=bid-3840; }
  else if (bid <  7552) { W=W3; Wt=T3; K=1024; N=256;  Kp=1024; Np_=256;  tx=32;  local=bid-7296; }
  else if (bid <  7808) { W=W4; Wt=T4; K=256;  N=1024; Kp=256;  Np_=1024; tx=8;   local=bid-7552; }
  else if (bid <  7840) { W=W5; Wt=T5; K=256;  N=64;   Kp=256;  Np_=128;  tx=8;   local=bid-7808; }
  else                  { W=W6; Wt=T6; K=1024; N=3372; Kp=1024; Np_=3456; tx=32;  local=bid-7840; }
  int k0 = (local % tx) * 32, n0 = (local / tx) * 32;
  for (int i = threadIdx.y; i < 32; i += 8) {
    int k = k0 + i, n = n0 + threadIdx.x;
    tile[i][threadIdx.x] = (k < K && n < N) ? W[(size_t)k * N + n] : 0.f;
  }
  __syncthreads();
  for (int i = threadIdx.y; i < 32; i += 8) {
    int n = n0 + i, k = k0 + threadIdx.x;
    if (n < Np_ && k < Kp) Wt[(size_t)n * Kp + k] = f2b(tile[threadIdx.x][i]);
  }
}

// vectorized colstats (for split-K layers only)
__global__ void colstats4(const float* __restrict__ Z, const float* __restrict__ Z2,
                          const float* __restrict__ Z3, int ldz, int cols,
                          float* __restrict__ csum, float* __restrict__ csumsq) {
  int c4 = blockIdx.x * 256 + threadIdx.x;
  if (c4 * 4 >= cols) return;
  int r0 = blockIdx.y * 16;
  float sx = 0.f, sy = 0.f, sz_ = 0.f, sw = 0.f;
  float qx = 0.f, qy = 0.f, qz = 0.f, qw = 0.f;
  for (int r = r0; r < r0 + 16; ++r) {
    float4 v = *(const float4*)(Z + (long)r * ldz + 4 * c4);
    if (Z2) { float4 w = *(const float4*)(Z2 + (long)r * ldz + 4 * c4);
              v.x += w.x; v.y += w.y; v.z += w.z; v.w += w.w; }
    if (Z3) { float4 w = *(const float4*)(Z3 + (long)r * ldz + 4 * c4);
              v.x += w.x; v.y += w.y; v.z += w.z; v.w += w.w; }
    sx += v.x; sy += v.y; sz_ += v.z; sw += v.w;
    qx += v.x * v.x; qy += v.y * v.y; qz += v.z * v.z; qw += v.w * v.w;
  }
  atomicAdd(&csum[4 * c4 + 0], sx); atomicAdd(&csum[4 * c4 + 1], sy);
  atomicAdd(&csum[4 * c4 + 2], sz_); atomicAdd(&csum[4 * c4 + 3], sw);
  atomicAdd(&csumsq[4 * c4 + 0], qx); atomicAdd(&csumsq[4 * c4 + 1], qy);
  atomicAdd(&csumsq[4 * c4 + 2], qz); atomicAdd(&csumsq[4 * c4 + 3], qw);
}

// apply with INLINE bn-finalize. csum==null -> bias-only.
__global__ void apply_bn4(const float* __restrict__ Z, const float* __restrict__ Z2,
                          const float* __restrict__ Z3,
                          int ldz, int total4, int cols4,
                          const float* __restrict__ csum, const float* __restrict__ csumsq,
                          const float* __restrict__ g, const float* __restrict__ beta,
                          int leaky,
                          float* __restrict__ f32out, int ldf,
                          unsigned short* __restrict__ b16out, int ldb) {
  int idx = blockIdx.x*256+threadIdx.x;
  if (idx >= total4) return;
  int b = idx / cols4, j = (idx % cols4) * 4;
  float4 v = *(const float4*)(Z + (long)b * ldz + j);
  if (Z2) { float4 w = *(const float4*)(Z2 + (long)b * ldz + j);
            v.x += w.x; v.y += w.y; v.z += w.z; v.w += w.w; }
  if (Z3) { float4 w = *(const float4*)(Z3 + (long)b * ldz + j);
            v.x += w.x; v.y += w.y; v.z += w.z; v.w += w.w; }
  if (csum) {
    const float invB = 1.f / 2048.f;
    float4 cs = *(const float4*)(csum + j);
    float4 cq = *(const float4*)(csumsq + j);
    float4 gg = *(const float4*)(g + j);
    float4 bb = *(const float4*)(beta + j);
    float m, var, sc;
    m = cs.x * invB; var = fmaxf(cq.x * invB - m * m, 0.f);
    sc = gg.x * rsqrtf(var + 1e-5f); v.x = v.x * sc + (bb.x - m * sc);
    m = cs.y * invB; var = fmaxf(cq.y * invB - m * m, 0.f);
    sc = gg.y * rsqrtf(var + 1e-5f); v.y = v.y * sc + (bb.y - m * sc);
    m = cs.z * invB; var = fmaxf(cq.z * invB - m * m, 0.f);
    sc = gg.z * rsqrtf(var + 1e-5f); v.z = v.z * sc + (bb.z - m * sc);
    m = cs.w * invB; var = fmaxf(cq.w * invB - m * m, 0.f);
    sc = gg.w * rsqrtf(var + 1e-5f); v.w = v.w * sc + (bb.w - m * sc);
  } else {
    float4 bb = *(const float4*)(beta + j);
    v.x += bb.x; v.y += bb.y; v.z += bb.z; v.w += bb.w;
  }
  const float neg = leaky ? 0.01f : 0.f;
  v.x = (v.x >= 0.f) ? v.x : neg * v.x;
  v.y = (v.y >= 0.f) ? v.y : neg * v.y;
  v.z = (v.z >= 0.f) ? v.z : neg * v.z;
  v.w = (v.w >= 0.f) ? v.w : neg * v.w;
  if (f32out) *(float4*)(f32out + (long)b * ldf + j) = v;
  if (b16out) {
    ushort4 o; o.x = f2b(v.x); o.y = f2b(v.y); o.z = f2b(v.z); o.w = f2b(v.w);
    *(ushort4*)(b16out + (long)b * ldb + j) = o;
  }
}

// GCN applies (f4) + feat copy (f4) + pad in one launch.
__global__ void apply_feat(const float* __restrict__ Zd, const float* __restrict__ Pd,
                           const float* __restrict__ bd,
                           const float* __restrict__ Zp, const float* __restrict__ Pp,
                           const float* __restrict__ bp,
                           const float* __restrict__ dv, const float* __restrict__ pe,
                           float* __restrict__ feat_f32, unsigned short* __restrict__ feat_b16) {
  int idx = blockIdx.x*256+threadIdx.x;
  const int APPLY_N = 2 * 2048 * 256;
  if (idx < APPLY_N) {
    const bool isP = idx >= 2048 * 256;
    int l = isP ? idx - 2048 * 256 : idx;
    int b = l >> 8, j = (l & 255) * 4;
    const float* Z = isP ? Zp : Zd;
    const float* P = isP ? Pp : Pd;
    const float* bias = isP ? bp : bd;
    const int coloff = isP ? 2348 : 1324;
    float4 v = *(const float4*)(Z + (long)b * 1024 + j);
    float4 w = *(const float4*)(P + (long)b * 1024 + j);
    float4 bb = *(const float4*)(bias + j);
    v.x += w.x + bb.x; v.y += w.y + bb.y; v.z += w.z + bb.z; v.w += w.w + bb.w;
    v.x = (v.x >= 0.f) ? v.x : 0.01f * v.x;
    v.y = (v.y >= 0.f) ? v.y : 0.01f * v.y;
    v.z = (v.z >= 0.f) ? v.z : 0.01f * v.z;
    v.w = (v.w >= 0.f) ? v.w : 0.01f * v.w;
    *(float4*)(feat_f32 + (long)b * 3372 + coloff + j) = v;
    ushort4 o; o.x = f2b(v.x); o.y = f2b(v.y); o.z = f2b(v.z); o.w = f2b(v.w);
    *(ushort4*)(feat_b16 + (long)b * 3456 + coloff + j) = o;
    return;
  }
  int q = idx - APPLY_N;
  if (q >= 2048 * 352) return;
  int b = q / 352, u = q % 352;
  if (u < 331) {
    int c = u * 4;
    float4 v;
    if (u < 75) v = *(const float4*)(dv + (long)b * 300 + c);
    else        v = *(const float4*)(pe + (long)b * 1024 + (c - 300));
    *(float4*)(feat_f32 + (long)b * 3372 + c) = v;
    ushort4 o; o.x = f2b(v.x); o.y = f2b(v.y); o.z = f2b(v.z); o.w = f2b(v.w);
    *(ushort4*)(feat_b16 + (long)b * 3456 + c) = o;
  } else {
    int c = 3372 + (u - 331) * 4;
    ushort4 o; o.x = 0; o.y = 0; o.z = 0; o.w = 0;
    *(ushort4*)(feat_b16 + (long)b * 3456 + c) = o;
  }
}

// head: bn(inline stats) + lrelu + dot(W2) + b2 -> y
__global__ void head_fused(const float* __restrict__ Z, int ldz,
                           const float* __restrict__ csum, const float* __restrict__ csumsq,
                           const float* __restrict__ g, const float* __restrict__ beta,
                           const float* __restrict__ W2, const float* __restrict__ b2,
                           float* __restrict__ y) {
  int b = blockIdx.x*256+threadIdx.x;
  if (b >= 2048) return;
  const float invB = 1.f / 2048.f;
  float s = b2[0];
  for (int k = 0; k < 64; ++k) {
    float m = csum[k] * invB;
    float var = fmaxf(csumsq[k] * invB - m * m, 0.f);
    float sc = g[k] * rsqrtf(var + 1e-5f);
    float sh = beta[k] - m * sc;
    float v = Z[(long)b * ldz + k];
    v = v * sc + sh;
    v = (v >= 0.f) ? v : 0.01f * v;
    s += v * W2[k];
  }
  y[b] = s;
}

extern "C" void kernel_launch(void* const* d_in, const int* in_sizes, int n_in,
                              void* d_out, int out_size, void* d_ws, size_t ws_size,
                              hipStream_t stream) {
  (void)in_sizes; (void)n_in; (void)out_size; (void)ws_size;
  const int*   d_index = (const int*)d_in[0];
  const int*   p_index = (const int*)d_in[1];
  const float* d_vecs  = (const float*)d_in[2];
  const float* p_emb   = (const float*)d_in[3];
  const float* d_ecfps = (const float*)d_in[4];
  const int*   d_ei    = (const int*)d_in[5];
  const float* d_ew    = (const float*)d_in[6];
  const float* p_gos   = (const float*)d_in[7];
  const int*   p_ei    = (const int*)d_in[8];
  const float* p_ew    = (const float*)d_in[9];
  const float* d_gcn_W = (const float*)d_in[10];
  const float* d_gcn_b = (const float*)d_in[11];
  const float* p_gcn_W = (const float*)d_in[12];
  const float* p_gcn_b = (const float*)d_in[13];
  const float* enc_W1  = (const float*)d_in[14];
  const float* enc_g1  = (const float*)d_in[16];
  const float* enc_be1 = (const float*)d_in[17];
  const float* enc_W2  = (const float*)d_in[18];
  const float* enc_g2  = (const float*)d_in[20];
  const float* enc_be2 = (const float*)d_in[21];
  const float* dec_W1  = (const float*)d_in[22];
  const float* dec_g1  = (const float*)d_in[24];
  const float* dec_be1 = (const float*)d_in[25];
  const float* dec_W2  = (const float*)d_in[26];
  const float* dec_g2  = (const float*)d_in[28];
  const float* dec_be2 = (const float*)d_in[29];
  const float* out_W1  = (const float*)d_in[30];
  const float* out_g1  = (const float*)d_in[32];
  const float* out_be1 = (const float*)d_in[33];
  const float* out_W2  = (const float*)d_in[34];
  const float* out_b2  = (const float*)d_in[35];

  float* out = (float*)d_out;
  float* y_out    = out;
  float* enc_out  = out + 2048;
  float* dec_out  = out + 526336;
  float* feat_out = out + 7432192;

  char* ws = (char*)d_ws;
  size_t off = 0;
  auto alloc = [&](size_t bytes) {
    size_t o = off; off = (off + bytes + 255) & ~(size_t)255; return (void*)(ws + o);
  };
  int* iz = (int*)alloc((size_t)23200 * 4);
  int* flag_d = iz;
  int* flag_p = iz + 10000;
  int* cnt_d  = iz + 15000;
  int* cnt_p  = iz + 17048;
  int* fill_d = iz + 19096;
  int* fill_p = iz + 21144;
  int* ctr    = iz + 23192;
  int* slotnode_d = (int*)alloc(2048 * 4);
  int* slotnode_p = (int*)alloc(2048 * 4);
  int* rowptr_d = (int*)alloc(2049 * 4);
  int* rowptr_p = (int*)alloc(2049 * 4);
  int* ridx_d = (int*)alloc(2048 * 4);
  int* ridx_p = (int*)alloc(2048 * 4);
  int2* em_d = (int2*)alloc((size_t)65536 * 8);
  int2* em_p = (int2*)alloc((size_t)25000 * 8);
  float* deg   = (float*)alloc((size_t)15000 * 4);
  float* deg_d = deg;
  float* deg_p = deg + 10000;
  float* stats = (float*)alloc((size_t)34560 * 4);
  float* cs_e1 = stats,         * cq_e1 = stats + 3456;
  float* cs_e2 = stats + 6912,  * cq_e2 = stats + 10368;
  float* cs_d1 = stats + 13824, * cq_d1 = stats + 17280;
  float* cs_d2 = stats + 27648, * cq_d2 = stats + 31104;
  unsigned short* aggd_b = (unsigned short*)alloc((size_t)2048 * 1024 * 2);
  unsigned short* aggp_b = (unsigned short*)alloc((size_t)2048 * 2816 * 2);
  unsigned short* WdT   = (unsigned short*)alloc((size_t)1024 * 1024 * 2);
  unsigned short* WpT   = (unsigned short*)alloc((size_t)1024 * 2816 * 2);
  unsigned short* eW1T  = (unsigned short*)alloc((size_t)1024 * 3456 * 2);
  unsigned short* eW2T  = (unsigned short*)alloc((size_t)256 * 1024 * 2);
  unsigned short* dhT   = (unsigned short*)alloc((size_t)1152 * 256 * 2);
  unsigned short* dW2T  = (unsigned short*)alloc((size_t)3456 * 1024 * 2);
  unsigned short* featb = (unsigned short*)alloc((size_t)2048 * 3456 * 2);
  float* Z    = (float*)alloc((size_t)2048 * 3456 * 4);
  float* P0   = (float*)alloc((size_t)2048 * 1152 * 4);
  float* P1   = (float*)alloc((size_t)2048 * 1152 * 4);
  float* P2   = (float*)alloc((size_t)2048 * 1152 * 4);
  unsigned short* h1b  = (unsigned short*)alloc((size_t)2048 * 1024 * 2);
  unsigned short* encb = (unsigned short*)alloc((size_t)2048 * 256 * 2);
  unsigned short* h3b  = (unsigned short*)alloc((size_t)2048 * 1024 * 2);

  // ---- GCN prep (merged launches) ----
  init_all<<<CDIV(34560,256),256,0,stream>>>(iz, 23200, deg, 15000, stats, 34560);
  prep_b<<<CDIV(90536,256),256,0,stream>>>(d_ei, d_ew, deg_d, p_ei, p_ew, deg_p,
                                           d_index, flag_d, p_index, flag_p);
  prep_c<<<CDIV(15000,256),256,0,stream>>>(deg, 15000, flag_d, ctr, slotnode_d,
                                           flag_p, ctr + 1, slotnode_p);
  prep_d<<<CDIV(90536,256),256,0,stream>>>(d_index, flag_d, ridx_d, p_index, flag_p, ridx_p,
                                           d_ei, cnt_d, p_ei, cnt_p);
  scan2048x2<<<2,256,0,stream>>>(cnt_d, rowptr_d, cnt_p, rowptr_p);
  fill_edges2<<<CDIV(90536,256),256,0,stream>>>(
      d_ei, d_ew, deg_d, flag_d, rowptr_d, fill_d, em_d,
      p_ei, p_ew, deg_p, flag_p, rowptr_p, fill_p, em_p);
  gather_agg5b<<<7680,256,0,stream>>>(
      d_ecfps, deg_d, slotnode_d, rowptr_d, em_d, ctr, aggd_b,
      p_gos,   deg_p, slotnode_p, rowptr_p, em_p, ctr + 1, aggp_b);

  // ---- all weight transposes in one launch ----
  transposeAll<<<11296, dim3(32,8), 0, stream>>>(
      d_gcn_W, WdT, p_gcn_W, WpT, enc_W1, eW1T, enc_W2, eW2T,
      dec_W1, dhT, out_W1, dhT + (size_t)1024 * 256, dec_W2, dW2T);

  // ---- GCN GEMMs: dbuf 128^2, d splitK x2 + p splitK x2 (512 blocks) ----
  {
    GA gd0{aggd_b,        WdT,        Z,  ridx_d, nullptr, nullptr, 1024,  512, 1024, 1024};
    GA gd1{aggd_b + 512,  WdT + 512,  P0, ridx_d, nullptr, nullptr, 1024,  512, 1024, 1024};
    GA gp0{aggp_b,        WpT,        P1, ridx_p, nullptr, nullptr, 1024, 1408, 2816, 2816};
    GA gp1{aggp_b + 1408, WpT + 1408, P2, ridx_p, nullptr, nullptr, 1024, 1408, 2816, 2816};
    gemm128z<<<dim3(16,8,4),256,0,stream>>>(gd0, gd1, gp0, gp1);
  }
  apply_feat<<<CDIV(2*2048*256 + 2048*352,256),256,0,stream>>>(
      Z, P0, d_gcn_b, P1, P2, p_gcn_b, d_vecs, p_emb, feat_out, featb);

  // ---- encoder L1: dbuf 128^2, split-K x3 (384 blocks) ----
  {
    GA e0{featb,        eW1T,        Z,  nullptr, nullptr, nullptr, 1024, 1152, 3456, 3456};
    GA e1{featb + 1152, eW1T + 1152, P0, nullptr, nullptr, nullptr, 1024, 1152, 3456, 3456};
    GA e2{featb + 2304, eW1T + 2304, P1, nullptr, nullptr, nullptr, 1024, 1152, 3456, 3456};
    gemm128z<<<dim3(16,8,3),256,0,stream>>>(e0, e1, e2, e0);
  }
  colstats4<<<dim3(1,128),256,0,stream>>>(Z, P0, P1, 1024, 1024, cs_e1, cq_e1);
  apply_bn4<<<CDIV(2048*256,256),256,0,stream>>>(Z, P0, P1, 1024, 2048*256, 256,
      cs_e1, cq_e1, enc_g1, enc_be1, 0, nullptr, 0, h1b, 1024);

  // ---- encoder L2: split-K x2 -> encoded (64-tile dbuf) ----
  {
    GA e0{h1b,       eW2T,       Z,  nullptr, nullptr, nullptr, 256, 512, 1024, 1024};
    GA e1{h1b + 512, eW2T + 512, P0, nullptr, nullptr, nullptr, 256, 512, 1024, 1024};
    gemm64s<<<dim3(32,2,2),256,0,stream>>>(e0, e1, e0, e0);
  }
  colstats4<<<dim3(1,128),256,0,stream>>>(Z, P0, nullptr, 256, 256, cs_e2, cq_e2);
  apply_bn4<<<CDIV(2048*64,256),256,0,stream>>>(Z, P0, nullptr, 256, 2048*64, 64,
      cs_e2, cq_e2, enc_g2, enc_be2, 0, enc_out, 256, encb, 256);

  // ---- decoder L1 + head GEMM with FUSED stats (288 blocks, no split-K) ----
  {
    GA g0{encb, dhT, Z, nullptr, cs_d1, cq_d1, 1152, 256, 256, 256};
    gemm64s<<<dim3(32,9,1),256,0,stream>>>(g0, g0, g0, g0);
  }
  apply_bn4<<<CDIV(2048*256,256),256,0,stream>>>(Z, nullptr, nullptr, 1152, 2048*256, 256,
      cs_d1, cq_d1, dec_g1, dec_be1, 0, nullptr, 0, h3b, 1024);
  head_fused<<<8,256,0,stream>>>(Z + 1024, 1152, cs_d1 + 1024, cq_d1 + 1024,
                                 out_g1, out_be1, out_W2, out_b2, y_out);

  // ---- decoder L2: dbuf 128^2 with FUSED stats (432 blocks, no split-K) ----
  {
    GA g0{h3b, dW2T, Z, nullptr, cs_d2, cq_d2, 3456, 1024, 1024, 1024};
    gemm128z<<<dim3(16,27,1),256,0,stream>>>(g0, g0, g0, g0);
  }
  apply_bn4<<<CDIV(2048*843,256),256,0,stream>>>(Z, nullptr, nullptr, 3456, 2048*843, 843,
      cs_d2, cq_d2, dec_g2, dec_be2, 0, dec_out, 3372, nullptr, 0);
}

// Round 19
// 274.846 us; speedup vs baseline: 1.2311x; 1.0224x over previous
//
#include <hip/hip_runtime.h>

#define CDIV(a,b) (((a)+(b)-1)/(b))

typedef __attribute__((ext_vector_type(8))) short bf16x8;
typedef __attribute__((ext_vector_type(4))) float f32x4;

__device__ __forceinline__ unsigned short f2b(float v) {
  union { float f; unsigned u; } x; x.f = v;
  unsigned r = x.u + 0x7FFFu + ((x.u >> 16) & 1u);
  return (unsigned short)(r >> 16);
}
__device__ __forceinline__ float b2f(unsigned short u) {
  union { unsigned u32; float f; } x; x.u32 = ((unsigned)u) << 16; return x.f;
}
__device__ __forceinline__ float4 ld4b(const unsigned short* p) {
  ushort4 u = *(const ushort4*)p;
  float4 v; v.x = b2f(u.x); v.y = b2f(u.y); v.z = b2f(u.z); v.w = b2f(u.w);
  return v;
}

__device__ __forceinline__ void gload_lds16(const void* g, void* l) {
  __builtin_amdgcn_global_load_lds(
      (const __attribute__((address_space(1))) unsigned int*)(g),
      (__attribute__((address_space(3))) unsigned int*)(l), 16, 0, 0);
}

struct GA {
  const unsigned short* A;
  const unsigned short* B;
  unsigned short* C;     // bf16 output
  const int* ridx;
  float* csum;           // non-null => fused column stats (REQUIRES no split-K)
  float* csumsq;
  int N, K, lda, ldb;
};

// ---- 128x128 MFMA GEMM, dbuf LDS + counted vmcnt, XOR-swizzled, optional
// A-row indirection + optional fused column stats; z selects operand set.
__global__ __launch_bounds__(256) void gemm128z(GA g0, GA g1, GA g2, GA g3) {
  __shared__ __align__(16) unsigned short As[2][128 * 64];
  __shared__ __align__(16) unsigned short Bs[2][128 * 64];
  const int z = blockIdx.z;
  GA g = (z == 0) ? g0 : (z == 1) ? g1 : (z == 2) ? g2 : g3;

  const int tid = threadIdx.x;
  const int lane = tid & 63;
  const int wid = tid >> 6;
  const int wm = (wid >> 1) * 64;
  const int wn = (wid & 1) * 64;
  const long bm = (long)blockIdx.x * 128;
  const long bn = (long)blockIdx.y * 128;

  f32x4 acc[4][4] = {};

  const int lr = tid >> 3;
  const int lc = (((tid & 7) ^ (lr & 7)) * 8);

  const unsigned short* ap[4];
  const unsigned short* bp[4];
#pragma unroll
  for (int i = 0; i < 4; ++i) {
    long row = bm + i * 32 + lr;
    long arow = g.ridx ? (long)g.ridx[row] : row;
    ap[i] = g.A + arow * g.lda + lc;
    bp[i] = g.B + (bn + i * 32 + lr) * (long)g.ldb + lc;
  }

  const int rsel = lane & 15;
  const int rx = rsel & 7;

  auto STAGE = [&](int buf, int k0) {
#pragma unroll
    for (int i = 0; i < 4; ++i) {
      const int eoff = (i * 256 + tid) * 8;
      gload_lds16(ap[i] + k0, &As[buf][eoff]);
      gload_lds16(bp[i] + k0, &Bs[buf][eoff]);
    }
  };
  auto COMPUTE = [&](int buf) {
#pragma unroll
    for (int kk = 0; kk < 2; ++kk) {
      const int koz = (((kk * 4 + (lane >> 4)) ^ rx) << 3);
      bf16x8 av[4], bv[4];
#pragma unroll
      for (int m = 0; m < 4; ++m)
        av[m] = *(const bf16x8*)(&As[buf][(wm + m * 16 + rsel) * 64 + koz]);
#pragma unroll
      for (int n = 0; n < 4; ++n)
        bv[n] = *(const bf16x8*)(&Bs[buf][(wn + n * 16 + rsel) * 64 + koz]);
#pragma unroll
      for (int m = 0; m < 4; ++m)
#pragma unroll
        for (int n = 0; n < 4; ++n)
          acc[m][n] = __builtin_amdgcn_mfma_f32_16x16x32_bf16(av[m], bv[n], acc[m][n], 0, 0, 0);
    }
  };

  STAGE(0, 0);
  int cur = 0;
  for (int k0 = 64; k0 < g.K; k0 += 64) {
    STAGE(cur ^ 1, k0);
    asm volatile("s_waitcnt vmcnt(8)" ::: "memory");
    __builtin_amdgcn_s_barrier();
    asm volatile("" ::: "memory");
    COMPUTE(cur);
    asm volatile("" ::: "memory");
    __builtin_amdgcn_s_barrier();
    cur ^= 1;
  }
  asm volatile("s_waitcnt vmcnt(0)" ::: "memory");
  __builtin_amdgcn_s_barrier();
  asm volatile("" ::: "memory");
  COMPUTE(cur);

  const int crow0 = (lane >> 4) * 4;
  const int ccol = lane & 15;
#pragma unroll
  for (int m = 0; m < 4; ++m)
#pragma unroll
    for (int n = 0; n < 4; ++n) {
      const long r = bm + wm + m * 16 + crow0;
      const long c = bn + wn + n * 16 + ccol;
#pragma unroll
      for (int q = 0; q < 4; ++q)
        g.C[(r + q) * (long)g.N + c] = f2b(acc[m][n][q]);
    }

  if (g.csum) {
#pragma unroll
    for (int n = 0; n < 4; ++n) {
      float s = 0.f, s2 = 0.f;
#pragma unroll
      for (int m = 0; m < 4; ++m)
#pragma unroll
        for (int q = 0; q < 4; ++q) {
          float v = acc[m][n][q];
          s += v; s2 += v * v;
        }
      s  += __shfl_xor(s, 16);  s  += __shfl_xor(s, 32);
      s2 += __shfl_xor(s2, 16); s2 += __shfl_xor(s2, 32);
      if ((lane >> 4) == 0) {
        const long c = bn + wn + n * 16 + ccol;
        atomicAdd(&g.csum[c], s);
        atomicAdd(&g.csumsq[c], s2);
      }
    }
  }
}

// ---- 64x128 MFMA GEMM, dbuf + counted vmcnt, swizzled, optional fused stats
__global__ __launch_bounds__(256) void gemm64s(GA g0, GA g1, GA g2, GA g3) {
  __shared__ __align__(16) unsigned short As[2][64 * 64];
  __shared__ __align__(16) unsigned short Bs[2][128 * 64];
  const int z = blockIdx.z;
  GA g = (z == 0) ? g0 : (z == 1) ? g1 : (z == 2) ? g2 : g3;

  const int tid = threadIdx.x;
  const int lane = tid & 63;
  const int wid = tid >> 6;
  const int wn = wid * 32;
  const long bm = (long)blockIdx.x * 64;
  const long bn = (long)blockIdx.y * 128;

  f32x4 acc[4][2] = {};

  const int lr = tid >> 3;
  const int lc = (((tid & 7) ^ (lr & 7)) * 8);

  const long r0 = g.ridx ? (long)g.ridx[bm + lr] : bm + lr;
  const long r1 = g.ridx ? (long)g.ridx[bm + 32 + lr] : bm + 32 + lr;
  const unsigned short* ap0 = g.A + r0 * g.lda + lc;
  const unsigned short* ap1 = g.A + r1 * g.lda + lc;
  const unsigned short* bp0 = g.B + (bn + lr) * (long)g.ldb + lc;
  const unsigned short* bp1 = g.B + (bn + 32 + lr) * (long)g.ldb + lc;
  const unsigned short* bp2 = g.B + (bn + 64 + lr) * (long)g.ldb + lc;
  const unsigned short* bp3 = g.B + (bn + 96 + lr) * (long)g.ldb + lc;

  const int rsel = lane & 15;
  const int rx = rsel & 7;

  auto STAGE = [&](int buf, int k0) {
    gload_lds16(ap0 + k0, &As[buf][tid * 8]);
    gload_lds16(ap1 + k0, &As[buf][(256 + tid) * 8]);
    gload_lds16(bp0 + k0, &Bs[buf][tid * 8]);
    gload_lds16(bp1 + k0, &Bs[buf][(256 + tid) * 8]);
    gload_lds16(bp2 + k0, &Bs[buf][(512 + tid) * 8]);
    gload_lds16(bp3 + k0, &Bs[buf][(768 + tid) * 8]);
  };
  auto COMPUTE = [&](int buf) {
#pragma unroll
    for (int kk = 0; kk < 2; ++kk) {
      const int koz = (((kk * 4 + (lane >> 4)) ^ rx) << 3);
      bf16x8 av[4], bv[2];
#pragma unroll
      for (int m = 0; m < 4; ++m)
        av[m] = *(const bf16x8*)(&As[buf][(m * 16 + rsel) * 64 + koz]);
#pragma unroll
      for (int n = 0; n < 2; ++n)
        bv[n] = *(const bf16x8*)(&Bs[buf][(wn + n * 16 + rsel) * 64 + koz]);
#pragma unroll
      for (int m = 0; m < 4; ++m)
#pragma unroll
        for (int n = 0; n < 2; ++n)
          acc[m][n] = __builtin_amdgcn_mfma_f32_16x16x32_bf16(av[m], bv[n], acc[m][n], 0, 0, 0);
    }
  };

  STAGE(0, 0);
  int cur = 0;
  for (int k0 = 64; k0 < g.K; k0 += 64) {
    STAGE(cur ^ 1, k0);
    asm volatile("s_waitcnt vmcnt(6)" ::: "memory");
    __builtin_amdgcn_s_barrier();
    asm volatile("" ::: "memory");
    COMPUTE(cur);
    asm volatile("" ::: "memory");
    __builtin_amdgcn_s_barrier();
    cur ^= 1;
  }
  asm volatile("s_waitcnt vmcnt(0)" ::: "memory");
  __builtin_amdgcn_s_barrier();
  asm volatile("" ::: "memory");
  COMPUTE(cur);

  const int crow0 = (lane >> 4) * 4;
  const int ccol = lane & 15;
#pragma unroll
  for (int m = 0; m < 4; ++m)
#pragma unroll
    for (int n = 0; n < 2; ++n) {
      const long r = bm + m * 16 + crow0;
      const long c = bn + wn + n * 16 + ccol;
#pragma unroll
      for (int q = 0; q < 4; ++q)
        g.C[(r + q) * (long)g.N + c] = f2b(acc[m][n][q]);
    }

  if (g.csum) {
#pragma unroll
    for (int n = 0; n < 2; ++n) {
      float s = 0.f, s2 = 0.f;
#pragma unroll
      for (int m = 0; m < 4; ++m)
#pragma unroll
        for (int q = 0; q < 4; ++q) {
          float v = acc[m][n][q];
          s += v; s2 += v * v;
        }
      s  += __shfl_xor(s, 16);  s  += __shfl_xor(s, 32);
      s2 += __shfl_xor(s2, 16); s2 += __shfl_xor(s2, 32);
      if ((lane >> 4) == 0) {
        const long c = bn + wn + n * 16 + ccol;
        atomicAdd(&g.csum[c], s);
        atomicAdd(&g.csumsq[c], s2);
      }
    }
  }
}

// ---------------- merged prep kernels ----------------
__global__ void init_all(int* iz, int nIz, float* deg, int nDeg,
                         float* stats, int nStats) {
  int i = blockIdx.x * 256 + threadIdx.x;
  if (i < nIz) iz[i] = 0;
  if (i < nDeg) deg[i] = 1.f;
  if (i < nStats) stats[i] = 0.f;
}

__global__ void prep_b(const int* __restrict__ d_ei, const float* __restrict__ d_ew,
                       float* __restrict__ deg_d,
                       const int* __restrict__ p_ei, const float* __restrict__ p_ew,
                       float* __restrict__ deg_p,
                       const int* __restrict__ d_index, int* __restrict__ flag_d,
                       const int* __restrict__ p_index, int* __restrict__ flag_p) {
  int e = blockIdx.x * 256 + threadIdx.x;
  if (e < 65536) atomicAdd(&deg_d[d_ei[65536 + e]], d_ew[e]);
  int e2 = e - 65536;
  if (e2 >= 0 && e2 < 25000) atomicAdd(&deg_p[p_ei[25000 + e2]], p_ew[e2]);
  if (e < 2048) flag_d[d_index[e]] = 1;
  else if (e < 4096) flag_p[p_index[e - 2048]] = 1;
}

__global__ void prep_c(float* __restrict__ deg, int nDeg,
                       int* __restrict__ flag_d, int* __restrict__ ctr_d,
                       int* __restrict__ slot_d,
                       int* __restrict__ flag_p, int* __restrict__ ctr_p,
                       int* __restrict__ slot_p) {
  int i = blockIdx.x * 256 + threadIdx.x;
  if (i < nDeg) deg[i] = rsqrtf(deg[i]);
  if (i < 10000) {
    if (flag_d[i]) { int s = atomicAdd(ctr_d, 1); flag_d[i] = s + 1; slot_d[s] = i; }
  } else if (i < 15000) {
    int j = i - 10000;
    if (flag_p[j]) { int s = atomicAdd(ctr_p, 1); flag_p[j] = s + 1; slot_p[s] = j; }
  }
}

__global__ void prep_d(const int* __restrict__ d_index, const int* __restrict__ flag_d,
                       int* __restrict__ ridx_d,
                       const int* __restrict__ p_index, const int* __restrict__ flag_p,
                       int* __restrict__ ridx_p,
                       const int* __restrict__ d_ei, int* __restrict__ cnt_d,
                       const int* __restrict__ p_ei, int* __restrict__ cnt_p) {
  int e = blockIdx.x * 256 + threadIdx.x;
  if (e < 2048) ridx_d[e] = flag_d[d_index[e]] - 1;
  else if (e < 4096) { int j = e - 2048; ridx_p[j] = flag_p[p_index[j]] - 1; }
  if (e < 65536) { int s = flag_d[d_ei[65536 + e]]; if (s) atomicAdd(&cnt_d[s - 1], 1); }
  int e2 = e - 65536;
  if (e2 >= 0 && e2 < 25000) { int s = flag_p[p_ei[25000 + e2]]; if (s) atomicAdd(&cnt_p[s - 1], 1); }
}

__global__ void scan2048x2(const int* __restrict__ cnt_d, int* __restrict__ rp_d,
                           const int* __restrict__ cnt_p, int* __restrict__ rp_p) {
  const int* cnt = blockIdx.x ? cnt_p : cnt_d;
  int* rowptr    = blockIdx.x ? rp_p : rp_d;
  __shared__ int part[256];
  int tid = threadIdx.x;
  int base = tid * 8;
  int vals[8]; int s = 0;
#pragma unroll
  for (int i = 0; i < 8; ++i) { vals[i] = s; s += cnt[base + i]; }
  part[tid] = s;
  __syncthreads();
  if (tid == 0) { int r = 0; for (int i = 0; i < 256; ++i) { int t = part[i]; part[i] = r; r += t; } }
  __syncthreads();
  int off = part[tid];
#pragma unroll
  for (int i = 0; i < 8; ++i) rowptr[base + i] = off + vals[i];
  if (tid == 255) rowptr[2048] = off + s;
}
__global__ void fill_edges2(
    const int* __restrict__ d_ei, const float* __restrict__ d_ew,
    const float* __restrict__ dinv_d, const int* __restrict__ flag_d,
    const int* __restrict__ rp_d, int* __restrict__ fill_d,
    int2* __restrict__ em_d,
    const int* __restrict__ p_ei, const float* __restrict__ p_ew,
    const float* __restrict__ dinv_p, const int* __restrict__ flag_p,
    const int* __restrict__ rp_p, int* __restrict__ fill_p,
    int2* __restrict__ em_p) {
  int e = blockIdx.x * 256 + threadIdx.x;
  if (e < 65536) {
    int dst = d_ei[65536 + e];
    int s = flag_d[dst];
    if (s) {
      int src = d_ei[e];
      int pos = rp_d[s - 1] + atomicAdd(&fill_d[s - 1], 1);
      float cf = d_ew[e] * dinv_d[src] * dinv_d[dst];
      em_d[pos] = make_int2(src, __float_as_int(cf));
    }
  }
  int e2 = e - 65536;
  if (e2 >= 0 && e2 < 25000) {
    int dst = p_ei[25000 + e2];
    int s = flag_p[dst];
    if (s) {
      int src = p_ei[e2];
      int pos = rp_p[s - 1] + atomicAdd(&fill_p[s - 1], 1);
      float cf = p_ew[e2] * dinv_p[src] * dinv_p[dst];
      em_p[pos] = make_int2(src, __float_as_int(cf));
    }
  }
}

// ---- wave-per-(slot, 64-f4 chunk) gather, 4-edge unroll, packed int2 meta.
__global__ __launch_bounds__(256) void gather_agg5b(
    const float* __restrict__ Xd, const float* __restrict__ dinv_d,
    const int* __restrict__ slot_d, const int* __restrict__ rp_d,
    const int2* __restrict__ em_d,
    const int* __restrict__ nflag_d, unsigned short* __restrict__ aggd,
    const float* __restrict__ Xp, const float* __restrict__ dinv_p,
    const int* __restrict__ slot_p, const int* __restrict__ rp_p,
    const int2* __restrict__ em_p,
    const int* __restrict__ nflag_p, unsigned short* __restrict__ aggp)
{
  const int gw = blockIdx.x * 4 + (threadIdx.x >> 6);
  const int lane = threadIdx.x & 63;

  int slot, c, Kdata4, Kst4, Kld, nflag;
  const float *X, *dinv; const int *slotn, *rp; const int2* em;
  unsigned short* agg;
  if (gw < 8192) {
    slot = gw >> 2;
    c = (gw & 3) * 64 + lane;
    X = Xd; dinv = dinv_d; slotn = slot_d; rp = rp_d; em = em_d;
    nflag = *nflag_d; agg = aggd; Kdata4 = 256; Kst4 = 256; Kld = 1024;
  } else {
    int q = gw - 8192;
    slot = q / 11;
    c = (q - slot * 11) * 64 + lane;
    X = Xp; dinv = dinv_p; slotn = slot_p; rp = rp_p; em = em_p;
    nflag = *nflag_p; agg = aggp; Kdata4 = 703; Kst4 = 704; Kld = 2812;
  }
  if (slot >= nflag) return;

  const int n = slotn[slot];
  const float dn = dinv[n];
  const float selfc = dn * dn;
  const int e0 = rp[slot], e1 = rp[slot + 1];
  const bool valid = c < Kdata4;

  float ax = 0.f, ay = 0.f, az = 0.f, aw = 0.f;
  if (valid) {
    float4 v = *(const float4*)(X + (long)n * Kld + 4 * c);
    ax = selfc * v.x; ay = selfc * v.y; az = selfc * v.z; aw = selfc * v.w;
  }

  int e = e0;
  for (; e + 4 <= e1; e += 4) {
    const int2 m0 = em[e], m1 = em[e + 1], m2 = em[e + 2], m3 = em[e + 3];
    if (valid) {
      float4 v0 = *(const float4*)(X + (long)m0.x * Kld + 4 * c);
      float4 v1 = *(const float4*)(X + (long)m1.x * Kld + 4 * c);
      float4 v2 = *(const float4*)(X + (long)m2.x * Kld + 4 * c);
      float4 v3 = *(const float4*)(X + (long)m3.x * Kld + 4 * c);
      const float c0 = __int_as_float(m0.y), c1 = __int_as_float(m1.y);
      const float c2 = __int_as_float(m2.y), c3 = __int_as_float(m3.y);
      ax += c0 * v0.x; ay += c0 * v0.y; az += c0 * v0.z; aw += c0 * v0.w;
      ax += c1 * v1.x; ay += c1 * v1.y; az += c1 * v1.z; aw += c1 * v1.w;
      ax += c2 * v2.x; ay += c2 * v2.y; az += c2 * v2.z; aw += c2 * v2.w;
      ax += c3 * v3.x; ay += c3 * v3.y; az += c3 * v3.z; aw += c3 * v3.w;
    }
  }
  for (; e < e1; ++e) {
    const int2 m = em[e];
    if (valid) {
      float4 v = *(const float4*)(X + (long)m.x * Kld + 4 * c);
      const float cf = __int_as_float(m.y);
      ax += cf * v.x; ay += cf * v.y; az += cf * v.z; aw += cf * v.w;
    }
  }

  if (c < Kst4) {
    ushort4 o; o.x = f2b(ax); o.y = f2b(ay); o.z = f2b(az); o.w = f2b(aw);
    *(ushort4*)(agg + (long)slot * (Kst4 * 4) + 4 * c) = o;
  }
}

// ---- all 7 weight transposes in one flattened launch ----
__global__ void transposeAll(
    const float* W0, unsigned short* T0,
    const float* W1, unsigned short* T1,
    const float* W2, unsigned short* T2,
    const float* W3, unsigned short* T3,
    const float* W4, unsigned short* T4,
    const float* W5, unsigned short* T5,
    const float* W6, unsigned short* T6)
{
  __shared__ float tile[32][33];
  int bid = blockIdx.x;
  const float* W; unsigned short* Wt; int K, N, Kp, Np_, tx, local;
  if      (bid <  1024) { W=W0; Wt=T0; K=1024; N=1024; Kp=1024; Np_=1024; tx=32;  local=bid; }
  else if (bid <  3840) { W=W1; Wt=T1; K=2812; N=1024; Kp=2816; Np_=1024; tx=88;  local=bid-1024; }
  else if (bid <  7296) { W=W2; Wt=T2; K=3372; N=1024; Kp=3456; Np_=1024; tx=108; local=bid-3840; }
  else if (bid <  7552) { W=W3; Wt=T3; K=1024; N=256;  Kp=1024; Np_=256;  tx=32;  local=bid-7296; }
  else if (bid <  7808) { W=W4; Wt=T4; K=256;  N=1024; Kp=256;  Np_=1024; tx=8;   local=bid-7552; }
  else if (bid <  7840) { W=W5; Wt=T5; K=256;  N=64;   Kp=256;  Np_=128;  tx=8;   local=bid-7808; }
  else                  { W=W6; Wt=T6; K=1024; N=3372; Kp=1024; Np_=3456; tx=32;  local=bid-7840; }
  int k0 = (local % tx) * 32, n0 = (local / tx) * 32;
  for (int i = threadIdx.y; i < 32; i += 8) {
    int k = k0 + i, n = n0 + threadIdx.x;
    tile[i][threadIdx.x] = (k < K && n < N) ? W[(size_t)k * N + n] : 0.f;
  }
  __syncthreads();
  for (int i = threadIdx.y; i < 32; i += 8) {
    int n = n0 + i, k = k0 + threadIdx.x;
    if (n < Np_ && k < Kp) Wt[(size_t)n * Kp + k] = f2b(tile[threadIdx.x][i]);
  }
}

// vectorized colstats over bf16 partials (for split-K layers only)
__global__ void colstats4(const unsigned short* __restrict__ Z,
                          const unsigned short* __restrict__ Z2,
                          const unsigned short* __restrict__ Z3, int ldz, int cols,
                          float* __restrict__ csum, float* __restrict__ csumsq) {
  int c4 = blockIdx.x * 256 + threadIdx.x;
  if (c4 * 4 >= cols) return;
  int r0 = blockIdx.y * 16;
  float sx = 0.f, sy = 0.f, sz_ = 0.f, sw = 0.f;
  float qx = 0.f, qy = 0.f, qz = 0.f, qw = 0.f;
  for (int r = r0; r < r0 + 16; ++r) {
    float4 v = ld4b(Z + (long)r * ldz + 4 * c4);
    if (Z2) { float4 w = ld4b(Z2 + (long)r * ldz + 4 * c4);
              v.x += w.x; v.y += w.y; v.z += w.z; v.w += w.w; }
    if (Z3) { float4 w = ld4b(Z3 + (long)r * ldz + 4 * c4);
              v.x += w.x; v.y += w.y; v.z += w.z; v.w += w.w; }
    sx += v.x; sy += v.y; sz_ += v.z; sw += v.w;
    qx += v.x * v.x; qy += v.y * v.y; qz += v.z * v.z; qw += v.w * v.w;
  }
  atomicAdd(&csum[4 * c4 + 0], sx); atomicAdd(&csum[4 * c4 + 1], sy);
  atomicAdd(&csum[4 * c4 + 2], sz_); atomicAdd(&csum[4 * c4 + 3], sw);
  atomicAdd(&csumsq[4 * c4 + 0], qx); atomicAdd(&csumsq[4 * c4 + 1], qy);
  atomicAdd(&csumsq[4 * c4 + 2], qz); atomicAdd(&csumsq[4 * c4 + 3], qw);
}

// apply with INLINE bn-finalize over bf16 partials. csum==null -> bias-only.
__global__ void apply_bn4(const unsigned short* __restrict__ Z,
                          const unsigned short* __restrict__ Z2,
                          const unsigned short* __restrict__ Z3,
                          int ldz, int total4, int cols4,
                          const float* __restrict__ csum, const float* __restrict__ csumsq,
                          const float* __restrict__ g, const float* __restrict__ beta,
                          int leaky,
                          float* __restrict__ f32out, int ldf,
                          unsigned short* __restrict__ b16out, int ldb) {
  int idx = blockIdx.x*256+threadIdx.x;
  if (idx >= total4) return;
  int b = idx / cols4, j = (idx % cols4) * 4;
  float4 v = ld4b(Z + (long)b * ldz + j);
  if (Z2) { float4 w = ld4b(Z2 + (long)b * ldz + j);
            v.x += w.x; v.y += w.y; v.z += w.z; v.w += w.w; }
  if (Z3) { float4 w = ld4b(Z3 + (long)b * ldz + j);
            v.x += w.x; v.y += w.y; v.z += w.z; v.w += w.w; }
  if (csum) {
    const float invB = 1.f / 2048.f;
    float4 cs = *(const float4*)(csum + j);
    float4 cq = *(const float4*)(csumsq + j);
    float4 gg = *(const float4*)(g + j);
    float4 bb = *(const float4*)(beta + j);
    float m, var, sc;
    m = cs.x * invB; var = fmaxf(cq.x * invB - m * m, 0.f);
    sc = gg.x * rsqrtf(var + 1e-5f); v.x = v.x * sc + (bb.x - m * sc);
    m = cs.y * invB; var = fmaxf(cq.y * invB - m * m, 0.f);
    sc = gg.y * rsqrtf(var + 1e-5f); v.y = v.y * sc + (bb.y - m * sc);
    m = cs.z * invB; var = fmaxf(cq.z * invB - m * m, 0.f);
    sc = gg.z * rsqrtf(var + 1e-5f); v.z = v.z * sc + (bb.z - m * sc);
    m = cs.w * invB; var = fmaxf(cq.w * invB - m * m, 0.f);
    sc = gg.w * rsqrtf(var + 1e-5f); v.w = v.w * sc + (bb.w - m * sc);
  } else {
    float4 bb = *(const float4*)(beta + j);
    v.x += bb.x; v.y += bb.y; v.z += bb.z; v.w += bb.w;
  }
  const float neg = leaky ? 0.01f : 0.f;
  v.x = (v.x >= 0.f) ? v.x : neg * v.x;
  v.y = (v.y >= 0.f) ? v.y : neg * v.y;
  v.z = (v.z >= 0.f) ? v.z : neg * v.z;
  v.w = (v.w >= 0.f) ? v.w : neg * v.w;
  if (f32out) *(float4*)(f32out + (long)b * ldf + j) = v;
  if (b16out) {
    ushort4 o; o.x = f2b(v.x); o.y = f2b(v.y); o.z = f2b(v.z); o.w = f2b(v.w);
    *(ushort4*)(b16out + (long)b * ldb + j) = o;
  }
}

// GCN applies (bf16 partials) + feat copy + pad in one launch.
__global__ void apply_feat(const unsigned short* __restrict__ Zd,
                           const unsigned short* __restrict__ Pd,
                           const float* __restrict__ bd,
                           const unsigned short* __restrict__ Zp,
                           const unsigned short* __restrict__ Pp,
                           const float* __restrict__ bp,
                           const float* __restrict__ dv, const float* __restrict__ pe,
                           float* __restrict__ feat_f32, unsigned short* __restrict__ feat_b16) {
  int idx = blockIdx.x*256+threadIdx.x;
  const int APPLY_N = 2 * 2048 * 256;
  if (idx < APPLY_N) {
    const bool isP = idx >= 2048 * 256;
    int l = isP ? idx - 2048 * 256 : idx;
    int b = l >> 8, j = (l & 255) * 4;
    const unsigned short* Z = isP ? Zp : Zd;
    const unsigned short* P = isP ? Pp : Pd;
    const float* bias = isP ? bp : bd;
    const int coloff = isP ? 2348 : 1324;
    float4 v = ld4b(Z + (long)b * 1024 + j);
    float4 w = ld4b(P + (long)b * 1024 + j);
    float4 bb = *(const float4*)(bias + j);
    v.x += w.x + bb.x; v.y += w.y + bb.y; v.z += w.z + bb.z; v.w += w.w + bb.w;
    v.x = (v.x >= 0.f) ? v.x : 0.01f * v.x;
    v.y = (v.y >= 0.f) ? v.y : 0.01f * v.y;
    v.z = (v.z >= 0.f) ? v.z : 0.01f * v.z;
    v.w = (v.w >= 0.f) ? v.w : 0.01f * v.w;
    *(float4*)(feat_f32 + (long)b * 3372 + coloff + j) = v;
    ushort4 o; o.x = f2b(v.x); o.y = f2b(v.y); o.z = f2b(v.z); o.w = f2b(v.w);
    *(ushort4*)(feat_b16 + (long)b * 3456 + coloff + j) = o;
    return;
  }
  int q = idx - APPLY_N;
  if (q >= 2048 * 352) return;
  int b = q / 352, u = q % 352;
  if (u < 331) {
    int c = u * 4;
    float4 v;
    if (u < 75) v = *(const float4*)(dv + (long)b * 300 + c);
    else        v = *(const float4*)(pe + (long)b * 1024 + (c - 300));
    *(float4*)(feat_f32 + (long)b * 3372 + c) = v;
    ushort4 o; o.x = f2b(v.x); o.y = f2b(v.y); o.z = f2b(v.z); o.w = f2b(v.w);
    *(ushort4*)(feat_b16 + (long)b * 3456 + c) = o;
  } else {
    int c = 3372 + (u - 331) * 4;
    ushort4 o; o.x = 0; o.y = 0; o.z = 0; o.w = 0;
    *(ushort4*)(feat_b16 + (long)b * 3456 + c) = o;
  }
}

// head: bn(inline stats) + lrelu + dot(W2) + b2 -> y   (Z bf16)
__global__ void head_fused(const unsigned short* __restrict__ Z, int ldz,
                           const float* __restrict__ csum, const float* __restrict__ csumsq,
                           const float* __restrict__ g, const float* __restrict__ beta,
                           const float* __restrict__ W2, const float* __restrict__ b2,
                           float* __restrict__ y) {
  int b = blockIdx.x*256+threadIdx.x;
  if (b >= 2048) return;
  const float invB = 1.f / 2048.f;
  float s = b2[0];
  for (int k = 0; k < 64; ++k) {
    float m = csum[k] * invB;
    float var = fmaxf(csumsq[k] * invB - m * m, 0.f);
    float sc = g[k] * rsqrtf(var + 1e-5f);
    float sh = beta[k] - m * sc;
    float v = b2f(Z[(long)b * ldz + k]);
    v = v * sc + sh;
    v = (v >= 0.f) ? v : 0.01f * v;
    s += v * W2[k];
  }
  y[b] = s;
}

extern "C" void kernel_launch(void* const* d_in, const int* in_sizes, int n_in,
                              void* d_out, int out_size, void* d_ws, size_t ws_size,
                              hipStream_t stream) {
  (void)in_sizes; (void)n_in; (void)out_size; (void)ws_size;
  const int*   d_index = (const int*)d_in[0];
  const int*   p_index = (const int*)d_in[1];
  const float* d_vecs  = (const float*)d_in[2];
  const float* p_emb   = (const float*)d_in[3];
  const float* d_ecfps = (const float*)d_in[4];
  const int*   d_ei    = (const int*)d_in[5];
  const float* d_ew    = (const float*)d_in[6];
  const float* p_gos   = (const float*)d_in[7];
  const int*   p_ei    = (const int*)d_in[8];
  const float* p_ew    = (const float*)d_in[9];
  const float* d_gcn_W = (const float*)d_in[10];
  const float* d_gcn_b = (const float*)d_in[11];
  const float* p_gcn_W = (const float*)d_in[12];
  const float* p_gcn_b = (const float*)d_in[13];
  const float* enc_W1  = (const float*)d_in[14];
  const float* enc_g1  = (const float*)d_in[16];
  const float* enc_be1 = (const float*)d_in[17];
  const float* enc_W2  = (const float*)d_in[18];
  const float* enc_g2  = (const float*)d_in[20];
  const float* enc_be2 = (const float*)d_in[21];
  const float* dec_W1  = (const float*)d_in[22];
  const float* dec_g1  = (const float*)d_in[24];
  const float* dec_be1 = (const float*)d_in[25];
  const float* dec_W2  = (const float*)d_in[26];
  const float* dec_g2  = (const float*)d_in[28];
  const float* dec_be2 = (const float*)d_in[29];
  const float* out_W1  = (const float*)d_in[30];
  const float* out_g1  = (const float*)d_in[32];
  const float* out_be1 = (const float*)d_in[33];
  const float* out_W2  = (const float*)d_in[34];
  const float* out_b2  = (const float*)d_in[35];

  float* out = (float*)d_out;
  float* y_out    = out;
  float* enc_out  = out + 2048;
  float* dec_out  = out + 526336;
  float* feat_out = out + 7432192;

  char* ws = (char*)d_ws;
  size_t off = 0;
  auto alloc = [&](size_t bytes) {
    size_t o = off; off = (off + bytes + 255) & ~(size_t)255; return (void*)(ws + o);
  };
  int* iz = (int*)alloc((size_t)23200 * 4);
  int* flag_d = iz;
  int* flag_p = iz + 10000;
  int* cnt_d  = iz + 15000;
  int* cnt_p  = iz + 17048;
  int* fill_d = iz + 19096;
  int* fill_p = iz + 21144;
  int* ctr    = iz + 23192;
  int* slotnode_d = (int*)alloc(2048 * 4);
  int* slotnode_p = (int*)alloc(2048 * 4);
  int* rowptr_d = (int*)alloc(2049 * 4);
  int* rowptr_p = (int*)alloc(2049 * 4);
  int* ridx_d = (int*)alloc(2048 * 4);
  int* ridx_p = (int*)alloc(2048 * 4);
  int2* em_d = (int2*)alloc((size_t)65536 * 8);
  int2* em_p = (int2*)alloc((size_t)25000 * 8);
  float* deg   = (float*)alloc((size_t)15000 * 4);
  float* deg_d = deg;
  float* deg_p = deg + 10000;
  float* stats = (float*)alloc((size_t)34560 * 4);
  float* cs_e1 = stats,         * cq_e1 = stats + 3456;
  float* cs_e2 = stats + 6912,  * cq_e2 = stats + 10368;
  float* cs_d1 = stats + 13824, * cq_d1 = stats + 17280;
  float* cs_d2 = stats + 27648, * cq_d2 = stats + 31104;
  unsigned short* aggd_b = (unsigned short*)alloc((size_t)2048 * 1024 * 2);
  unsigned short* aggp_b = (unsigned short*)alloc((size_t)2048 * 2816 * 2);
  unsigned short* WdT   = (unsigned short*)alloc((size_t)1024 * 1024 * 2);
  unsigned short* WpT   = (unsigned short*)alloc((size_t)1024 * 2816 * 2);
  unsigned short* eW1T  = (unsigned short*)alloc((size_t)1024 * 3456 * 2);
  unsigned short* eW2T  = (unsigned short*)alloc((size_t)256 * 1024 * 2);
  unsigned short* dhT   = (unsigned short*)alloc((size_t)1152 * 256 * 2);
  unsigned short* dW2T  = (unsigned short*)alloc((size_t)3456 * 1024 * 2);
  unsigned short* featb = (unsigned short*)alloc((size_t)2048 * 3456 * 2);
  unsigned short* Z   = (unsigned short*)alloc((size_t)2048 * 3456 * 2);
  unsigned short* P0  = (unsigned short*)alloc((size_t)2048 * 1152 * 2);
  unsigned short* P1  = (unsigned short*)alloc((size_t)2048 * 1152 * 2);
  unsigned short* P2  = (unsigned short*)alloc((size_t)2048 * 1152 * 2);
  unsigned short* h1b  = (unsigned short*)alloc((size_t)2048 * 1024 * 2);
  unsigned short* encb = (unsigned short*)alloc((size_t)2048 * 256 * 2);
  unsigned short* h3b  = (unsigned short*)alloc((size_t)2048 * 1024 * 2);

  // ---- GCN prep (merged launches) ----
  init_all<<<CDIV(34560,256),256,0,stream>>>(iz, 23200, deg, 15000, stats, 34560);
  prep_b<<<CDIV(90536,256),256,0,stream>>>(d_ei, d_ew, deg_d, p_ei, p_ew, deg_p,
                                           d_index, flag_d, p_index, flag_p);
  prep_c<<<CDIV(15000,256),256,0,stream>>>(deg, 15000, flag_d, ctr, slotnode_d,
                                           flag_p, ctr + 1, slotnode_p);
  prep_d<<<CDIV(90536,256),256,0,stream>>>(d_index, flag_d, ridx_d, p_index, flag_p, ridx_p,
                                           d_ei, cnt_d, p_ei, cnt_p);
  scan2048x2<<<2,256,0,stream>>>(cnt_d, rowptr_d, cnt_p, rowptr_p);
  fill_edges2<<<CDIV(90536,256),256,0,stream>>>(
      d_ei, d_ew, deg_d, flag_d, rowptr_d, fill_d, em_d,
      p_ei, p_ew, deg_p, flag_p, rowptr_p, fill_p, em_p);
  gather_agg5b<<<7680,256,0,stream>>>(
      d_ecfps, deg_d, slotnode_d, rowptr_d, em_d, ctr, aggd_b,
      p_gos,   deg_p, slotnode_p, rowptr_p, em_p, ctr + 1, aggp_b);

  // ---- all weight transposes in one launch ----
  transposeAll<<<11296, dim3(32,8), 0, stream>>>(
      d_gcn_W, WdT, p_gcn_W, WpT, enc_W1, eW1T, enc_W2, eW2T,
      dec_W1, dhT, out_W1, dhT + (size_t)1024 * 256, dec_W2, dW2T);

  // ---- GCN GEMMs: dbuf 128^2, d splitK x2 + p splitK x2 (512 blocks) ----
  {
    GA gd0{aggd_b,        WdT,        Z,  ridx_d, nullptr, nullptr, 1024,  512, 1024, 1024};
    GA gd1{aggd_b + 512,  WdT + 512,  P0, ridx_d, nullptr, nullptr, 1024,  512, 1024, 1024};
    GA gp0{aggp_b,        WpT,        P1, ridx_p, nullptr, nullptr, 1024, 1408, 2816, 2816};
    GA gp1{aggp_b + 1408, WpT + 1408, P2, ridx_p, nullptr, nullptr, 1024, 1408, 2816, 2816};
    gemm128z<<<dim3(16,8,4),256,0,stream>>>(gd0, gd1, gp0, gp1);
  }
  apply_feat<<<CDIV(2*2048*256 + 2048*352,256),256,0,stream>>>(
      Z, P0, d_gcn_b, P1, P2, p_gcn_b, d_vecs, p_emb, feat_out, featb);

  // ---- encoder L1: dbuf 128^2, split-K x3 (384 blocks) ----
  {
    GA e0{featb,        eW1T,        Z,  nullptr, nullptr, nullptr, 1024, 1152, 3456, 3456};
    GA e1{featb + 1152, eW1T + 1152, P0, nullptr, nullptr, nullptr, 1024, 1152, 3456, 3456};
    GA e2{featb + 2304, eW1T + 2304, P1, nullptr, nullptr, nullptr, 1024, 1152, 3456, 3456};
    gemm128z<<<dim3(16,8,3),256,0,stream>>>(e0, e1, e2, e0);
  }
  colstats4<<<dim3(1,128),256,0,stream>>>(Z, P0, P1, 1024, 1024, cs_e1, cq_e1);
  apply_bn4<<<CDIV(2048*256,256),256,0,stream>>>(Z, P0, P1, 1024, 2048*256, 256,
      cs_e1, cq_e1, enc_g1, enc_be1, 0, nullptr, 0, h1b, 1024);

  // ---- encoder L2: split-K x2 -> encoded (64-tile dbuf) ----
  {
    GA e0{h1b,       eW2T,       Z,  nullptr, nullptr, nullptr, 256, 512, 1024, 1024};
    GA e1{h1b + 512, eW2T + 512, P0, nullptr, nullptr, nullptr, 256, 512, 1024, 1024};
    gemm64s<<<dim3(32,2,2),256,0,stream>>>(e0, e1, e0, e0);
  }
  colstats4<<<dim3(1,128),256,0,stream>>>(Z, P0, nullptr, 256, 256, cs_e2, cq_e2);
  apply_bn4<<<CDIV(2048*64,256),256,0,stream>>>(Z, P0, nullptr, 256, 2048*64, 64,
      cs_e2, cq_e2, enc_g2, enc_be2, 0, enc_out, 256, encb, 256);

  // ---- decoder L1 + head GEMM with FUSED stats (288 blocks, no split-K) ----
  {
    GA g0{encb, dhT, Z, nullptr, cs_d1, cq_d1, 1152, 256, 256, 256};
    gemm64s<<<dim3(32,9,1),256,0,stream>>>(g0, g0, g0, g0);
  }
  apply_bn4<<<CDIV(2048*256,256),256,0,stream>>>(Z, nullptr, nullptr, 1152, 2048*256, 256,
      cs_d1, cq_d1, dec_g1, dec_be1, 0, nullptr, 0, h3b, 1024);
  head_fused<<<8,256,0,stream>>>(Z + 1024, 1152, cs_d1 + 1024, cq_d1 + 1024,
                                 out_g1, out_be1, out_W2, out_b2, y_out);

  // ---- decoder L2: dbuf 128^2 with FUSED stats (432 blocks, no split-K) ----
  {
    GA g0{h3b, dW2T, Z, nullptr, cs_d2, cq_d2, 3456, 1024, 1024, 1024};
    gemm128z<<<dim3(16,27,1),256,0,stream>>>(g0, g0, g0, g0);
  }
  apply_bn4<<<CDIV(2048*843,256),256,0,stream>>>(Z, nullptr, nullptr, 3456, 2048*843, 843,
      cs_d2, cq_d2, dec_g2, dec_be2, 0, dec_out, 3372, nullptr, 0);
}

// Round 20
// 271.761 us; speedup vs baseline: 1.2450x; 1.0114x over previous
//
#include <hip/hip_runtime.h>

#define CDIV(a,b) (((a)+(b)-1)/(b))

typedef __attribute__((ext_vector_type(8))) short bf16x8;
typedef __attribute__((ext_vector_type(4))) float f32x4;

__device__ __forceinline__ unsigned short f2b(float v) {
  union { float f; unsigned u; } x; x.f = v;
  unsigned r = x.u + 0x7FFFu + ((x.u >> 16) & 1u);
  return (unsigned short)(r >> 16);
}
__device__ __forceinline__ float b2f(unsigned short u) {
  union { unsigned u32; float f; } x; x.u32 = ((unsigned)u) << 16; return x.f;
}
__device__ __forceinline__ float4 ld4b(const unsigned short* p) {
  ushort4 u = *(const ushort4*)p;
  float4 v; v.x = b2f(u.x); v.y = b2f(u.y); v.z = b2f(u.z); v.w = b2f(u.w);
  return v;
}

__device__ __forceinline__ void gload_lds16(const void* g, void* l) {
  __builtin_amdgcn_global_load_lds(
      (const __attribute__((address_space(1))) unsigned int*)(g),
      (__attribute__((address_space(3))) unsigned int*)(l), 16, 0, 0);
}

struct GA {
  const unsigned short* A;
  const unsigned short* B;
  unsigned short* C;     // bf16 output
  const int* ridx;
  float* csum;           // non-null => fused column stats (REQUIRES no split-K)
  float* csumsq;
  int N, K, lda, ldb;
};

// ---- 128x128 MFMA GEMM, dbuf LDS + counted vmcnt, XOR-swizzled, optional
// A-row indirection + optional fused column stats; z selects operand set.
__global__ __launch_bounds__(256) void gemm128z(GA g0, GA g1, GA g2, GA g3) {
  __shared__ __align__(16) unsigned short As[2][128 * 64];
  __shared__ __align__(16) unsigned short Bs[2][128 * 64];
  const int z = blockIdx.z;
  GA g = (z == 0) ? g0 : (z == 1) ? g1 : (z == 2) ? g2 : g3;

  const int tid = threadIdx.x;
  const int lane = tid & 63;
  const int wid = tid >> 6;
  const int wm = (wid >> 1) * 64;
  const int wn = (wid & 1) * 64;
  const long bm = (long)blockIdx.x * 128;
  const long bn = (long)blockIdx.y * 128;

  f32x4 acc[4][4] = {};

  const int lr = tid >> 3;
  const int lc = (((tid & 7) ^ (lr & 7)) * 8);

  const unsigned short* ap[4];
  const unsigned short* bp[4];
#pragma unroll
  for (int i = 0; i < 4; ++i) {
    long row = bm + i * 32 + lr;
    long arow = g.ridx ? (long)g.ridx[row] : row;
    ap[i] = g.A + arow * g.lda + lc;
    bp[i] = g.B + (bn + i * 32 + lr) * (long)g.ldb + lc;
  }

  const int rsel = lane & 15;
  const int rx = rsel & 7;

  auto STAGE = [&](int buf, int k0) {
#pragma unroll
    for (int i = 0; i < 4; ++i) {
      const int eoff = (i * 256 + tid) * 8;
      gload_lds16(ap[i] + k0, &As[buf][eoff]);
      gload_lds16(bp[i] + k0, &Bs[buf][eoff]);
    }
  };
  auto COMPUTE = [&](int buf) {
#pragma unroll
    for (int kk = 0; kk < 2; ++kk) {
      const int koz = (((kk * 4 + (lane >> 4)) ^ rx) << 3);
      bf16x8 av[4], bv[4];
#pragma unroll
      for (int m = 0; m < 4; ++m)
        av[m] = *(const bf16x8*)(&As[buf][(wm + m * 16 + rsel) * 64 + koz]);
#pragma unroll
      for (int n = 0; n < 4; ++n)
        bv[n] = *(const bf16x8*)(&Bs[buf][(wn + n * 16 + rsel) * 64 + koz]);
#pragma unroll
      for (int m = 0; m < 4; ++m)
#pragma unroll
        for (int n = 0; n < 4; ++n)
          acc[m][n] = __builtin_amdgcn_mfma_f32_16x16x32_bf16(av[m], bv[n], acc[m][n], 0, 0, 0);
    }
  };

  STAGE(0, 0);
  int cur = 0;
  for (int k0 = 64; k0 < g.K; k0 += 64) {
    STAGE(cur ^ 1, k0);
    asm volatile("s_waitcnt vmcnt(8)" ::: "memory");
    __builtin_amdgcn_s_barrier();
    asm volatile("" ::: "memory");
    COMPUTE(cur);
    asm volatile("" ::: "memory");
    __builtin_amdgcn_s_barrier();
    cur ^= 1;
  }
  asm volatile("s_waitcnt vmcnt(0)" ::: "memory");
  __builtin_amdgcn_s_barrier();
  asm volatile("" ::: "memory");
  COMPUTE(cur);

  const int crow0 = (lane >> 4) * 4;
  const int ccol = lane & 15;
#pragma unroll
  for (int m = 0; m < 4; ++m)
#pragma unroll
    for (int n = 0; n < 4; ++n) {
      const long r = bm + wm + m * 16 + crow0;
      const long c = bn + wn + n * 16 + ccol;
#pragma unroll
      for (int q = 0; q < 4; ++q)
        g.C[(r + q) * (long)g.N + c] = f2b(acc[m][n][q]);
    }

  if (g.csum) {
#pragma unroll
    for (int n = 0; n < 4; ++n) {
      float s = 0.f, s2 = 0.f;
#pragma unroll
      for (int m = 0; m < 4; ++m)
#pragma unroll
        for (int q = 0; q < 4; ++q) {
          float v = acc[m][n][q];
          s += v; s2 += v * v;
        }
      s  += __shfl_xor(s, 16);  s  += __shfl_xor(s, 32);
      s2 += __shfl_xor(s2, 16); s2 += __shfl_xor(s2, 32);
      if ((lane >> 4) == 0) {
        const long c = bn + wn + n * 16 + ccol;
        atomicAdd(&g.csum[c], s);
        atomicAdd(&g.csumsq[c], s2);
      }
    }
  }
}

// ---- 64x128 MFMA GEMM, dbuf + counted vmcnt, swizzled, optional fused stats
__global__ __launch_bounds__(256) void gemm64s(GA g0, GA g1, GA g2, GA g3) {
  __shared__ __align__(16) unsigned short As[2][64 * 64];
  __shared__ __align__(16) unsigned short Bs[2][128 * 64];
  const int z = blockIdx.z;
  GA g = (z == 0) ? g0 : (z == 1) ? g1 : (z == 2) ? g2 : g3;

  const int tid = threadIdx.x;
  const int lane = tid & 63;
  const int wid = tid >> 6;
  const int wn = wid * 32;
  const long bm = (long)blockIdx.x * 64;
  const long bn = (long)blockIdx.y * 128;

  f32x4 acc[4][2] = {};

  const int lr = tid >> 3;
  const int lc = (((tid & 7) ^ (lr & 7)) * 8);

  const long r0 = g.ridx ? (long)g.ridx[bm + lr] : bm + lr;
  const long r1 = g.ridx ? (long)g.ridx[bm + 32 + lr] : bm + 32 + lr;
  const unsigned short* ap0 = g.A + r0 * g.lda + lc;
  const unsigned short* ap1 = g.A + r1 * g.lda + lc;
  const unsigned short* bp0 = g.B + (bn + lr) * (long)g.ldb + lc;
  const unsigned short* bp1 = g.B + (bn + 32 + lr) * (long)g.ldb + lc;
  const unsigned short* bp2 = g.B + (bn + 64 + lr) * (long)g.ldb + lc;
  const unsigned short* bp3 = g.B + (bn + 96 + lr) * (long)g.ldb + lc;

  const int rsel = lane & 15;
  const int rx = rsel & 7;

  auto STAGE = [&](int buf, int k0) {
    gload_lds16(ap0 + k0, &As[buf][tid * 8]);
    gload_lds16(ap1 + k0, &As[buf][(256 + tid) * 8]);
    gload_lds16(bp0 + k0, &Bs[buf][tid * 8]);
    gload_lds16(bp1 + k0, &Bs[buf][(256 + tid) * 8]);
    gload_lds16(bp2 + k0, &Bs[buf][(512 + tid) * 8]);
    gload_lds16(bp3 + k0, &Bs[buf][(768 + tid) * 8]);
  };
  auto COMPUTE = [&](int buf) {
#pragma unroll
    for (int kk = 0; kk < 2; ++kk) {
      const int koz = (((kk * 4 + (lane >> 4)) ^ rx) << 3);
      bf16x8 av[4], bv[2];
#pragma unroll
      for (int m = 0; m < 4; ++m)
        av[m] = *(const bf16x8*)(&As[buf][(m * 16 + rsel) * 64 + koz]);
#pragma unroll
      for (int n = 0; n < 2; ++n)
        bv[n] = *(const bf16x8*)(&Bs[buf][(wn + n * 16 + rsel) * 64 + koz]);
#pragma unroll
      for (int m = 0; m < 4; ++m)
#pragma unroll
        for (int n = 0; n < 2; ++n)
          acc[m][n] = __builtin_amdgcn_mfma_f32_16x16x32_bf16(av[m], bv[n], acc[m][n], 0, 0, 0);
    }
  };

  STAGE(0, 0);
  int cur = 0;
  for (int k0 = 64; k0 < g.K; k0 += 64) {
    STAGE(cur ^ 1, k0);
    asm volatile("s_waitcnt vmcnt(6)" ::: "memory");
    __builtin_amdgcn_s_barrier();
    asm volatile("" ::: "memory");
    COMPUTE(cur);
    asm volatile("" ::: "memory");
    __builtin_amdgcn_s_barrier();
    cur ^= 1;
  }
  asm volatile("s_waitcnt vmcnt(0)" ::: "memory");
  __builtin_amdgcn_s_barrier();
  asm volatile("" ::: "memory");
  COMPUTE(cur);

  const int crow0 = (lane >> 4) * 4;
  const int ccol = lane & 15;
#pragma unroll
  for (int m = 0; m < 4; ++m)
#pragma unroll
    for (int n = 0; n < 2; ++n) {
      const long r = bm + m * 16 + crow0;
      const long c = bn + wn + n * 16 + ccol;
#pragma unroll
      for (int q = 0; q < 4; ++q)
        g.C[(r + q) * (long)g.N + c] = f2b(acc[m][n][q]);
    }

  if (g.csum) {
#pragma unroll
    for (int n = 0; n < 2; ++n) {
      float s = 0.f, s2 = 0.f;
#pragma unroll
      for (int m = 0; m < 4; ++m)
#pragma unroll
        for (int q = 0; q < 4; ++q) {
          float v = acc[m][n][q];
          s += v; s2 += v * v;
        }
      s  += __shfl_xor(s, 16);  s  += __shfl_xor(s, 32);
      s2 += __shfl_xor(s2, 16); s2 += __shfl_xor(s2, 32);
      if ((lane >> 4) == 0) {
        const long c = bn + wn + n * 16 + ccol;
        atomicAdd(&g.csum[c], s);
        atomicAdd(&g.csumsq[c], s2);
      }
    }
  }
}

// ---------------- merged prep kernels ----------------
__global__ void init_all(int* iz, int nIz, float* deg, int nDeg,
                         float* stats, int nStats) {
  int i = blockIdx.x * 256 + threadIdx.x;
  if (i < nIz) iz[i] = 0;
  if (i < nDeg) deg[i] = 1.f;
  if (i < nStats) stats[i] = 0.f;
}

__global__ void prep_b(const int* __restrict__ d_ei, const float* __restrict__ d_ew,
                       float* __restrict__ deg_d,
                       const int* __restrict__ p_ei, const float* __restrict__ p_ew,
                       float* __restrict__ deg_p,
                       const int* __restrict__ d_index, int* __restrict__ flag_d,
                       const int* __restrict__ p_index, int* __restrict__ flag_p) {
  int e = blockIdx.x * 256 + threadIdx.x;
  if (e < 65536) atomicAdd(&deg_d[d_ei[65536 + e]], d_ew[e]);
  int e2 = e - 65536;
  if (e2 >= 0 && e2 < 25000) atomicAdd(&deg_p[p_ei[25000 + e2]], p_ew[e2]);
  if (e < 2048) flag_d[d_index[e]] = 1;
  else if (e < 4096) flag_p[p_index[e - 2048]] = 1;
}

__global__ void prep_c(float* __restrict__ deg, int nDeg,
                       int* __restrict__ flag_d, int* __restrict__ ctr_d,
                       int* __restrict__ slot_d,
                       int* __restrict__ flag_p, int* __restrict__ ctr_p,
                       int* __restrict__ slot_p) {
  int i = blockIdx.x * 256 + threadIdx.x;
  if (i < nDeg) deg[i] = rsqrtf(deg[i]);
  if (i < 10000) {
    if (flag_d[i]) { int s = atomicAdd(ctr_d, 1); flag_d[i] = s + 1; slot_d[s] = i; }
  } else if (i < 15000) {
    int j = i - 10000;
    if (flag_p[j]) { int s = atomicAdd(ctr_p, 1); flag_p[j] = s + 1; slot_p[s] = j; }
  }
}

__global__ void prep_d(const int* __restrict__ d_index, const int* __restrict__ flag_d,
                       int* __restrict__ ridx_d,
                       const int* __restrict__ p_index, const int* __restrict__ flag_p,
                       int* __restrict__ ridx_p,
                       const int* __restrict__ d_ei, int* __restrict__ cnt_d,
                       const int* __restrict__ p_ei, int* __restrict__ cnt_p) {
  int e = blockIdx.x * 256 + threadIdx.x;
  if (e < 2048) ridx_d[e] = flag_d[d_index[e]] - 1;
  else if (e < 4096) { int j = e - 2048; ridx_p[j] = flag_p[p_index[j]] - 1; }
  if (e < 65536) { int s = flag_d[d_ei[65536 + e]]; if (s) atomicAdd(&cnt_d[s - 1], 1); }
  int e2 = e - 65536;
  if (e2 >= 0 && e2 < 25000) { int s = flag_p[p_ei[25000 + e2]]; if (s) atomicAdd(&cnt_p[s - 1], 1); }
}

__global__ void scan2048x2(const int* __restrict__ cnt_d, int* __restrict__ rp_d,
                           const int* __restrict__ cnt_p, int* __restrict__ rp_p) {
  const int* cnt = blockIdx.x ? cnt_p : cnt_d;
  int* rowptr    = blockIdx.x ? rp_p : rp_d;
  __shared__ int part[256];
  int tid = threadIdx.x;
  int base = tid * 8;
  int vals[8]; int s = 0;
#pragma unroll
  for (int i = 0; i < 8; ++i) { vals[i] = s; s += cnt[base + i]; }
  part[tid] = s;
  __syncthreads();
  if (tid == 0) { int r = 0; for (int i = 0; i < 256; ++i) { int t = part[i]; part[i] = r; r += t; } }
  __syncthreads();
  int off = part[tid];
#pragma unroll
  for (int i = 0; i < 8; ++i) rowptr[base + i] = off + vals[i];
  if (tid == 255) rowptr[2048] = off + s;
}
__global__ void fill_edges2(
    const int* __restrict__ d_ei, const float* __restrict__ d_ew,
    const float* __restrict__ dinv_d, const int* __restrict__ flag_d,
    const int* __restrict__ rp_d, int* __restrict__ fill_d,
    int2* __restrict__ em_d,
    const int* __restrict__ p_ei, const float* __restrict__ p_ew,
    const float* __restrict__ dinv_p, const int* __restrict__ flag_p,
    const int* __restrict__ rp_p, int* __restrict__ fill_p,
    int2* __restrict__ em_p) {
  int e = blockIdx.x * 256 + threadIdx.x;
  if (e < 65536) {
    int dst = d_ei[65536 + e];
    int s = flag_d[dst];
    if (s) {
      int src = d_ei[e];
      int pos = rp_d[s - 1] + atomicAdd(&fill_d[s - 1], 1);
      float cf = d_ew[e] * dinv_d[src] * dinv_d[dst];
      em_d[pos] = make_int2(src, __float_as_int(cf));
    }
  }
  int e2 = e - 65536;
  if (e2 >= 0 && e2 < 25000) {
    int dst = p_ei[25000 + e2];
    int s = flag_p[dst];
    if (s) {
      int src = p_ei[e2];
      int pos = rp_p[s - 1] + atomicAdd(&fill_p[s - 1], 1);
      float cf = p_ew[e2] * dinv_p[src] * dinv_p[dst];
      em_p[pos] = make_int2(src, __float_as_int(cf));
    }
  }
}

// ---- merged gather + weight transposes, one launch.
// blocks [0,7680): wave-per-(slot, 64-f4 chunk) gather (4 waves/block).
// blocks [7680, 7680+11296): 32x32 weight-transpose tiles (bf16, padded).
__global__ __launch_bounds__(256) void gather_or_transpose(
    const float* __restrict__ Xd, const float* __restrict__ dinv_d,
    const int* __restrict__ slot_d, const int* __restrict__ rp_d,
    const int2* __restrict__ em_d,
    const int* __restrict__ nflag_d, unsigned short* __restrict__ aggd,
    const float* __restrict__ Xp, const float* __restrict__ dinv_p,
    const int* __restrict__ slot_p, const int* __restrict__ rp_p,
    const int2* __restrict__ em_p,
    const int* __restrict__ nflag_p, unsigned short* __restrict__ aggp,
    const float* W0, unsigned short* T0,
    const float* W1, unsigned short* T1,
    const float* W2, unsigned short* T2,
    const float* W3, unsigned short* T3,
    const float* W4, unsigned short* T4,
    const float* W5, unsigned short* T5,
    const float* W6, unsigned short* T6)
{
  __shared__ float tile[32][33];
  const int tid = threadIdx.x;

  if (blockIdx.x >= 7680) {
    // ---------- transpose role ----------
    int bid = blockIdx.x - 7680;
    const float* W; unsigned short* Wt; int K, N, Kp, Np_, tx, local;
    if      (bid <  1024) { W=W0; Wt=T0; K=1024; N=1024; Kp=1024; Np_=1024; tx=32;  local=bid; }
    else if (bid <  3840) { W=W1; Wt=T1; K=2812; N=1024; Kp=2816; Np_=1024; tx=88;  local=bid-1024; }
    else if (bid <  7296) { W=W2; Wt=T2; K=3372; N=1024; Kp=3456; Np_=1024; tx=108; local=bid-3840; }
    else if (bid <  7552) { W=W3; Wt=T3; K=1024; N=256;  Kp=1024; Np_=256;  tx=32;  local=bid-7296; }
    else if (bid <  7808) { W=W4; Wt=T4; K=256;  N=1024; Kp=256;  Np_=1024; tx=8;   local=bid-7552; }
    else if (bid <  7840) { W=W5; Wt=T5; K=256;  N=64;   Kp=256;  Np_=128;  tx=8;   local=bid-7808; }
    else                  { W=W6; Wt=T6; K=1024; N=3372; Kp=1024; Np_=3456; tx=32;  local=bid-7840; }
    const int thx = tid & 31, thy = tid >> 5;   // 32 x 8
    int k0 = (local % tx) * 32, n0 = (local / tx) * 32;
    for (int i = thy; i < 32; i += 8) {
      int k = k0 + i, n = n0 + thx;
      tile[i][thx] = (k < K && n < N) ? W[(size_t)k * N + n] : 0.f;
    }
    __syncthreads();
    for (int i = thy; i < 32; i += 8) {
      int n = n0 + i, k = k0 + thx;
      if (n < Np_ && k < Kp) Wt[(size_t)n * Kp + k] = f2b(tile[thx][i]);
    }
    return;
  }

  // ---------- gather role ----------
  const int gw = blockIdx.x * 4 + (tid >> 6);
  const int lane = tid & 63;

  int slot, c, Kdata4, Kst4, Kld, nflag;
  const float *X, *dinv; const int *slotn, *rp; const int2* em;
  unsigned short* agg;
  if (gw < 8192) {
    slot = gw >> 2;
    c = (gw & 3) * 64 + lane;
    X = Xd; dinv = dinv_d; slotn = slot_d; rp = rp_d; em = em_d;
    nflag = *nflag_d; agg = aggd; Kdata4 = 256; Kst4 = 256; Kld = 1024;
  } else {
    int q = gw - 8192;
    slot = q / 11;
    c = (q - slot * 11) * 64 + lane;
    X = Xp; dinv = dinv_p; slotn = slot_p; rp = rp_p; em = em_p;
    nflag = *nflag_p; agg = aggp; Kdata4 = 703; Kst4 = 704; Kld = 2812;
  }
  if (slot >= nflag) return;

  const int n = slotn[slot];
  const float dn = dinv[n];
  const float selfc = dn * dn;
  const int e0 = rp[slot], e1 = rp[slot + 1];
  const bool valid = c < Kdata4;

  float ax = 0.f, ay = 0.f, az = 0.f, aw = 0.f;
  if (valid) {
    float4 v = *(const float4*)(X + (long)n * Kld + 4 * c);
    ax = selfc * v.x; ay = selfc * v.y; az = selfc * v.z; aw = selfc * v.w;
  }

  int e = e0;
  for (; e + 4 <= e1; e += 4) {
    const int2 m0 = em[e], m1 = em[e + 1], m2 = em[e + 2], m3 = em[e + 3];
    if (valid) {
      float4 v0 = *(const float4*)(X + (long)m0.x * Kld + 4 * c);
      float4 v1 = *(const float4*)(X + (long)m1.x * Kld + 4 * c);
      float4 v2 = *(const float4*)(X + (long)m2.x * Kld + 4 * c);
      float4 v3 = *(const float4*)(X + (long)m3.x * Kld + 4 * c);
      const float c0 = __int_as_float(m0.y), c1 = __int_as_float(m1.y);
      const float c2 = __int_as_float(m2.y), c3 = __int_as_float(m3.y);
      ax += c0 * v0.x; ay += c0 * v0.y; az += c0 * v0.z; aw += c0 * v0.w;
      ax += c1 * v1.x; ay += c1 * v1.y; az += c1 * v1.z; aw += c1 * v1.w;
      ax += c2 * v2.x; ay += c2 * v2.y; az += c2 * v2.z; aw += c2 * v2.w;
      ax += c3 * v3.x; ay += c3 * v3.y; az += c3 * v3.z; aw += c3 * v3.w;
    }
  }
  for (; e < e1; ++e) {
    const int2 m = em[e];
    if (valid) {
      float4 v = *(const float4*)(X + (long)m.x * Kld + 4 * c);
      const float cf = __int_as_float(m.y);
      ax += cf * v.x; ay += cf * v.y; az += cf * v.z; aw += cf * v.w;
    }
  }

  if (c < Kst4) {
    ushort4 o; o.x = f2b(ax); o.y = f2b(ay); o.z = f2b(az); o.w = f2b(aw);
    *(ushort4*)(agg + (long)slot * (Kst4 * 4) + 4 * c) = o;
  }
}

// vectorized colstats over bf16 partials (for split-K layers only)
__global__ void colstats4(const unsigned short* __restrict__ Z,
                          const unsigned short* __restrict__ Z2,
                          const unsigned short* __restrict__ Z3, int ldz, int cols,
                          float* __restrict__ csum, float* __restrict__ csumsq) {
  int c4 = blockIdx.x * 256 + threadIdx.x;
  if (c4 * 4 >= cols) return;
  int r0 = blockIdx.y * 16;
  float sx = 0.f, sy = 0.f, sz_ = 0.f, sw = 0.f;
  float qx = 0.f, qy = 0.f, qz = 0.f, qw = 0.f;
  for (int r = r0; r < r0 + 16; ++r) {
    float4 v = ld4b(Z + (long)r * ldz + 4 * c4);
    if (Z2) { float4 w = ld4b(Z2 + (long)r * ldz + 4 * c4);
              v.x += w.x; v.y += w.y; v.z += w.z; v.w += w.w; }
    if (Z3) { float4 w = ld4b(Z3 + (long)r * ldz + 4 * c4);
              v.x += w.x; v.y += w.y; v.z += w.z; v.w += w.w; }
    sx += v.x; sy += v.y; sz_ += v.z; sw += v.w;
    qx += v.x * v.x; qy += v.y * v.y; qz += v.z * v.z; qw += v.w * v.w;
  }
  atomicAdd(&csum[4 * c4 + 0], sx); atomicAdd(&csum[4 * c4 + 1], sy);
  atomicAdd(&csum[4 * c4 + 2], sz_); atomicAdd(&csum[4 * c4 + 3], sw);
  atomicAdd(&csumsq[4 * c4 + 0], qx); atomicAdd(&csumsq[4 * c4 + 1], qy);
  atomicAdd(&csumsq[4 * c4 + 2], qz); atomicAdd(&csumsq[4 * c4 + 3], qw);
}

// apply with INLINE bn-finalize over bf16 partials. csum==null -> bias-only.
__global__ void apply_bn4(const unsigned short* __restrict__ Z,
                          const unsigned short* __restrict__ Z2,
                          const unsigned short* __restrict__ Z3,
                          int ldz, int total4, int cols4,
                          const float* __restrict__ csum, const float* __restrict__ csumsq,
                          const float* __restrict__ g, const float* __restrict__ beta,
                          int leaky,
                          float* __restrict__ f32out, int ldf,
                          unsigned short* __restrict__ b16out, int ldb) {
  int idx = blockIdx.x*256+threadIdx.x;
  if (idx >= total4) return;
  int b = idx / cols4, j = (idx % cols4) * 4;
  float4 v = ld4b(Z + (long)b * ldz + j);
  if (Z2) { float4 w = ld4b(Z2 + (long)b * ldz + j);
            v.x += w.x; v.y += w.y; v.z += w.z; v.w += w.w; }
  if (Z3) { float4 w = ld4b(Z3 + (long)b * ldz + j);
            v.x += w.x; v.y += w.y; v.z += w.z; v.w += w.w; }
  if (csum) {
    const float invB = 1.f / 2048.f;
    float4 cs = *(const float4*)(csum + j);
    float4 cq = *(const float4*)(csumsq + j);
    float4 gg = *(const float4*)(g + j);
    float4 bb = *(const float4*)(beta + j);
    float m, var, sc;
    m = cs.x * invB; var = fmaxf(cq.x * invB - m * m, 0.f);
    sc = gg.x * rsqrtf(var + 1e-5f); v.x = v.x * sc + (bb.x - m * sc);
    m = cs.y * invB; var = fmaxf(cq.y * invB - m * m, 0.f);
    sc = gg.y * rsqrtf(var + 1e-5f); v.y = v.y * sc + (bb.y - m * sc);
    m = cs.z * invB; var = fmaxf(cq.z * invB - m * m, 0.f);
    sc = gg.z * rsqrtf(var + 1e-5f); v.z = v.z * sc + (bb.z - m * sc);
    m = cs.w * invB; var = fmaxf(cq.w * invB - m * m, 0.f);
    sc = gg.w * rsqrtf(var + 1e-5f); v.w = v.w * sc + (bb.w - m * sc);
  } else {
    float4 bb = *(const float4*)(beta + j);
    v.x += bb.x; v.y += bb.y; v.z += bb.z; v.w += bb.w;
  }
  const float neg = leaky ? 0.01f : 0.f;
  v.x = (v.x >= 0.f) ? v.x : neg * v.x;
  v.y = (v.y >= 0.f) ? v.y : neg * v.y;
  v.z = (v.z >= 0.f) ? v.z : neg * v.z;
  v.w = (v.w >= 0.f) ? v.w : neg * v.w;
  if (f32out) *(float4*)(f32out + (long)b * ldf + j) = v;
  if (b16out) {
    ushort4 o; o.x = f2b(v.x); o.y = f2b(v.y); o.z = f2b(v.z); o.w = f2b(v.w);
    *(ushort4*)(b16out + (long)b * ldb + j) = o;
  }
}

// GCN applies (bf16 partials) + feat copy + pad in one launch.
__global__ void apply_feat(const unsigned short* __restrict__ Zd,
                           const unsigned short* __restrict__ Pd,
                           const float* __restrict__ bd,
                           const unsigned short* __restrict__ Zp,
                           const unsigned short* __restrict__ Pp,
                           const float* __restrict__ bp,
                           const float* __restrict__ dv, const float* __restrict__ pe,
                           float* __restrict__ feat_f32, unsigned short* __restrict__ feat_b16) {
  int idx = blockIdx.x*256+threadIdx.x;
  const int APPLY_N = 2 * 2048 * 256;
  if (idx < APPLY_N) {
    const bool isP = idx >= 2048 * 256;
    int l = isP ? idx - 2048 * 256 : idx;
    int b = l >> 8, j = (l & 255) * 4;
    const unsigned short* Z = isP ? Zp : Zd;
    const unsigned short* P = isP ? Pp : Pd;
    const float* bias = isP ? bp : bd;
    const int coloff = isP ? 2348 : 1324;
    float4 v = ld4b(Z + (long)b * 1024 + j);
    float4 w = ld4b(P + (long)b * 1024 + j);
    float4 bb = *(const float4*)(bias + j);
    v.x += w.x + bb.x; v.y += w.y + bb.y; v.z += w.z + bb.z; v.w += w.w + bb.w;
    v.x = (v.x >= 0.f) ? v.x : 0.01f * v.x;
    v.y = (v.y >= 0.f) ? v.y : 0.01f * v.y;
    v.z = (v.z >= 0.f) ? v.z : 0.01f * v.z;
    v.w = (v.w >= 0.f) ? v.w : 0.01f * v.w;
    *(float4*)(feat_f32 + (long)b * 3372 + coloff + j) = v;
    ushort4 o; o.x = f2b(v.x); o.y = f2b(v.y); o.z = f2b(v.z); o.w = f2b(v.w);
    *(ushort4*)(feat_b16 + (long)b * 3456 + coloff + j) = o;
    return;
  }
  int q = idx - APPLY_N;
  if (q >= 2048 * 352) return;
  int b = q / 352, u = q % 352;
  if (u < 331) {
    int c = u * 4;
    float4 v;
    if (u < 75) v = *(const float4*)(dv + (long)b * 300 + c);
    else        v = *(const float4*)(pe + (long)b * 1024 + (c - 300));
    *(float4*)(feat_f32 + (long)b * 3372 + c) = v;
    ushort4 o; o.x = f2b(v.x); o.y = f2b(v.y); o.z = f2b(v.z); o.w = f2b(v.w);
    *(ushort4*)(feat_b16 + (long)b * 3456 + c) = o;
  } else {
    int c = 3372 + (u - 331) * 4;
    ushort4 o; o.x = 0; o.y = 0; o.z = 0; o.w = 0;
    *(ushort4*)(feat_b16 + (long)b * 3456 + c) = o;
  }
}

// head: bn(inline stats) + lrelu + dot(W2) + b2 -> y   (Z bf16)
__global__ void head_fused(const unsigned short* __restrict__ Z, int ldz,
                           const float* __restrict__ csum, const float* __restrict__ csumsq,
                           const float* __restrict__ g, const float* __restrict__ beta,
                           const float* __restrict__ W2, const float* __restrict__ b2,
                           float* __restrict__ y) {
  int b = blockIdx.x*256+threadIdx.x;
  if (b >= 2048) return;
  const float invB = 1.f / 2048.f;
  float s = b2[0];
  for (int k = 0; k < 64; ++k) {
    float m = csum[k] * invB;
    float var = fmaxf(csumsq[k] * invB - m * m, 0.f);
    float sc = g[k] * rsqrtf(var + 1e-5f);
    float sh = beta[k] - m * sc;
    float v = b2f(Z[(long)b * ldz + k]);
    v = v * sc + sh;
    v = (v >= 0.f) ? v : 0.01f * v;
    s += v * W2[k];
  }
  y[b] = s;
}

extern "C" void kernel_launch(void* const* d_in, const int* in_sizes, int n_in,
                              void* d_out, int out_size, void* d_ws, size_t ws_size,
                              hipStream_t stream) {
  (void)in_sizes; (void)n_in; (void)out_size; (void)ws_size;
  const int*   d_index = (const int*)d_in[0];
  const int*   p_index = (const int*)d_in[1];
  const float* d_vecs  = (const float*)d_in[2];
  const float* p_emb   = (const float*)d_in[3];
  const float* d_ecfps = (const float*)d_in[4];
  const int*   d_ei    = (const int*)d_in[5];
  const float* d_ew    = (const float*)d_in[6];
  const float* p_gos   = (const float*)d_in[7];
  const int*   p_ei    = (const int*)d_in[8];
  const float* p_ew    = (const float*)d_in[9];
  const float* d_gcn_W = (const float*)d_in[10];
  const float* d_gcn_b = (const float*)d_in[11];
  const float* p_gcn_W = (const float*)d_in[12];
  const float* p_gcn_b = (const float*)d_in[13];
  const float* enc_W1  = (const float*)d_in[14];
  const float* enc_g1  = (const float*)d_in[16];
  const float* enc_be1 = (const float*)d_in[17];
  const float* enc_W2  = (const float*)d_in[18];
  const float* enc_g2  = (const float*)d_in[20];
  const float* enc_be2 = (const float*)d_in[21];
  const float* dec_W1  = (const float*)d_in[22];
  const float* dec_g1  = (const float*)d_in[24];
  const float* dec_be1 = (const float*)d_in[25];
  const float* dec_W2  = (const float*)d_in[26];
  const float* dec_g2  = (const float*)d_in[28];
  const float* dec_be2 = (const float*)d_in[29];
  const float* out_W1  = (const float*)d_in[30];
  const float* out_g1  = (const float*)d_in[32];
  const float* out_be1 = (const float*)d_in[33];
  const float* out_W2  = (const float*)d_in[34];
  const float* out_b2  = (const float*)d_in[35];

  float* out = (float*)d_out;
  float* y_out    = out;
  float* enc_out  = out + 2048;
  float* dec_out  = out + 526336;
  float* feat_out = out + 7432192;

  char* ws = (char*)d_ws;
  size_t off = 0;
  auto alloc = [&](size_t bytes) {
    size_t o = off; off = (off + bytes + 255) & ~(size_t)255; return (void*)(ws + o);
  };
  int* iz = (int*)alloc((size_t)23200 * 4);
  int* flag_d = iz;
  int* flag_p = iz + 10000;
  int* cnt_d  = iz + 15000;
  int* cnt_p  = iz + 17048;
  int* fill_d = iz + 19096;
  int* fill_p = iz + 21144;
  int* ctr    = iz + 23192;
  int* slotnode_d = (int*)alloc(2048 * 4);
  int* slotnode_p = (int*)alloc(2048 * 4);
  int* rowptr_d = (int*)alloc(2049 * 4);
  int* rowptr_p = (int*)alloc(2049 * 4);
  int* ridx_d = (int*)alloc(2048 * 4);
  int* ridx_p = (int*)alloc(2048 * 4);
  int2* em_d = (int2*)alloc((size_t)65536 * 8);
  int2* em_p = (int2*)alloc((size_t)25000 * 8);
  float* deg   = (float*)alloc((size_t)15000 * 4);
  float* deg_d = deg;
  float* deg_p = deg + 10000;
  float* stats = (float*)alloc((size_t)34560 * 4);
  float* cs_e1 = stats,         * cq_e1 = stats + 3456;
  float* cs_e2 = stats + 6912,  * cq_e2 = stats + 10368;
  float* cs_d1 = stats + 13824, * cq_d1 = stats + 17280;
  float* cs_d2 = stats + 27648, * cq_d2 = stats + 31104;
  unsigned short* aggd_b = (unsigned short*)alloc((size_t)2048 * 1024 * 2);
  unsigned short* aggp_b = (unsigned short*)alloc((size_t)2048 * 2816 * 2);
  unsigned short* WdT   = (unsigned short*)alloc((size_t)1024 * 1024 * 2);
  unsigned short* WpT   = (unsigned short*)alloc((size_t)1024 * 2816 * 2);
  unsigned short* eW1T  = (unsigned short*)alloc((size_t)1024 * 3456 * 2);
  unsigned short* eW2T  = (unsigned short*)alloc((size_t)256 * 1024 * 2);
  unsigned short* dhT   = (unsigned short*)alloc((size_t)1152 * 256 * 2);
  unsigned short* dW2T  = (unsigned short*)alloc((size_t)3456 * 1024 * 2);
  unsigned short* featb = (unsigned short*)alloc((size_t)2048 * 3456 * 2);
  unsigned short* Z   = (unsigned short*)alloc((size_t)2048 * 3456 * 2);
  unsigned short* P0  = (unsigned short*)alloc((size_t)2048 * 1152 * 2);
  unsigned short* P1  = (unsigned short*)alloc((size_t)2048 * 1152 * 2);
  unsigned short* P2  = (unsigned short*)alloc((size_t)2048 * 1152 * 2);
  unsigned short* h1b  = (unsigned short*)alloc((size_t)2048 * 1024 * 2);
  unsigned short* encb = (unsigned short*)alloc((size_t)2048 * 256 * 2);
  unsigned short* h3b  = (unsigned short*)alloc((size_t)2048 * 1024 * 2);

  // ---- GCN prep (merged launches) ----
  init_all<<<CDIV(34560,256),256,0,stream>>>(iz, 23200, deg, 15000, stats, 34560);
  prep_b<<<CDIV(90536,256),256,0,stream>>>(d_ei, d_ew, deg_d, p_ei, p_ew, deg_p,
                                           d_index, flag_d, p_index, flag_p);
  prep_c<<<CDIV(15000,256),256,0,stream>>>(deg, 15000, flag_d, ctr, slotnode_d,
                                           flag_p, ctr + 1, slotnode_p);
  prep_d<<<CDIV(90536,256),256,0,stream>>>(d_index, flag_d, ridx_d, p_index, flag_p, ridx_p,
                                           d_ei, cnt_d, p_ei, cnt_p);
  scan2048x2<<<2,256,0,stream>>>(cnt_d, rowptr_d, cnt_p, rowptr_p);
  fill_edges2<<<CDIV(90536,256),256,0,stream>>>(
      d_ei, d_ew, deg_d, flag_d, rowptr_d, fill_d, em_d,
      p_ei, p_ew, deg_p, flag_p, rowptr_p, fill_p, em_p);

  // ---- gather + all weight transposes in ONE launch (independent roles) ----
  gather_or_transpose<<<7680 + 11296, 256, 0, stream>>>(
      d_ecfps, deg_d, slotnode_d, rowptr_d, em_d, ctr, aggd_b,
      p_gos,   deg_p, slotnode_p, rowptr_p, em_p, ctr + 1, aggp_b,
      d_gcn_W, WdT, p_gcn_W, WpT, enc_W1, eW1T, enc_W2, eW2T,
      dec_W1, dhT, out_W1, dhT + (size_t)1024 * 256, dec_W2, dW2T);

  // ---- GCN GEMMs: dbuf 128^2, d splitK x2 + p splitK x2 (512 blocks) ----
  {
    GA gd0{aggd_b,        WdT,        Z,  ridx_d, nullptr, nullptr, 1024,  512, 1024, 1024};
    GA gd1{aggd_b + 512,  WdT + 512,  P0, ridx_d, nullptr, nullptr, 1024,  512, 1024, 1024};
    GA gp0{aggp_b,        WpT,        P1, ridx_p, nullptr, nullptr, 1024, 1408, 2816, 2816};
    GA gp1{aggp_b + 1408, WpT + 1408, P2, ridx_p, nullptr, nullptr, 1024, 1408, 2816, 2816};
    gemm128z<<<dim3(16,8,4),256,0,stream>>>(gd0, gd1, gp0, gp1);
  }
  apply_feat<<<CDIV(2*2048*256 + 2048*352,256),256,0,stream>>>(
      Z, P0, d_gcn_b, P1, P2, p_gcn_b, d_vecs, p_emb, feat_out, featb);

  // ---- encoder L1: dbuf 128^2, split-K x3 (384 blocks) ----
  {
    GA e0{featb,        eW1T,        Z,  nullptr, nullptr, nullptr, 1024, 1152, 3456, 3456};
    GA e1{featb + 1152, eW1T + 1152, P0, nullptr, nullptr, nullptr, 1024, 1152, 3456, 3456};
    GA e2{featb + 2304, eW1T + 2304, P1, nullptr, nullptr, nullptr, 1024, 1152, 3456, 3456};
    gemm128z<<<dim3(16,8,3),256,0,stream>>>(e0, e1, e2, e0);
  }
  colstats4<<<dim3(1,128),256,0,stream>>>(Z, P0, P1, 1024, 1024, cs_e1, cq_e1);
  apply_bn4<<<CDIV(2048*256,256),256,0,stream>>>(Z, P0, P1, 1024, 2048*256, 256,
      cs_e1, cq_e1, enc_g1, enc_be1, 0, nullptr, 0, h1b, 1024);

  // ---- encoder L2: split-K x2 -> encoded (64-tile dbuf) ----
  {
    GA e0{h1b,       eW2T,       Z,  nullptr, nullptr, nullptr, 256, 512, 1024, 1024};
    GA e1{h1b + 512, eW2T + 512, P0, nullptr, nullptr, nullptr, 256, 512, 1024, 1024};
    gemm64s<<<dim3(32,2,2),256,0,stream>>>(e0, e1, e0, e0);
  }
  colstats4<<<dim3(1,128),256,0,stream>>>(Z, P0, nullptr, 256, 256, cs_e2, cq_e2);
  apply_bn4<<<CDIV(2048*64,256),256,0,stream>>>(Z, P0, nullptr, 256, 2048*64, 64,
      cs_e2, cq_e2, enc_g2, enc_be2, 0, enc_out, 256, encb, 256);

  // ---- decoder L1 + head GEMM with FUSED stats (288 blocks, no split-K) ----
  {
    GA g0{encb, dhT, Z, nullptr, cs_d1, cq_d1, 1152, 256, 256, 256};
    gemm64s<<<dim3(32,9,1),256,0,stream>>>(g0, g0, g0, g0);
  }
  apply_bn4<<<CDIV(2048*256,256),256,0,stream>>>(Z, nullptr, nullptr, 1152, 2048*256, 256,
      cs_d1, cq_d1, dec_g1, dec_be1, 0, nullptr, 0, h3b, 1024);
  head_fused<<<8,256,0,stream>>>(Z + 1024, 1152, cs_d1 + 1024, cq_d1 + 1024,
                                 out_g1, out_be1, out_W2, out_b2, y_out);

  // ---- decoder L2: dbuf 128^2 with FUSED stats (432 blocks, no split-K) ----
  {
    GA g0{h3b, dW2T, Z, nullptr, cs_d2, cq_d2, 3456, 1024, 1024, 1024};
    gemm128z<<<dim3(16,27,1),256,0,stream>>>(g0, g0, g0, g0);
  }
  apply_bn4<<<CDIV(2048*843,256),256,0,stream>>>(Z, nullptr, nullptr, 3456, 2048*843, 843,
      cs_d2, cq_d2, dec_g2, dec_be2, 0, dec_out, 3372, nullptr, 0);
}

// Round 21
// 269.005 us; speedup vs baseline: 1.2578x; 1.0102x over previous
//
#include <hip/hip_runtime.h>

#define CDIV(a,b) (((a)+(b)-1)/(b))

typedef __attribute__((ext_vector_type(8))) short bf16x8;
typedef __attribute__((ext_vector_type(4))) float f32x4;

__device__ __forceinline__ unsigned short f2b(float v) {
  union { float f; unsigned u; } x; x.f = v;
  unsigned r = x.u + 0x7FFFu + ((x.u >> 16) & 1u);
  return (unsigned short)(r >> 16);
}
__device__ __forceinline__ float b2f(unsigned short u) {
  union { unsigned u32; float f; } x; x.u32 = ((unsigned)u) << 16; return x.f;
}
__device__ __forceinline__ float4 ld4b(const unsigned short* p) {
  ushort4 u = *(const ushort4*)p;
  float4 v; v.x = b2f(u.x); v.y = b2f(u.y); v.z = b2f(u.z); v.w = b2f(u.w);
  return v;
}

__device__ __forceinline__ void gload_lds16(const void* g, void* l) {
  __builtin_amdgcn_global_load_lds(
      (const __attribute__((address_space(1))) unsigned int*)(g),
      (__attribute__((address_space(3))) unsigned int*)(l), 16, 0, 0);
}

struct GA {
  const unsigned short* A;
  const unsigned short* B;
  unsigned short* C;     // bf16 output
  const int* ridx;
  float* csum;           // non-null => fused column stats (REQUIRES no split-K)
  float* csumsq;
  int N, K, lda, ldb;
};

// ---- 128x128 MFMA GEMM, dbuf LDS + counted vmcnt, XOR-swizzled, optional
// A-row indirection + optional fused column stats; z selects operand set.
__global__ __launch_bounds__(256) void gemm128z(GA g0, GA g1, GA g2, GA g3) {
  __shared__ __align__(16) unsigned short As[2][128 * 64];
  __shared__ __align__(16) unsigned short Bs[2][128 * 64];
  const int z = blockIdx.z;
  GA g = (z == 0) ? g0 : (z == 1) ? g1 : (z == 2) ? g2 : g3;

  const int tid = threadIdx.x;
  const int lane = tid & 63;
  const int wid = tid >> 6;
  const int wm = (wid >> 1) * 64;
  const int wn = (wid & 1) * 64;
  const long bm = (long)blockIdx.x * 128;
  const long bn = (long)blockIdx.y * 128;

  f32x4 acc[4][4] = {};

  const int lr = tid >> 3;
  const int lc = (((tid & 7) ^ (lr & 7)) * 8);

  const unsigned short* ap[4];
  const unsigned short* bp[4];
#pragma unroll
  for (int i = 0; i < 4; ++i) {
    long row = bm + i * 32 + lr;
    long arow = g.ridx ? (long)g.ridx[row] : row;
    ap[i] = g.A + arow * g.lda + lc;
    bp[i] = g.B + (bn + i * 32 + lr) * (long)g.ldb + lc;
  }

  const int rsel = lane & 15;
  const int rx = rsel & 7;

  auto STAGE = [&](int buf, int k0) {
#pragma unroll
    for (int i = 0; i < 4; ++i) {
      const int eoff = (i * 256 + tid) * 8;
      gload_lds16(ap[i] + k0, &As[buf][eoff]);
      gload_lds16(bp[i] + k0, &Bs[buf][eoff]);
    }
  };
  auto COMPUTE = [&](int buf) {
#pragma unroll
    for (int kk = 0; kk < 2; ++kk) {
      const int koz = (((kk * 4 + (lane >> 4)) ^ rx) << 3);
      bf16x8 av[4], bv[4];
#pragma unroll
      for (int m = 0; m < 4; ++m)
        av[m] = *(const bf16x8*)(&As[buf][(wm + m * 16 + rsel) * 64 + koz]);
#pragma unroll
      for (int n = 0; n < 4; ++n)
        bv[n] = *(const bf16x8*)(&Bs[buf][(wn + n * 16 + rsel) * 64 + koz]);
#pragma unroll
      for (int m = 0; m < 4; ++m)
#pragma unroll
        for (int n = 0; n < 4; ++n)
          acc[m][n] = __builtin_amdgcn_mfma_f32_16x16x32_bf16(av[m], bv[n], acc[m][n], 0, 0, 0);
    }
  };

  STAGE(0, 0);
  int cur = 0;
  for (int k0 = 64; k0 < g.K; k0 += 64) {
    STAGE(cur ^ 1, k0);
    asm volatile("s_waitcnt vmcnt(8)" ::: "memory");
    __builtin_amdgcn_s_barrier();
    asm volatile("" ::: "memory");
    COMPUTE(cur);
    asm volatile("" ::: "memory");
    __builtin_amdgcn_s_barrier();
    cur ^= 1;
  }
  asm volatile("s_waitcnt vmcnt(0)" ::: "memory");
  __builtin_amdgcn_s_barrier();
  asm volatile("" ::: "memory");
  COMPUTE(cur);

  const int crow0 = (lane >> 4) * 4;
  const int ccol = lane & 15;
#pragma unroll
  for (int m = 0; m < 4; ++m)
#pragma unroll
    for (int n = 0; n < 4; ++n) {
      const long r = bm + wm + m * 16 + crow0;
      const long c = bn + wn + n * 16 + ccol;
#pragma unroll
      for (int q = 0; q < 4; ++q)
        g.C[(r + q) * (long)g.N + c] = f2b(acc[m][n][q]);
    }

  if (g.csum) {
#pragma unroll
    for (int n = 0; n < 4; ++n) {
      float s = 0.f, s2 = 0.f;
#pragma unroll
      for (int m = 0; m < 4; ++m)
#pragma unroll
        for (int q = 0; q < 4; ++q) {
          float v = acc[m][n][q];
          s += v; s2 += v * v;
        }
      s  += __shfl_xor(s, 16);  s  += __shfl_xor(s, 32);
      s2 += __shfl_xor(s2, 16); s2 += __shfl_xor(s2, 32);
      if ((lane >> 4) == 0) {
        const long c = bn + wn + n * 16 + ccol;
        atomicAdd(&g.csum[c], s);
        atomicAdd(&g.csumsq[c], s2);
      }
    }
  }
}

// ---- 64x128 MFMA GEMM, dbuf + counted vmcnt, swizzled, optional fused stats
__global__ __launch_bounds__(256) void gemm64s(GA g0, GA g1, GA g2, GA g3) {
  __shared__ __align__(16) unsigned short As[2][64 * 64];
  __shared__ __align__(16) unsigned short Bs[2][128 * 64];
  const int z = blockIdx.z;
  GA g = (z == 0) ? g0 : (z == 1) ? g1 : (z == 2) ? g2 : g3;

  const int tid = threadIdx.x;
  const int lane = tid & 63;
  const int wid = tid >> 6;
  const int wn = wid * 32;
  const long bm = (long)blockIdx.x * 64;
  const long bn = (long)blockIdx.y * 128;

  f32x4 acc[4][2] = {};

  const int lr = tid >> 3;
  const int lc = (((tid & 7) ^ (lr & 7)) * 8);

  const long r0 = g.ridx ? (long)g.ridx[bm + lr] : bm + lr;
  const long r1 = g.ridx ? (long)g.ridx[bm + 32 + lr] : bm + 32 + lr;
  const unsigned short* ap0 = g.A + r0 * g.lda + lc;
  const unsigned short* ap1 = g.A + r1 * g.lda + lc;
  const unsigned short* bp0 = g.B + (bn + lr) * (long)g.ldb + lc;
  const unsigned short* bp1 = g.B + (bn + 32 + lr) * (long)g.ldb + lc;
  const unsigned short* bp2 = g.B + (bn + 64 + lr) * (long)g.ldb + lc;
  const unsigned short* bp3 = g.B + (bn + 96 + lr) * (long)g.ldb + lc;

  const int rsel = lane & 15;
  const int rx = rsel & 7;

  auto STAGE = [&](int buf, int k0) {
    gload_lds16(ap0 + k0, &As[buf][tid * 8]);
    gload_lds16(ap1 + k0, &As[buf][(256 + tid) * 8]);
    gload_lds16(bp0 + k0, &Bs[buf][tid * 8]);
    gload_lds16(bp1 + k0, &Bs[buf][(256 + tid) * 8]);
    gload_lds16(bp2 + k0, &Bs[buf][(512 + tid) * 8]);
    gload_lds16(bp3 + k0, &Bs[buf][(768 + tid) * 8]);
  };
  auto COMPUTE = [&](int buf) {
#pragma unroll
    for (int kk = 0; kk < 2; ++kk) {
      const int koz = (((kk * 4 + (lane >> 4)) ^ rx) << 3);
      bf16x8 av[4], bv[2];
#pragma unroll
      for (int m = 0; m < 4; ++m)
        av[m] = *(const bf16x8*)(&As[buf][(m * 16 + rsel) * 64 + koz]);
#pragma unroll
      for (int n = 0; n < 2; ++n)
        bv[n] = *(const bf16x8*)(&Bs[buf][(wn + n * 16 + rsel) * 64 + koz]);
#pragma unroll
      for (int m = 0; m < 4; ++m)
#pragma unroll
        for (int n = 0; n < 2; ++n)
          acc[m][n] = __builtin_amdgcn_mfma_f32_16x16x32_bf16(av[m], bv[n], acc[m][n], 0, 0, 0);
    }
  };

  STAGE(0, 0);
  int cur = 0;
  for (int k0 = 64; k0 < g.K; k0 += 64) {
    STAGE(cur ^ 1, k0);
    asm volatile("s_waitcnt vmcnt(6)" ::: "memory");
    __builtin_amdgcn_s_barrier();
    asm volatile("" ::: "memory");
    COMPUTE(cur);
    asm volatile("" ::: "memory");
    __builtin_amdgcn_s_barrier();
    cur ^= 1;
  }
  asm volatile("s_waitcnt vmcnt(0)" ::: "memory");
  __builtin_amdgcn_s_barrier();
  asm volatile("" ::: "memory");
  COMPUTE(cur);

  const int crow0 = (lane >> 4) * 4;
  const int ccol = lane & 15;
#pragma unroll
  for (int m = 0; m < 4; ++m)
#pragma unroll
    for (int n = 0; n < 2; ++n) {
      const long r = bm + m * 16 + crow0;
      const long c = bn + wn + n * 16 + ccol;
#pragma unroll
      for (int q = 0; q < 4; ++q)
        g.C[(r + q) * (long)g.N + c] = f2b(acc[m][n][q]);
    }

  if (g.csum) {
#pragma unroll
    for (int n = 0; n < 2; ++n) {
      float s = 0.f, s2 = 0.f;
#pragma unroll
      for (int m = 0; m < 4; ++m)
#pragma unroll
        for (int q = 0; q < 4; ++q) {
          float v = acc[m][n][q];
          s += v; s2 += v * v;
        }
      s  += __shfl_xor(s, 16);  s  += __shfl_xor(s, 32);
      s2 += __shfl_xor(s2, 16); s2 += __shfl_xor(s2, 32);
      if ((lane >> 4) == 0) {
        const long c = bn + wn + n * 16 + ccol;
        atomicAdd(&g.csum[c], s);
        atomicAdd(&g.csumsq[c], s2);
      }
    }
  }
}

// ---------------- merged prep kernels ----------------
__global__ void init_all(int* iz, int nIz, float* deg, int nDeg,
                         float* stats, int nStats) {
  int i = blockIdx.x * 256 + threadIdx.x;
  if (i < nIz) iz[i] = 0;
  if (i < nDeg) deg[i] = 1.f;
  if (i < nStats) stats[i] = 0.f;
}

__global__ void prep_b(const int* __restrict__ d_ei, const float* __restrict__ d_ew,
                       float* __restrict__ deg_d,
                       const int* __restrict__ p_ei, const float* __restrict__ p_ew,
                       float* __restrict__ deg_p,
                       const int* __restrict__ d_index, int* __restrict__ flag_d,
                       const int* __restrict__ p_index, int* __restrict__ flag_p) {
  int e = blockIdx.x * 256 + threadIdx.x;
  if (e < 65536) atomicAdd(&deg_d[d_ei[65536 + e]], d_ew[e]);
  int e2 = e - 65536;
  if (e2 >= 0 && e2 < 25000) atomicAdd(&deg_p[p_ei[25000 + e2]], p_ew[e2]);
  if (e < 2048) flag_d[d_index[e]] = 1;
  else if (e < 4096) flag_p[p_index[e - 2048]] = 1;
}

__global__ void prep_c(float* __restrict__ deg, int nDeg,
                       int* __restrict__ flag_d, int* __restrict__ ctr_d,
                       int* __restrict__ slot_d,
                       int* __restrict__ flag_p, int* __restrict__ ctr_p,
                       int* __restrict__ slot_p) {
  int i = blockIdx.x * 256 + threadIdx.x;
  if (i < nDeg) deg[i] = rsqrtf(deg[i]);
  if (i < 10000) {
    if (flag_d[i]) { int s = atomicAdd(ctr_d, 1); flag_d[i] = s + 1; slot_d[s] = i; }
  } else if (i < 15000) {
    int j = i - 10000;
    if (flag_p[j]) { int s = atomicAdd(ctr_p, 1); flag_p[j] = s + 1; slot_p[s] = j; }
  }
}

__global__ void prep_d(const int* __restrict__ d_index, const int* __restrict__ flag_d,
                       int* __restrict__ ridx_d,
                       const int* __restrict__ p_index, const int* __restrict__ flag_p,
                       int* __restrict__ ridx_p,
                       const int* __restrict__ d_ei, int* __restrict__ cnt_d,
                       const int* __restrict__ p_ei, int* __restrict__ cnt_p) {
  int e = blockIdx.x * 256 + threadIdx.x;
  if (e < 2048) ridx_d[e] = flag_d[d_index[e]] - 1;
  else if (e < 4096) { int j = e - 2048; ridx_p[j] = flag_p[p_index[j]] - 1; }
  if (e < 65536) { int s = flag_d[d_ei[65536 + e]]; if (s) atomicAdd(&cnt_d[s - 1], 1); }
  int e2 = e - 65536;
  if (e2 >= 0 && e2 < 25000) { int s = flag_p[p_ei[25000 + e2]]; if (s) atomicAdd(&cnt_p[s - 1], 1); }
}

__global__ void scan2048x2(const int* __restrict__ cnt_d, int* __restrict__ rp_d,
                           const int* __restrict__ cnt_p, int* __restrict__ rp_p) {
  const int* cnt = blockIdx.x ? cnt_p : cnt_d;
  int* rowptr    = blockIdx.x ? rp_p : rp_d;
  __shared__ int part[256];
  int tid = threadIdx.x;
  int base = tid * 8;
  int vals[8]; int s = 0;
#pragma unroll
  for (int i = 0; i < 8; ++i) { vals[i] = s; s += cnt[base + i]; }
  part[tid] = s;
  __syncthreads();
  if (tid == 0) { int r = 0; for (int i = 0; i < 256; ++i) { int t = part[i]; part[i] = r; r += t; } }
  __syncthreads();
  int off = part[tid];
#pragma unroll
  for (int i = 0; i < 8; ++i) rowptr[base + i] = off + vals[i];
  if (tid == 255) rowptr[2048] = off + s;
}
__global__ void fill_edges2(
    const int* __restrict__ d_ei, const float* __restrict__ d_ew,
    const float* __restrict__ dinv_d, const int* __restrict__ flag_d,
    const int* __restrict__ rp_d, int* __restrict__ fill_d,
    int2* __restrict__ em_d,
    const int* __restrict__ p_ei, const float* __restrict__ p_ew,
    const float* __restrict__ dinv_p, const int* __restrict__ flag_p,
    const int* __restrict__ rp_p, int* __restrict__ fill_p,
    int2* __restrict__ em_p) {
  int e = blockIdx.x * 256 + threadIdx.x;
  if (e < 65536) {
    int dst = d_ei[65536 + e];
    int s = flag_d[dst];
    if (s) {
      int src = d_ei[e];
      int pos = rp_d[s - 1] + atomicAdd(&fill_d[s - 1], 1);
      float cf = d_ew[e] * dinv_d[src] * dinv_d[dst];
      em_d[pos] = make_int2(src, __float_as_int(cf));
    }
  }
  int e2 = e - 65536;
  if (e2 >= 0 && e2 < 25000) {
    int dst = p_ei[25000 + e2];
    int s = flag_p[dst];
    if (s) {
      int src = p_ei[e2];
      int pos = rp_p[s - 1] + atomicAdd(&fill_p[s - 1], 1);
      float cf = p_ew[e2] * dinv_p[src] * dinv_p[dst];
      em_p[pos] = make_int2(src, __float_as_int(cf));
    }
  }
}

// ---- merged gather + weight transposes, one launch.
__global__ __launch_bounds__(256) void gather_or_transpose(
    const float* __restrict__ Xd, const float* __restrict__ dinv_d,
    const int* __restrict__ slot_d, const int* __restrict__ rp_d,
    const int2* __restrict__ em_d,
    const int* __restrict__ nflag_d, unsigned short* __restrict__ aggd,
    const float* __restrict__ Xp, const float* __restrict__ dinv_p,
    const int* __restrict__ slot_p, const int* __restrict__ rp_p,
    const int2* __restrict__ em_p,
    const int* __restrict__ nflag_p, unsigned short* __restrict__ aggp,
    const float* W0, unsigned short* T0,
    const float* W1, unsigned short* T1,
    const float* W2, unsigned short* T2,
    const float* W3, unsigned short* T3,
    const float* W4, unsigned short* T4,
    const float* W5, unsigned short* T5,
    const float* W6, unsigned short* T6)
{
  __shared__ float tile[32][33];
  const int tid = threadIdx.x;

  if (blockIdx.x >= 7680) {
    int bid = blockIdx.x - 7680;
    const float* W; unsigned short* Wt; int K, N, Kp, Np_, tx, local;
    if      (bid <  1024) { W=W0; Wt=T0; K=1024; N=1024; Kp=1024; Np_=1024; tx=32;  local=bid; }
    else if (bid <  3840) { W=W1; Wt=T1; K=2812; N=1024; Kp=2816; Np_=1024; tx=88;  local=bid-1024; }
    else if (bid <  7296) { W=W2; Wt=T2; K=3372; N=1024; Kp=3456; Np_=1024; tx=108; local=bid-3840; }
    else if (bid <  7552) { W=W3; Wt=T3; K=1024; N=256;  Kp=1024; Np_=256;  tx=32;  local=bid-7296; }
    else if (bid <  7808) { W=W4; Wt=T4; K=256;  N=1024; Kp=256;  Np_=1024; tx=8;   local=bid-7552; }
    else if (bid <  7840) { W=W5; Wt=T5; K=256;  N=64;   Kp=256;  Np_=128;  tx=8;   local=bid-7808; }
    else                  { W=W6; Wt=T6; K=1024; N=3372; Kp=1024; Np_=3456; tx=32;  local=bid-7840; }
    const int thx = tid & 31, thy = tid >> 5;
    int k0 = (local % tx) * 32, n0 = (local / tx) * 32;
    for (int i = thy; i < 32; i += 8) {
      int k = k0 + i, n = n0 + thx;
      tile[i][thx] = (k < K && n < N) ? W[(size_t)k * N + n] : 0.f;
    }
    __syncthreads();
    for (int i = thy; i < 32; i += 8) {
      int n = n0 + i, k = k0 + thx;
      if (n < Np_ && k < Kp) Wt[(size_t)n * Kp + k] = f2b(tile[thx][i]);
    }
    return;
  }

  const int gw = blockIdx.x * 4 + (tid >> 6);
  const int lane = tid & 63;

  int slot, c, Kdata4, Kst4, Kld, nflag;
  const float *X, *dinv; const int *slotn, *rp; const int2* em;
  unsigned short* agg;
  if (gw < 8192) {
    slot = gw >> 2;
    c = (gw & 3) * 64 + lane;
    X = Xd; dinv = dinv_d; slotn = slot_d; rp = rp_d; em = em_d;
    nflag = *nflag_d; agg = aggd; Kdata4 = 256; Kst4 = 256; Kld = 1024;
  } else {
    int q = gw - 8192;
    slot = q / 11;
    c = (q - slot * 11) * 64 + lane;
    X = Xp; dinv = dinv_p; slotn = slot_p; rp = rp_p; em = em_p;
    nflag = *nflag_p; agg = aggp; Kdata4 = 703; Kst4 = 704; Kld = 2812;
  }
  if (slot >= nflag) return;

  const int n = slotn[slot];
  const float dn = dinv[n];
  const float selfc = dn * dn;
  const int e0 = rp[slot], e1 = rp[slot + 1];
  const bool valid = c < Kdata4;

  float ax = 0.f, ay = 0.f, az = 0.f, aw = 0.f;
  if (valid) {
    float4 v = *(const float4*)(X + (long)n * Kld + 4 * c);
    ax = selfc * v.x; ay = selfc * v.y; az = selfc * v.z; aw = selfc * v.w;
  }

  int e = e0;
  for (; e + 4 <= e1; e += 4) {
    const int2 m0 = em[e], m1 = em[e + 1], m2 = em[e + 2], m3 = em[e + 3];
    if (valid) {
      float4 v0 = *(const float4*)(X + (long)m0.x * Kld + 4 * c);
      float4 v1 = *(const float4*)(X + (long)m1.x * Kld + 4 * c);
      float4 v2 = *(const float4*)(X + (long)m2.x * Kld + 4 * c);
      float4 v3 = *(const float4*)(X + (long)m3.x * Kld + 4 * c);
      const float c0 = __int_as_float(m0.y), c1 = __int_as_float(m1.y);
      const float c2 = __int_as_float(m2.y), c3 = __int_as_float(m3.y);
      ax += c0 * v0.x; ay += c0 * v0.y; az += c0 * v0.z; aw += c0 * v0.w;
      ax += c1 * v1.x; ay += c1 * v1.y; az += c1 * v1.z; aw += c1 * v1.w;
      ax += c2 * v2.x; ay += c2 * v2.y; az += c2 * v2.z; aw += c2 * v2.w;
      ax += c3 * v3.x; ay += c3 * v3.y; az += c3 * v3.z; aw += c3 * v3.w;
    }
  }
  for (; e < e1; ++e) {
    const int2 m = em[e];
    if (valid) {
      float4 v = *(const float4*)(X + (long)m.x * Kld + 4 * c);
      const float cf = __int_as_float(m.y);
      ax += cf * v.x; ay += cf * v.y; az += cf * v.z; aw += cf * v.w;
    }
  }

  if (c < Kst4) {
    ushort4 o; o.x = f2b(ax); o.y = f2b(ay); o.z = f2b(az); o.w = f2b(aw);
    *(ushort4*)(agg + (long)slot * (Kst4 * 4) + 4 * c) = o;
  }
}

// vectorized colstats over bf16 partials (for split-K layers only)
__global__ void colstats4(const unsigned short* __restrict__ Z,
                          const unsigned short* __restrict__ Z2,
                          const unsigned short* __restrict__ Z3, int ldz, int cols,
                          float* __restrict__ csum, float* __restrict__ csumsq) {
  int c4 = blockIdx.x * 256 + threadIdx.x;
  if (c4 * 4 >= cols) return;
  int r0 = blockIdx.y * 16;
  float sx = 0.f, sy = 0.f, sz_ = 0.f, sw = 0.f;
  float qx = 0.f, qy = 0.f, qz = 0.f, qw = 0.f;
  for (int r = r0; r < r0 + 16; ++r) {
    float4 v = ld4b(Z + (long)r * ldz + 4 * c4);
    if (Z2) { float4 w = ld4b(Z2 + (long)r * ldz + 4 * c4);
              v.x += w.x; v.y += w.y; v.z += w.z; v.w += w.w; }
    if (Z3) { float4 w = ld4b(Z3 + (long)r * ldz + 4 * c4);
              v.x += w.x; v.y += w.y; v.z += w.z; v.w += w.w; }
    sx += v.x; sy += v.y; sz_ += v.z; sw += v.w;
    qx += v.x * v.x; qy += v.y * v.y; qz += v.z * v.z; qw += v.w * v.w;
  }
  atomicAdd(&csum[4 * c4 + 0], sx); atomicAdd(&csum[4 * c4 + 1], sy);
  atomicAdd(&csum[4 * c4 + 2], sz_); atomicAdd(&csum[4 * c4 + 3], sw);
  atomicAdd(&csumsq[4 * c4 + 0], qx); atomicAdd(&csumsq[4 * c4 + 1], qy);
  atomicAdd(&csumsq[4 * c4 + 2], qz); atomicAdd(&csumsq[4 * c4 + 3], qw);
}

// apply with INLINE bn-finalize over bf16 partials. csum==null -> bias-only.
__global__ void apply_bn4(const unsigned short* __restrict__ Z,
                          const unsigned short* __restrict__ Z2,
                          const unsigned short* __restrict__ Z3,
                          int ldz, int total4, int cols4,
                          const float* __restrict__ csum, const float* __restrict__ csumsq,
                          const float* __restrict__ g, const float* __restrict__ beta,
                          int leaky,
                          float* __restrict__ f32out, int ldf,
                          unsigned short* __restrict__ b16out, int ldb) {
  int idx = blockIdx.x*256+threadIdx.x;
  if (idx >= total4) return;
  int b = idx / cols4, j = (idx % cols4) * 4;
  float4 v = ld4b(Z + (long)b * ldz + j);
  if (Z2) { float4 w = ld4b(Z2 + (long)b * ldz + j);
            v.x += w.x; v.y += w.y; v.z += w.z; v.w += w.w; }
  if (Z3) { float4 w = ld4b(Z3 + (long)b * ldz + j);
            v.x += w.x; v.y += w.y; v.z += w.z; v.w += w.w; }
  if (csum) {
    const float invB = 1.f / 2048.f;
    float4 cs = *(const float4*)(csum + j);
    float4 cq = *(const float4*)(csumsq + j);
    float4 gg = *(const float4*)(g + j);
    float4 bb = *(const float4*)(beta + j);
    float m, var, sc;
    m = cs.x * invB; var = fmaxf(cq.x * invB - m * m, 0.f);
    sc = gg.x * rsqrtf(var + 1e-5f); v.x = v.x * sc + (bb.x - m * sc);
    m = cs.y * invB; var = fmaxf(cq.y * invB - m * m, 0.f);
    sc = gg.y * rsqrtf(var + 1e-5f); v.y = v.y * sc + (bb.y - m * sc);
    m = cs.z * invB; var = fmaxf(cq.z * invB - m * m, 0.f);
    sc = gg.z * rsqrtf(var + 1e-5f); v.z = v.z * sc + (bb.z - m * sc);
    m = cs.w * invB; var = fmaxf(cq.w * invB - m * m, 0.f);
    sc = gg.w * rsqrtf(var + 1e-5f); v.w = v.w * sc + (bb.w - m * sc);
  } else {
    float4 bb = *(const float4*)(beta + j);
    v.x += bb.x; v.y += bb.y; v.z += bb.z; v.w += bb.w;
  }
  const float neg = leaky ? 0.01f : 0.f;
  v.x = (v.x >= 0.f) ? v.x : neg * v.x;
  v.y = (v.y >= 0.f) ? v.y : neg * v.y;
  v.z = (v.z >= 0.f) ? v.z : neg * v.z;
  v.w = (v.w >= 0.f) ? v.w : neg * v.w;
  if (f32out) *(float4*)(f32out + (long)b * ldf + j) = v;
  if (b16out) {
    ushort4 o; o.x = f2b(v.x); o.y = f2b(v.y); o.z = f2b(v.z); o.w = f2b(v.w);
    *(ushort4*)(b16out + (long)b * ldb + j) = o;
  }
}

// dec-L1 apply + head in ONE launch (role-split):
// blocks [0, 2048): apply role (2048*256 f4 elems of dec1 -> h3b)
// blocks [2048, 2056): head role (2048 rows: bn+lrelu+dot -> y)
__global__ void apply_d1_head(const unsigned short* __restrict__ Z, int ldz,
                              const float* __restrict__ csum, const float* __restrict__ csumsq,
                              const float* __restrict__ g1, const float* __restrict__ be1,
                              unsigned short* __restrict__ h3b,
                              const float* __restrict__ csh, const float* __restrict__ cqh,
                              const float* __restrict__ gh, const float* __restrict__ beh,
                              const float* __restrict__ W2, const float* __restrict__ b2,
                              float* __restrict__ y) {
  const float invB = 1.f / 2048.f;
  if (blockIdx.x < 2048) {
    int idx = blockIdx.x * 256 + threadIdx.x;
    int b = idx >> 8, j = (idx & 255) * 4;
    float4 v = ld4b(Z + (long)b * ldz + j);
    float4 cs = *(const float4*)(csum + j);
    float4 cq = *(const float4*)(csumsq + j);
    float4 gg = *(const float4*)(g1 + j);
    float4 bb = *(const float4*)(be1 + j);
    float m, var, sc;
    m = cs.x * invB; var = fmaxf(cq.x * invB - m * m, 0.f);
    sc = gg.x * rsqrtf(var + 1e-5f); v.x = v.x * sc + (bb.x - m * sc);
    m = cs.y * invB; var = fmaxf(cq.y * invB - m * m, 0.f);
    sc = gg.y * rsqrtf(var + 1e-5f); v.y = v.y * sc + (bb.y - m * sc);
    m = cs.z * invB; var = fmaxf(cq.z * invB - m * m, 0.f);
    sc = gg.z * rsqrtf(var + 1e-5f); v.z = v.z * sc + (bb.z - m * sc);
    m = cs.w * invB; var = fmaxf(cq.w * invB - m * m, 0.f);
    sc = gg.w * rsqrtf(var + 1e-5f); v.w = v.w * sc + (bb.w - m * sc);
    v.x = (v.x >= 0.f) ? v.x : 0.f;
    v.y = (v.y >= 0.f) ? v.y : 0.f;
    v.z = (v.z >= 0.f) ? v.z : 0.f;
    v.w = (v.w >= 0.f) ? v.w : 0.f;
    ushort4 o; o.x = f2b(v.x); o.y = f2b(v.y); o.z = f2b(v.z); o.w = f2b(v.w);
    *(ushort4*)(h3b + (long)b * 1024 + j) = o;
    return;
  }
  int b = (blockIdx.x - 2048) * 256 + threadIdx.x;
  if (b >= 2048) return;
  float s = b2[0];
  for (int k = 0; k < 64; ++k) {
    float m = csh[k] * invB;
    float var = fmaxf(cqh[k] * invB - m * m, 0.f);
    float sc = gh[k] * rsqrtf(var + 1e-5f);
    float sh = beh[k] - m * sc;
    float v = b2f(Z[(long)b * ldz + 1024 + k]);
    v = v * sc + sh;
    v = (v >= 0.f) ? v : 0.01f * v;
    s += v * W2[k];
  }
  y[b] = s;
}

// GCN applies (bf16 partials) + feat copy + pad in one launch.
__global__ void apply_feat(const unsigned short* __restrict__ Zd,
                           const unsigned short* __restrict__ Pd,
                           const float* __restrict__ bd,
                           const unsigned short* __restrict__ Zp,
                           const unsigned short* __restrict__ Pp,
                           const float* __restrict__ bp,
                           const float* __restrict__ dv, const float* __restrict__ pe,
                           float* __restrict__ feat_f32, unsigned short* __restrict__ feat_b16) {
  int idx = blockIdx.x*256+threadIdx.x;
  const int APPLY_N = 2 * 2048 * 256;
  if (idx < APPLY_N) {
    const bool isP = idx >= 2048 * 256;
    int l = isP ? idx - 2048 * 256 : idx;
    int b = l >> 8, j = (l & 255) * 4;
    const unsigned short* Z = isP ? Zp : Zd;
    const unsigned short* P = isP ? Pp : Pd;
    const float* bias = isP ? bp : bd;
    const int coloff = isP ? 2348 : 1324;
    float4 v = ld4b(Z + (long)b * 1024 + j);
    float4 w = ld4b(P + (long)b * 1024 + j);
    float4 bb = *(const float4*)(bias + j);
    v.x += w.x + bb.x; v.y += w.y + bb.y; v.z += w.z + bb.z; v.w += w.w + bb.w;
    v.x = (v.x >= 0.f) ? v.x : 0.01f * v.x;
    v.y = (v.y >= 0.f) ? v.y : 0.01f * v.y;
    v.z = (v.z >= 0.f) ? v.z : 0.01f * v.z;
    v.w = (v.w >= 0.f) ? v.w : 0.01f * v.w;
    *(float4*)(feat_f32 + (long)b * 3372 + coloff + j) = v;
    ushort4 o; o.x = f2b(v.x); o.y = f2b(v.y); o.z = f2b(v.z); o.w = f2b(v.w);
    *(ushort4*)(feat_b16 + (long)b * 3456 + coloff + j) = o;
    return;
  }
  int q = idx - APPLY_N;
  if (q >= 2048 * 352) return;
  int b = q / 352, u = q % 352;
  if (u < 331) {
    int c = u * 4;
    float4 v;
    if (u < 75) v = *(const float4*)(dv + (long)b * 300 + c);
    else        v = *(const float4*)(pe + (long)b * 1024 + (c - 300));
    *(float4*)(feat_f32 + (long)b * 3372 + c) = v;
    ushort4 o; o.x = f2b(v.x); o.y = f2b(v.y); o.z = f2b(v.z); o.w = f2b(v.w);
    *(ushort4*)(feat_b16 + (long)b * 3456 + c) = o;
  } else {
    int c = 3372 + (u - 331) * 4;
    ushort4 o; o.x = 0; o.y = 0; o.z = 0; o.w = 0;
    *(ushort4*)(feat_b16 + (long)b * 3456 + c) = o;
  }
}

extern "C" void kernel_launch(void* const* d_in, const int* in_sizes, int n_in,
                              void* d_out, int out_size, void* d_ws, size_t ws_size,
                              hipStream_t stream) {
  (void)in_sizes; (void)n_in; (void)out_size; (void)ws_size;
  const int*   d_index = (const int*)d_in[0];
  const int*   p_index = (const int*)d_in[1];
  const float* d_vecs  = (const float*)d_in[2];
  const float* p_emb   = (const float*)d_in[3];
  const float* d_ecfps = (const float*)d_in[4];
  const int*   d_ei    = (const int*)d_in[5];
  const float* d_ew    = (const float*)d_in[6];
  const float* p_gos   = (const float*)d_in[7];
  const int*   p_ei    = (const int*)d_in[8];
  const float* p_ew    = (const float*)d_in[9];
  const float* d_gcn_W = (const float*)d_in[10];
  const float* d_gcn_b = (const float*)d_in[11];
  const float* p_gcn_W = (const float*)d_in[12];
  const float* p_gcn_b = (const float*)d_in[13];
  const float* enc_W1  = (const float*)d_in[14];
  const float* enc_g1  = (const float*)d_in[16];
  const float* enc_be1 = (const float*)d_in[17];
  const float* enc_W2  = (const float*)d_in[18];
  const float* enc_g2  = (const float*)d_in[20];
  const float* enc_be2 = (const float*)d_in[21];
  const float* dec_W1  = (const float*)d_in[22];
  const float* dec_g1  = (const float*)d_in[24];
  const float* dec_be1 = (const float*)d_in[25];
  const float* dec_W2  = (const float*)d_in[26];
  const float* dec_g2  = (const float*)d_in[28];
  const float* dec_be2 = (const float*)d_in[29];
  const float* out_W1  = (const float*)d_in[30];
  const float* out_g1  = (const float*)d_in[32];
  const float* out_be1 = (const float*)d_in[33];
  const float* out_W2  = (const float*)d_in[34];
  const float* out_b2  = (const float*)d_in[35];

  float* out = (float*)d_out;
  float* y_out    = out;
  float* enc_out  = out + 2048;
  float* dec_out  = out + 526336;
  float* feat_out = out + 7432192;

  char* ws = (char*)d_ws;
  size_t off = 0;
  auto alloc = [&](size_t bytes) {
    size_t o = off; off = (off + bytes + 255) & ~(size_t)255; return (void*)(ws + o);
  };
  int* iz = (int*)alloc((size_t)23200 * 4);
  int* flag_d = iz;
  int* flag_p = iz + 10000;
  int* cnt_d  = iz + 15000;
  int* cnt_p  = iz + 17048;
  int* fill_d = iz + 19096;
  int* fill_p = iz + 21144;
  int* ctr    = iz + 23192;
  int* slotnode_d = (int*)alloc(2048 * 4);
  int* slotnode_p = (int*)alloc(2048 * 4);
  int* rowptr_d = (int*)alloc(2049 * 4);
  int* rowptr_p = (int*)alloc(2049 * 4);
  int* ridx_d = (int*)alloc(2048 * 4);
  int* ridx_p = (int*)alloc(2048 * 4);
  int2* em_d = (int2*)alloc((size_t)65536 * 8);
  int2* em_p = (int2*)alloc((size_t)25000 * 8);
  float* deg   = (float*)alloc((size_t)15000 * 4);
  float* deg_d = deg;
  float* deg_p = deg + 10000;
  float* stats = (float*)alloc((size_t)34560 * 4);
  float* cs_e1 = stats,         * cq_e1 = stats + 3456;
  float* cs_e2 = stats + 6912,  * cq_e2 = stats + 10368;
  float* cs_d1 = stats + 13824, * cq_d1 = stats + 17280;
  float* cs_d2 = stats + 27648, * cq_d2 = stats + 31104;
  unsigned short* aggd_b = (unsigned short*)alloc((size_t)2048 * 1024 * 2);
  unsigned short* aggp_b = (unsigned short*)alloc((size_t)2048 * 2816 * 2);
  unsigned short* WdT   = (unsigned short*)alloc((size_t)1024 * 1024 * 2);
  unsigned short* WpT   = (unsigned short*)alloc((size_t)1024 * 2816 * 2);
  unsigned short* eW1T  = (unsigned short*)alloc((size_t)1024 * 3456 * 2);
  unsigned short* eW2T  = (unsigned short*)alloc((size_t)256 * 1024 * 2);
  unsigned short* dhT   = (unsigned short*)alloc((size_t)1152 * 256 * 2);
  unsigned short* dW2T  = (unsigned short*)alloc((size_t)3456 * 1024 * 2);
  unsigned short* featb = (unsigned short*)alloc((size_t)2048 * 3456 * 2);
  unsigned short* Z   = (unsigned short*)alloc((size_t)2048 * 3456 * 2);
  unsigned short* P0  = (unsigned short*)alloc((size_t)2048 * 1152 * 2);
  unsigned short* P1  = (unsigned short*)alloc((size_t)2048 * 1152 * 2);
  unsigned short* P2  = (unsigned short*)alloc((size_t)2048 * 1152 * 2);
  unsigned short* h1b  = (unsigned short*)alloc((size_t)2048 * 1024 * 2);
  unsigned short* encb = (unsigned short*)alloc((size_t)2048 * 256 * 2);
  unsigned short* h3b  = (unsigned short*)alloc((size_t)2048 * 1024 * 2);

  // ---- GCN prep (merged launches) ----
  init_all<<<CDIV(34560,256),256,0,stream>>>(iz, 23200, deg, 15000, stats, 34560);
  prep_b<<<CDIV(90536,256),256,0,stream>>>(d_ei, d_ew, deg_d, p_ei, p_ew, deg_p,
                                           d_index, flag_d, p_index, flag_p);
  prep_c<<<CDIV(15000,256),256,0,stream>>>(deg, 15000, flag_d, ctr, slotnode_d,
                                           flag_p, ctr + 1, slotnode_p);
  prep_d<<<CDIV(90536,256),256,0,stream>>>(d_index, flag_d, ridx_d, p_index, flag_p, ridx_p,
                                           d_ei, cnt_d, p_ei, cnt_p);
  scan2048x2<<<2,256,0,stream>>>(cnt_d, rowptr_d, cnt_p, rowptr_p);
  fill_edges2<<<CDIV(90536,256),256,0,stream>>>(
      d_ei, d_ew, deg_d, flag_d, rowptr_d, fill_d, em_d,
      p_ei, p_ew, deg_p, flag_p, rowptr_p, fill_p, em_p);

  // ---- gather + all weight transposes in ONE launch ----
  gather_or_transpose<<<7680 + 11296, 256, 0, stream>>>(
      d_ecfps, deg_d, slotnode_d, rowptr_d, em_d, ctr, aggd_b,
      p_gos,   deg_p, slotnode_p, rowptr_p, em_p, ctr + 1, aggp_b,
      d_gcn_W, WdT, p_gcn_W, WpT, enc_W1, eW1T, enc_W2, eW2T,
      dec_W1, dhT, out_W1, dhT + (size_t)1024 * 256, dec_W2, dW2T);

  // ---- GCN GEMMs: dbuf 128^2, d splitK x2 + p splitK x2 (512 blocks) ----
  {
    GA gd0{aggd_b,        WdT,        Z,  ridx_d, nullptr, nullptr, 1024,  512, 1024, 1024};
    GA gd1{aggd_b + 512,  WdT + 512,  P0, ridx_d, nullptr, nullptr, 1024,  512, 1024, 1024};
    GA gp0{aggp_b,        WpT,        P1, ridx_p, nullptr, nullptr, 1024, 1408, 2816, 2816};
    GA gp1{aggp_b + 1408, WpT + 1408, P2, ridx_p, nullptr, nullptr, 1024, 1408, 2816, 2816};
    gemm128z<<<dim3(16,8,4),256,0,stream>>>(gd0, gd1, gp0, gp1);
  }
  apply_feat<<<CDIV(2*2048*256 + 2048*352,256),256,0,stream>>>(
      Z, P0, d_gcn_b, P1, P2, p_gcn_b, d_vecs, p_emb, feat_out, featb);

  // ---- encoder L1: dbuf 128^2, split-K x3 (384 blocks) ----
  {
    GA e0{featb,        eW1T,        Z,  nullptr, nullptr, nullptr, 1024, 1152, 3456, 3456};
    GA e1{featb + 1152, eW1T + 1152, P0, nullptr, nullptr, nullptr, 1024, 1152, 3456, 3456};
    GA e2{featb + 2304, eW1T + 2304, P1, nullptr, nullptr, nullptr, 1024, 1152, 3456, 3456};
    gemm128z<<<dim3(16,8,3),256,0,stream>>>(e0, e1, e2, e0);
  }
  colstats4<<<dim3(1,128),256,0,stream>>>(Z, P0, P1, 1024, 1024, cs_e1, cq_e1);
  apply_bn4<<<CDIV(2048*256,256),256,0,stream>>>(Z, P0, P1, 1024, 2048*256, 256,
      cs_e1, cq_e1, enc_g1, enc_be1, 0, nullptr, 0, h1b, 1024);

  // ---- encoder L2: split-K x2 -> encoded (64-tile dbuf) ----
  {
    GA e0{h1b,       eW2T,       Z,  nullptr, nullptr, nullptr, 256, 512, 1024, 1024};
    GA e1{h1b + 512, eW2T + 512, P0, nullptr, nullptr, nullptr, 256, 512, 1024, 1024};
    gemm64s<<<dim3(32,2,2),256,0,stream>>>(e0, e1, e0, e0);
  }
  colstats4<<<dim3(1,128),256,0,stream>>>(Z, P0, nullptr, 256, 256, cs_e2, cq_e2);
  apply_bn4<<<CDIV(2048*64,256),256,0,stream>>>(Z, P0, nullptr, 256, 2048*64, 64,
      cs_e2, cq_e2, enc_g2, enc_be2, 0, enc_out, 256, encb, 256);

  // ---- decoder L1 + head GEMM with FUSED stats (288 blocks, no split-K) ----
  {
    GA g0{encb, dhT, Z, nullptr, cs_d1, cq_d1, 1152, 256, 256, 256};
    gemm64s<<<dim3(32,9,1),256,0,stream>>>(g0, g0, g0, g0);
  }
  // dec-L1 apply + head in one launch (role-split)
  apply_d1_head<<<2056,256,0,stream>>>(Z, 1152, cs_d1, cq_d1, dec_g1, dec_be1, h3b,
                                       cs_d1 + 1024, cq_d1 + 1024, out_g1, out_be1,
                                       out_W2, out_b2, y_out);

  // ---- decoder L2: dbuf 128^2 with FUSED stats (432 blocks, no split-K) ----
  {
    GA g0{h3b, dW2T, Z, nullptr, cs_d2, cq_d2, 3456, 1024, 1024, 1024};
    gemm128z<<<dim3(16,27,1),256,0,stream>>>(g0, g0, g0, g0);
  }
  apply_bn4<<<CDIV(2048*843,256),256,0,stream>>>(Z, nullptr, nullptr, 3456, 2048*843, 843,
      cs_d2, cq_d2, dec_g2, dec_be2, 0, dec_out, 3372, nullptr, 0);
}